// Round 1
// baseline (9205.587 us; speedup 1.0000x reference)
//
#include <hip/hip_runtime.h>
#include <hip/hip_bf16.h>

// Problem constants
#define Bz   16
#define Sz   300
#define Dz   768
#define Kc   512
#define Vz   5000
#define Hh   8
#define HD   96
#define Lz   50
#define Tz   49          // L-1
#define NTOK 4800        // B*S
#define NDTOK 784        // B*T

// ---------------------------------------------------------------------------
// Generic tiled fp32 GEMM:  C[M,N] = A[M,Kd] * Bw[N,Kd]^T (+bias[n]) (+resid[m,n]) (relu?)
// 128x128 tile, BK=8, 256 threads, 8x8 per-thread micro-tile.
// ---------------------------------------------------------------------------
__global__ __launch_bounds__(256) void gemm_kernel(
    const float* __restrict__ A, int lda,
    const float* __restrict__ Bw, int ldb,
    float* __restrict__ C, int ldc,
    const float* __restrict__ bias,
    const float* __restrict__ resid,
    int relu, int M, int N, int Kd)
{
    __shared__ float As[8][128];
    __shared__ float Bs[8][128];
    const int tid  = threadIdx.x;
    const int row0 = blockIdx.y * 128;
    const int col0 = blockIdx.x * 128;
    const int tx = tid & 15, ty = tid >> 4;
    const int lm = tid >> 1;
    const int lk = (tid & 1) * 4;

    float acc[8][8];
#pragma unroll
    for (int i = 0; i < 8; ++i)
#pragma unroll
        for (int j = 0; j < 8; ++j) acc[i][j] = 0.f;

    const int garow = row0 + lm;
    const int gbrow = col0 + lm;
    const float* Aptr = A + (size_t)garow * lda + lk;
    const float* Bptr = Bw + (size_t)gbrow * ldb + lk;

    for (int k0 = 0; k0 < Kd; k0 += 8) {
        float4 av = make_float4(0.f, 0.f, 0.f, 0.f);
        float4 bv = make_float4(0.f, 0.f, 0.f, 0.f);
        if (garow < M) av = *(const float4*)(Aptr + k0);
        if (gbrow < N) bv = *(const float4*)(Bptr + k0);
        As[lk + 0][lm] = av.x; As[lk + 1][lm] = av.y;
        As[lk + 2][lm] = av.z; As[lk + 3][lm] = av.w;
        Bs[lk + 0][lm] = bv.x; Bs[lk + 1][lm] = bv.y;
        Bs[lk + 2][lm] = bv.z; Bs[lk + 3][lm] = bv.w;
        __syncthreads();
#pragma unroll
        for (int kk = 0; kk < 8; ++kk) {
            float a[8], b[8];
#pragma unroll
            for (int i = 0; i < 8; ++i) a[i] = As[kk][ty * 8 + i];
#pragma unroll
            for (int j = 0; j < 8; ++j) b[j] = Bs[kk][tx * 8 + j];
#pragma unroll
            for (int i = 0; i < 8; ++i)
#pragma unroll
                for (int j = 0; j < 8; ++j)
                    acc[i][j] = fmaf(a[i], b[j], acc[i][j]);
        }
        __syncthreads();
    }

#pragma unroll
    for (int i = 0; i < 8; ++i) {
        int r = row0 + ty * 8 + i;
        if (r >= M) continue;
#pragma unroll
        for (int j = 0; j < 8; ++j) {
            int c = col0 + tx * 8 + j;
            if (c >= N) continue;
            float v = acc[i][j];
            if (bias)  v += bias[c];
            if (resid) v += resid[(size_t)r * ldc + c];
            if (relu)  v = fmaxf(v, 0.f);
            C[(size_t)r * ldc + c] = v;
        }
    }
}

// ---------------------------------------------------------------------------
// Flash-style attention, fp32, hd=96, Tq=Tk=32.
// O layout: (b, sq, h, hd) with row stride 768 (head-major inside row).
// ---------------------------------------------------------------------------
__global__ __launch_bounds__(256) void attn_kernel(
    const float* __restrict__ Qp, int qld, int qoff,
    const float* __restrict__ Kp, int kld, int koff,
    const float* __restrict__ Vp, int vld, int voff,
    float* __restrict__ Op,
    int Sq, int Sk, float scale, int causal,
    const int* __restrict__ lab)   // labels for key-padding mask, or nullptr
{
    const int qt = blockIdx.x, h = blockIdx.y, b = blockIdx.z;
    const int q0 = qt * 32;
    __shared__ float Qs[32][100];
    __shared__ float Ks[32][100];
    __shared__ float Vs[32][100];
    __shared__ float Ps[32][33];
    __shared__ float mrow[32], lrow[32], arow[32];
    const int tid = threadIdx.x;

    for (int e = tid; e < 32 * 24; e += 256) {
        int r = e / 24, c4 = (e % 24) * 4;
        int gq = q0 + r;
        float4 v = make_float4(0.f, 0.f, 0.f, 0.f);
        if (gq < Sq)
            v = *(const float4*)(Qp + (size_t)(b * Sq + gq) * qld + qoff + h * HD + c4);
        Qs[r][c4] = v.x; Qs[r][c4 + 1] = v.y; Qs[r][c4 + 2] = v.z; Qs[r][c4 + 3] = v.w;
    }
    if (tid < 32) { mrow[tid] = -3e38f; lrow[tid] = 0.f; }

    float o[12];
#pragma unroll
    for (int c = 0; c < 12; ++c) o[c] = 0.f;
    const int orow = tid & 31, oc0 = (tid >> 5) * 12;
    const int si = tid >> 3, sj0 = (tid & 7) * 4;
    __syncthreads();

    for (int k0 = 0; k0 < Sk; k0 += 32) {
        for (int e = tid; e < 32 * 24; e += 256) {
            int r = e / 24, c4 = (e % 24) * 4;
            int gk = k0 + r;
            float4 kv = make_float4(0.f, 0.f, 0.f, 0.f);
            float4 vv = make_float4(0.f, 0.f, 0.f, 0.f);
            if (gk < Sk) {
                kv = *(const float4*)(Kp + (size_t)(b * Sk + gk) * kld + koff + h * HD + c4);
                vv = *(const float4*)(Vp + (size_t)(b * Sk + gk) * vld + voff + h * HD + c4);
            }
            Ks[r][c4] = kv.x; Ks[r][c4 + 1] = kv.y; Ks[r][c4 + 2] = kv.z; Ks[r][c4 + 3] = kv.w;
            Vs[r][c4] = vv.x; Vs[r][c4 + 1] = vv.y; Vs[r][c4 + 2] = vv.z; Vs[r][c4 + 3] = vv.w;
        }
        __syncthreads();

        // scores: each thread computes Ps[si][sj0..sj0+3]
        {
            float s0 = 0.f, s1 = 0.f, s2 = 0.f, s3 = 0.f;
#pragma unroll 4
            for (int d = 0; d < HD; ++d) {
                float qv = Qs[si][d];
                s0 = fmaf(qv, Ks[sj0 + 0][d], s0);
                s1 = fmaf(qv, Ks[sj0 + 1][d], s1);
                s2 = fmaf(qv, Ks[sj0 + 2][d], s2);
                s3 = fmaf(qv, Ks[sj0 + 3][d], s3);
            }
            float sv[4] = { s0, s1, s2, s3 };
            int gq = q0 + si;
#pragma unroll
            for (int jj = 0; jj < 4; ++jj) {
                int gk = k0 + sj0 + jj;
                float sc = sv[jj] * scale;
                bool ok = (gk < Sk);
                if (causal && gk > gq) ok = false;
                if (ok && lab && lab[b * Lz + gk + 1] == 0) ok = false;
                Ps[si][sj0 + jj] = ok ? sc : -3e38f;
            }
        }
        __syncthreads();

        if (tid < 32) {
            int i = tid;
            float mo = mrow[i];
            float mm = mo;
#pragma unroll
            for (int j = 0; j < 32; ++j) mm = fmaxf(mm, Ps[i][j]);
            float alpha = __expf(mo - mm);
            float ls = 0.f;
#pragma unroll
            for (int j = 0; j < 32; ++j) {
                float p = __expf(Ps[i][j] - mm);
                Ps[i][j] = p;
                ls += p;
            }
            lrow[i] = lrow[i] * alpha + ls;
            mrow[i] = mm;
            arow[i] = alpha;
        }
        __syncthreads();

        {
            float al = arow[orow];
#pragma unroll
            for (int c = 0; c < 12; ++c) o[c] *= al;
            for (int j = 0; j < 32; ++j) {
                float p = Ps[orow][j];
#pragma unroll
                for (int c = 0; c < 12; ++c)
                    o[c] = fmaf(p, Vs[j][oc0 + c], o[c]);
            }
        }
        __syncthreads();
    }

    int gq = q0 + orow;
    if (gq < Sq) {
        float invl = 1.f / lrow[orow];
        float* dst = Op + (size_t)(b * Sq + gq) * Dz + h * HD + oc0;
#pragma unroll
        for (int c = 0; c < 12; ++c) dst[c] = o[c] * invl;
    }
}

// ---------------------------------------------------------------------------
// LayerNorm over last dim (768). One block per token.
// ---------------------------------------------------------------------------
__global__ __launch_bounds__(256) void ln_kernel(
    const float* __restrict__ X, float* __restrict__ Y,
    const float* __restrict__ g, const float* __restrict__ bb)
{
    const int n = blockIdx.x;
    const int tid = threadIdx.x;
    const float* x = X + (size_t)n * Dz;
    float v0 = x[tid], v1 = x[tid + 256], v2 = x[tid + 512];
    float s = v0 + v1 + v2;
    float q = v0 * v0 + v1 * v1 + v2 * v2;
#pragma unroll
    for (int off = 32; off > 0; off >>= 1) {
        s += __shfl_down(s, off);
        q += __shfl_down(q, off);
    }
    __shared__ float sbuf[4], qbuf[4];
    __shared__ float mv[2];
    int wid = tid >> 6;
    if ((tid & 63) == 0) { sbuf[wid] = s; qbuf[wid] = q; }
    __syncthreads();
    if (tid == 0) {
        float ts = sbuf[0] + sbuf[1] + sbuf[2] + sbuf[3];
        float tq = qbuf[0] + qbuf[1] + qbuf[2] + qbuf[3];
        float mean = ts * (1.f / 768.f);
        float var = tq * (1.f / 768.f) - mean * mean;
        mv[0] = mean;
        mv[1] = rsqrtf(var + 1e-5f);
    }
    __syncthreads();
    float mean = mv[0], inv = mv[1];
    float* y = Y + (size_t)n * Dz;
    y[tid]       = (v0 - mean) * inv * g[tid]       + bb[tid];
    y[tid + 256] = (v1 - mean) * inv * g[tid + 256] + bb[tid + 256];
    y[tid + 512] = (v2 - mean) * inv * g[tid + 512] + bb[tid + 512];
}

// ---------------------------------------------------------------------------
// Codebook row sum of squares.
// ---------------------------------------------------------------------------
__global__ __launch_bounds__(256) void sumsq_kernel(
    const float* __restrict__ cb, float* __restrict__ out)
{
    const int c = blockIdx.x, tid = threadIdx.x;
    const float* x = cb + (size_t)c * Dz;
    float v0 = x[tid], v1 = x[tid + 256], v2 = x[tid + 512];
    float q = v0 * v0 + v1 * v1 + v2 * v2;
#pragma unroll
    for (int off = 32; off > 0; off >>= 1) q += __shfl_down(q, off);
    __shared__ float qbuf[4];
    int wid = tid >> 6;
    if ((tid & 63) == 0) qbuf[wid] = q;
    __syncthreads();
    if (tid == 0) out[c] = qbuf[0] + qbuf[1] + qbuf[2] + qbuf[3];
}

// ---------------------------------------------------------------------------
// VQ post: argmin over codes from dot products, gather emb into H, loss accum.
// ---------------------------------------------------------------------------
__global__ __launch_bounds__(256) void vq_post_kernel(
    const float* __restrict__ dots, const float* __restrict__ sumc2,
    const float* __restrict__ feats, const float* __restrict__ codebook,
    const float* __restrict__ emb, float* __restrict__ H,
    float* __restrict__ loss)
{
    const int n = blockIdx.x, tid = threadIdx.x;
    float best = 3.4e38f; int bi = 0;
    for (int c = tid; c < Kc; c += 256) {
        float dct = sumc2[c] - 2.f * dots[(size_t)n * Kc + c];
        if (dct < best) { best = dct; bi = c; }
    }
#pragma unroll
    for (int off = 32; off > 0; off >>= 1) {
        float ov = __shfl_down(best, off);
        int   oi = __shfl_down(bi, off);
        if (ov < best || (ov == best && oi < bi)) { best = ov; bi = oi; }
    }
    __shared__ float vb[4]; __shared__ int ib[4];
    __shared__ int bidx;
    int wid = tid >> 6;
    if ((tid & 63) == 0) { vb[wid] = best; ib[wid] = bi; }
    __syncthreads();
    if (tid == 0) {
        float v = vb[0]; int i = ib[0];
        for (int w = 1; w < 4; ++w)
            if (vb[w] < v || (vb[w] == v && ib[w] < i)) { v = vb[w]; i = ib[w]; }
        bidx = i;
    }
    __syncthreads();
    const int c = bidx;
    float part = 0.f;
    for (int d = tid; d < Dz; d += 256) {
        float xv = feats[(size_t)n * Dz + d];
        float cv = codebook[(size_t)c * Dz + d];
        float df = cv - xv;
        part += df * df;
        H[(size_t)n * Dz + d] = emb[(size_t)c * Dz + d];
    }
#pragma unroll
    for (int off = 32; off > 0; off >>= 1) part += __shfl_down(part, off);
    __shared__ float pb[4];
    if ((tid & 63) == 0) pb[wid] = part;
    __syncthreads();
    if (tid == 0) atomicAdd(loss, pb[0] + pb[1] + pb[2] + pb[3]);
}

// ---------------------------------------------------------------------------
// Decoder input embedding + write target (as float) to output.
// ---------------------------------------------------------------------------
__global__ __launch_bounds__(256) void dec_embed_kernel(
    const int* __restrict__ labels, const float* __restrict__ tok,
    float* __restrict__ Y, float* __restrict__ tgt)
{
    const int t = blockIdx.x;
    const int b = t / Tz, pos = t % Tz;
    const int lab = labels[b * Lz + pos];
    const int tid = threadIdx.x;
    const float* src = tok + (size_t)lab * Dz;
    float* dst = Y + (size_t)t * Dz;
    dst[tid]       = src[tid];
    dst[tid + 256] = src[tid + 256];
    dst[tid + 512] = src[tid + 512];
    if (tid == 0) tgt[t] = (float)labels[b * Lz + pos + 1];
}

__global__ void zero_loss_kernel(float* loss) { *loss = 0.f; }

__global__ void finalize_kernel(const float* loss, float* out)
{
    out[0] = loss[0] * (0.25f / (float)(NTOK * Dz));
}

// ---------------------------------------------------------------------------
extern "C" void kernel_launch(void* const* d_in, const int* in_sizes, int n_in,
                              void* d_out, int out_size, void* d_ws, size_t ws_size,
                              hipStream_t stream)
{
    // Disambiguate input ordering: dict order (per instructions) vs forward()
    // signature order. In signature order in_sizes[8] = enc_bqkv = 4*2304 = 9216.
    bool sig = (n_in > 8 && in_sizes[8] == 9216);
    int I_eWqkv, I_ebqkv, I_eWo, I_ebo, I_eln1g, I_eln1b, I_eW1, I_eb1, I_eW2, I_eb2,
        I_eln2g, I_eln2b, I_sWqkv, I_sbqkv, I_sWo, I_sbo, I_cWqkv, I_cbqkv, I_cWo,
        I_cbo, I_dln1g, I_dln1b, I_dln2g, I_dln2b, I_dln3g, I_dln3b, I_dW1, I_db1,
        I_dW2, I_db2;
    if (sig) {
        I_eWqkv = 7; I_ebqkv = 8; I_eWo = 9; I_ebo = 10; I_eln1g = 11; I_eln1b = 12;
        I_eW1 = 13; I_eb1 = 14; I_eW2 = 15; I_eb2 = 16; I_eln2g = 17; I_eln2b = 18;
        I_sWqkv = 19; I_sbqkv = 20; I_sWo = 21; I_sbo = 22;
        I_cWqkv = 23; I_cbqkv = 24; I_cWo = 25; I_cbo = 26;
        I_dln1g = 27; I_dln1b = 28; I_dln2g = 29; I_dln2b = 30; I_dln3g = 31; I_dln3b = 32;
        I_dW1 = 33; I_db1 = 34; I_dW2 = 35; I_db2 = 36;
    } else {
        I_eWqkv = 7; I_sWqkv = 8; I_cWqkv = 9;
        I_ebqkv = 10; I_eWo = 11; I_ebo = 12; I_eln1g = 13; I_eln1b = 14;
        I_eW1 = 15; I_eb1 = 16; I_eW2 = 17; I_eb2 = 18; I_eln2g = 19; I_eln2b = 20;
        I_sbqkv = 21; I_sWo = 22; I_sbo = 23;
        I_cbqkv = 24; I_cWo = 25; I_cbo = 26;
        I_dln1g = 27; I_dln1b = 28; I_dln2g = 29; I_dln2b = 30; I_dln3g = 31; I_dln3b = 32;
        I_dW1 = 33; I_db1 = 34; I_dW2 = 35; I_db2 = 36;
    }

    const float* feats = (const float*)d_in[0];
    const int*   labels = (const int*)d_in[1];
    const float* cb    = (const float*)d_in[2];
    const float* emb   = (const float*)d_in[3];
    const float* tok   = (const float*)d_in[4];
    const float* fcW   = (const float*)d_in[5];
    const float* fcb   = (const float*)d_in[6];
    const float* eWqkv = (const float*)d_in[I_eWqkv];
    const float* ebqkv = (const float*)d_in[I_ebqkv];
    const float* eWo   = (const float*)d_in[I_eWo];
    const float* ebo   = (const float*)d_in[I_ebo];
    const float* eln1g = (const float*)d_in[I_eln1g];
    const float* eln1b = (const float*)d_in[I_eln1b];
    const float* eW1   = (const float*)d_in[I_eW1];
    const float* eb1   = (const float*)d_in[I_eb1];
    const float* eW2   = (const float*)d_in[I_eW2];
    const float* eb2   = (const float*)d_in[I_eb2];
    const float* eln2g = (const float*)d_in[I_eln2g];
    const float* eln2b = (const float*)d_in[I_eln2b];
    const float* sWqkv = (const float*)d_in[I_sWqkv];
    const float* sbqkv = (const float*)d_in[I_sbqkv];
    const float* sWo   = (const float*)d_in[I_sWo];
    const float* sbo   = (const float*)d_in[I_sbo];
    const float* cWqkv = (const float*)d_in[I_cWqkv];
    const float* cbqkv = (const float*)d_in[I_cbqkv];
    const float* cWo   = (const float*)d_in[I_cWo];
    const float* cbo   = (const float*)d_in[I_cbo];
    const float* dln1g = (const float*)d_in[I_dln1g];
    const float* dln1b = (const float*)d_in[I_dln1b];
    const float* dln2g = (const float*)d_in[I_dln2g];
    const float* dln2b = (const float*)d_in[I_dln2b];
    const float* dln3g = (const float*)d_in[I_dln3g];
    const float* dln3b = (const float*)d_in[I_dln3b];
    const float* dW1   = (const float*)d_in[I_dW1];
    const float* db1   = (const float*)d_in[I_db1];
    const float* dW2   = (const float*)d_in[I_dW2];
    const float* db2   = (const float*)d_in[I_db2];

    // Workspace layout (floats)
    float* ws    = (float*)d_ws;
    float* sumc2 = ws;                     // 512
    float* loss  = ws + 512;               // 1
    float* Hb    = ws + 1024;              // 4800*768
    float* T1    = Hb + 3686400;           // 4800*768
    float* BIG   = T1 + 3686400;           // 4800*2304
    float* ATT   = BIG + 11059200;         // 4800*768
    // decoder aliases
    float* dots  = ATT;                    // 4800*512 (dead before encoder attn)
    float* Yb    = T1;                     // 784*768
    float* T1d   = T1 + 602112;            // 784*768
    float* QKVd  = T1 + 1204224;           // 784*2304 (also FF scratch)
    float* ATTd  = ATT;                    // 784*768
    float* outF  = (float*)d_out;

    auto gemm = [&](const float* A, int lda, const float* Bw, int ldb, float* C, int ldc,
                    const float* bias, const float* resid, int relu, int M, int N, int Kd) {
        dim3 g((N + 127) / 128, (M + 127) / 128);
        gemm_kernel<<<g, 256, 0, stream>>>(A, lda, Bw, ldb, C, ldc, bias, resid, relu, M, N, Kd);
    };

    const float scale = 0.1020620726159658f; // 1/sqrt(96)

    // --- VQ stage ---
    zero_loss_kernel<<<1, 1, 0, stream>>>(loss);
    sumsq_kernel<<<Kc, 256, 0, stream>>>(cb, sumc2);
    gemm(feats, Dz, cb, Dz, dots, Kc, nullptr, nullptr, 0, NTOK, Kc, Dz);
    vq_post_kernel<<<NTOK, 256, 0, stream>>>(dots, sumc2, feats, cb, emb, Hb, loss);
    finalize_kernel<<<1, 1, 0, stream>>>(loss, outF + 3920000);

    // --- Encoder ---
    for (int i = 0; i < 4; ++i) {
        gemm(Hb, Dz, eWqkv + (size_t)i * 2304 * Dz, Dz, BIG, 2304,
             ebqkv + i * 2304, nullptr, 0, NTOK, 2304, Dz);
        attn_kernel<<<dim3(10, Hh, Bz), 256, 0, stream>>>(
            BIG, 2304, 0, BIG, 2304, 768, BIG, 2304, 1536, ATT,
            Sz, Sz, scale, 0, nullptr);
        gemm(ATT, Dz, eWo + (size_t)i * Dz * Dz, Dz, T1, Dz,
             ebo + i * Dz, Hb, 0, NTOK, Dz, Dz);
        ln_kernel<<<NTOK, 256, 0, stream>>>(T1, Hb, eln1g + i * Dz, eln1b + i * Dz);
        gemm(Hb, Dz, eW1 + (size_t)i * 1536 * Dz, Dz, BIG, 1536,
             eb1 + i * 1536, nullptr, 1, NTOK, 1536, Dz);
        gemm(BIG, 1536, eW2 + (size_t)i * Dz * 1536, 1536, T1, Dz,
             eb2 + i * Dz, Hb, 0, NTOK, Dz, 1536);
        ln_kernel<<<NTOK, 256, 0, stream>>>(T1, Hb, eln2g + i * Dz, eln2b + i * Dz);
    }
    // Hb now holds memory (4800 x 768)

    // --- Decoder ---
    dec_embed_kernel<<<NDTOK, 256, 0, stream>>>(labels, tok, Yb, outF + 3920001);
    for (int i = 0; i < 4; ++i) {
        // self-attention
        gemm(Yb, Dz, sWqkv + (size_t)i * 2304 * Dz, Dz, QKVd, 2304,
             sbqkv + i * 2304, nullptr, 0, NDTOK, 2304, Dz);
        attn_kernel<<<dim3(2, Hh, Bz), 256, 0, stream>>>(
            QKVd, 2304, 0, QKVd, 2304, 768, QKVd, 2304, 1536, ATTd,
            Tz, Tz, scale, 1, labels);
        gemm(ATTd, Dz, sWo + (size_t)i * Dz * Dz, Dz, T1d, Dz,
             sbo + i * Dz, Yb, 0, NDTOK, Dz, Dz);
        ln_kernel<<<NDTOK, 256, 0, stream>>>(T1d, Yb, dln1g + i * Dz, dln1b + i * Dz);
        // cross-attention: q from Yb, k/v from memory
        gemm(Yb, Dz, cWqkv + (size_t)i * 2304 * Dz, Dz, QKVd, Dz,
             cbqkv + i * 2304, nullptr, 0, NDTOK, Dz, Dz);
        gemm(Hb, Dz, cWqkv + (size_t)i * 2304 * Dz + (size_t)768 * Dz, Dz, BIG, 1536,
             cbqkv + i * 2304 + 768, nullptr, 0, NTOK, 1536, Dz);
        attn_kernel<<<dim3(2, Hh, Bz), 256, 0, stream>>>(
            QKVd, 768, 0, BIG, 1536, 0, BIG, 1536, 768, ATTd,
            Tz, Sz, scale, 0, nullptr);
        gemm(ATTd, Dz, cWo + (size_t)i * Dz * Dz, Dz, T1d, Dz,
             cbo + i * Dz, Yb, 0, NDTOK, Dz, Dz);
        ln_kernel<<<NDTOK, 256, 0, stream>>>(T1d, Yb, dln2g + i * Dz, dln2b + i * Dz);
        // feed-forward
        gemm(Yb, Dz, dW1 + (size_t)i * 1536 * Dz, Dz, QKVd, 1536,
             db1 + i * 1536, nullptr, 1, NDTOK, 1536, Dz);
        gemm(QKVd, 1536, dW2 + (size_t)i * Dz * 1536, 1536, T1d, Dz,
             db2 + i * Dz, Yb, 0, NDTOK, Dz, 1536);
        ln_kernel<<<NDTOK, 256, 0, stream>>>(T1d, Yb, dln3g + i * Dz, dln3b + i * Dz);
    }

    // --- Final FC: logits straight into d_out ---
    gemm(Yb, Dz, fcW, Dz, outF, Vz, fcb, nullptr, 0, NDTOK, Vz, Dz);
}

// Round 2
// 3560.119 us; speedup vs baseline: 2.5858x; 2.5858x over previous
//
#include <hip/hip_runtime.h>
#include <hip/hip_bf16.h>

// Problem constants
#define Bz   16
#define Sz   300
#define Dz   768
#define Kc   512
#define Vz   5000
#define Hh   8
#define HD   96
#define Lz   50
#define Tz   49          // L-1
#define NTOK 4800        // B*S
#define NDTOK 784        // B*T

typedef short bf16x8 __attribute__((ext_vector_type(8)));
typedef float f32x4  __attribute__((ext_vector_type(4)));

// RNE float->bf16 (finite inputs)
__device__ __forceinline__ unsigned short f2b(float f) {
    unsigned u = __float_as_uint(f);
    unsigned r = (u + 0x7fffu + ((u >> 16) & 1u)) >> 16;
    return (unsigned short)r;
}

__device__ __forceinline__ void glds16(const unsigned short* g, unsigned short* l) {
    __builtin_amdgcn_global_load_lds(
        (const __attribute__((address_space(1))) void*)g,
        (__attribute__((address_space(3))) void*)l, 16, 0, 0);
}

// ---------------------------------------------------------------------------
// bf16 MFMA GEMM (m97 structure): C[M,N] = A[M,K] * W[N,K]^T
// 128x128 tile, BK=32, 256 threads (4 waves, 2x2), 16x16x32 MFMA, 4x4 tiles/wave.
// A,W bf16 (as ushort). Epilogue: +bias(col), +resid fp32, relu, out fp32 and/or bf16.
// Edge rows/cols handled by clamping load rows (results discarded on store).
// ---------------------------------------------------------------------------
__global__ __launch_bounds__(256) void gemm_bf16_kernel(
    const unsigned short* __restrict__ A,   // [M x Kd]
    const unsigned short* __restrict__ Bw,  // [N x Kd]
    float* __restrict__ Cf,                 // fp32 out (or null)
    unsigned short* __restrict__ Cb,        // bf16 out (or null)
    int ldc,
    const float* __restrict__ bias,
    const float* __restrict__ resid, int ldr,
    int relu, int M, int N, int Kd)
{
    __shared__ unsigned short As[128 * 32];
    __shared__ unsigned short Bs[128 * 32];
    const int tid  = threadIdx.x;
    const int wave = tid >> 6, lane = tid & 63;
    const int row0 = blockIdx.y * 128, col0 = blockIdx.x * 128;

    // staging: chunk c (0..7) = rows [c*16, c*16+16) of the 128x32 tile.
    // lane covers row c*16 + (lane>>2), k-elems (lane&3)*8 .. +7 (16 bytes).
    const int c0 = wave * 2;
    const int srow = lane >> 2;
    const int skcol = (lane & 3) * 8;
    int rA0 = row0 + c0 * 16 + srow;        if (rA0 > M - 1) rA0 = M - 1;
    int rA1 = row0 + (c0 + 1) * 16 + srow;  if (rA1 > M - 1) rA1 = M - 1;
    int rB0 = col0 + c0 * 16 + srow;        if (rB0 > N - 1) rB0 = N - 1;
    int rB1 = col0 + (c0 + 1) * 16 + srow;  if (rB1 > N - 1) rB1 = N - 1;
    const unsigned short* pA0 = A + (size_t)rA0 * Kd + skcol;
    const unsigned short* pA1 = A + (size_t)rA1 * Kd + skcol;
    const unsigned short* pB0 = Bw + (size_t)rB0 * Kd + skcol;
    const unsigned short* pB1 = Bw + (size_t)rB1 * Kd + skcol;
    unsigned short* lA0 = &As[c0 * 512];        // wave-uniform LDS base
    unsigned short* lA1 = &As[(c0 + 1) * 512];
    unsigned short* lB0 = &Bs[c0 * 512];
    unsigned short* lB1 = &Bs[(c0 + 1) * 512];

    const int wr = (wave >> 1) * 64, wc = (wave & 1) * 64;
    const int fr = lane & 15;
    const int kq = (lane >> 4) * 8;

    f32x4 acc[4][4];
    const f32x4 zero = { 0.f, 0.f, 0.f, 0.f };
#pragma unroll
    for (int i = 0; i < 4; ++i)
#pragma unroll
        for (int j = 0; j < 4; ++j) acc[i][j] = zero;

    for (int k0 = 0; k0 < Kd; k0 += 32) {
        __syncthreads();
        glds16(pA0 + k0, lA0);
        glds16(pA1 + k0, lA1);
        glds16(pB0 + k0, lB0);
        glds16(pB1 + k0, lB1);
        __syncthreads();

        bf16x8 af[4], bfr[4];
#pragma unroll
        for (int i = 0; i < 4; ++i)
            af[i] = *(const bf16x8*)(const void*)(&As[(wr + i * 16 + fr) * 32 + kq]);
#pragma unroll
        for (int j = 0; j < 4; ++j)
            bfr[j] = *(const bf16x8*)(const void*)(&Bs[(wc + j * 16 + fr) * 32 + kq]);
#pragma unroll
        for (int i = 0; i < 4; ++i)
#pragma unroll
            for (int j = 0; j < 4; ++j)
                acc[i][j] = __builtin_amdgcn_mfma_f32_16x16x32_bf16(
                    af[i], bfr[j], acc[i][j], 0, 0, 0);
    }

    // epilogue: C/D layout col = lane&15, row = (lane>>4)*4 + reg
    const int rbase = row0 + wr + ((lane >> 4) << 2);
    const int cbase = col0 + wc + (lane & 15);
#pragma unroll
    for (int i = 0; i < 4; ++i) {
#pragma unroll
        for (int r = 0; r < 4; ++r) {
            int row = rbase + i * 16 + r;
            if (row >= M) continue;
#pragma unroll
            for (int j = 0; j < 4; ++j) {
                int col = cbase + j * 16;
                if (col >= N) continue;
                float v = acc[i][j][r];
                if (bias)  v += bias[col];
                if (resid) v += resid[(size_t)row * ldr + col];
                if (relu)  v = fmaxf(v, 0.f);
                if (Cf) Cf[(size_t)row * ldc + col] = v;
                if (Cb) Cb[(size_t)row * ldc + col] = f2b(v);
            }
        }
    }
}

// ---------------------------------------------------------------------------
// fp32 tiled GEMM (VQ distance only): C[M,N] = A * Bw^T
// ---------------------------------------------------------------------------
__global__ __launch_bounds__(256) void gemm_kernel(
    const float* __restrict__ A, int lda,
    const float* __restrict__ Bw, int ldb,
    float* __restrict__ C, int ldc,
    int M, int N, int Kd)
{
    __shared__ float As[8][128];
    __shared__ float Bs[8][128];
    const int tid  = threadIdx.x;
    const int row0 = blockIdx.y * 128;
    const int col0 = blockIdx.x * 128;
    const int tx = tid & 15, ty = tid >> 4;
    const int lm = tid >> 1;
    const int lk = (tid & 1) * 4;

    float acc[8][8];
#pragma unroll
    for (int i = 0; i < 8; ++i)
#pragma unroll
        for (int j = 0; j < 8; ++j) acc[i][j] = 0.f;

    const int garow = row0 + lm;
    const int gbrow = col0 + lm;
    const float* Aptr = A + (size_t)garow * lda + lk;
    const float* Bptr = Bw + (size_t)gbrow * ldb + lk;

    for (int k0 = 0; k0 < Kd; k0 += 8) {
        float4 av = make_float4(0.f, 0.f, 0.f, 0.f);
        float4 bv = make_float4(0.f, 0.f, 0.f, 0.f);
        if (garow < M) av = *(const float4*)(Aptr + k0);
        if (gbrow < N) bv = *(const float4*)(Bptr + k0);
        As[lk + 0][lm] = av.x; As[lk + 1][lm] = av.y;
        As[lk + 2][lm] = av.z; As[lk + 3][lm] = av.w;
        Bs[lk + 0][lm] = bv.x; Bs[lk + 1][lm] = bv.y;
        Bs[lk + 2][lm] = bv.z; Bs[lk + 3][lm] = bv.w;
        __syncthreads();
#pragma unroll
        for (int kk = 0; kk < 8; ++kk) {
            float a[8], b[8];
#pragma unroll
            for (int i = 0; i < 8; ++i) a[i] = As[kk][ty * 8 + i];
#pragma unroll
            for (int j = 0; j < 8; ++j) b[j] = Bs[kk][tx * 8 + j];
#pragma unroll
            for (int i = 0; i < 8; ++i)
#pragma unroll
                for (int j = 0; j < 8; ++j)
                    acc[i][j] = fmaf(a[i], b[j], acc[i][j]);
        }
        __syncthreads();
    }

#pragma unroll
    for (int i = 0; i < 8; ++i) {
        int r = row0 + ty * 8 + i;
        if (r >= M) continue;
#pragma unroll
        for (int j = 0; j < 8; ++j) {
            int c = col0 + tx * 8 + j;
            if (c >= N) continue;
            C[(size_t)r * ldc + c] = acc[i][j];
        }
    }
}

// ---------------------------------------------------------------------------
// Flash-style attention, fp32 in, bf16 out, hd=96, tiles 32x32.
// ---------------------------------------------------------------------------
__global__ __launch_bounds__(256) void attn_kernel(
    const float* __restrict__ Qp, int qld, int qoff,
    const float* __restrict__ Kp, int kld, int koff,
    const float* __restrict__ Vp, int vld, int voff,
    unsigned short* __restrict__ Op,
    int Sq, int Sk, float scale, int causal,
    const int* __restrict__ lab)
{
    const int qt = blockIdx.x, h = blockIdx.y, b = blockIdx.z;
    const int q0 = qt * 32;
    __shared__ float Qs[32][100];
    __shared__ float Ks[32][100];
    __shared__ float Vs[32][100];
    __shared__ float Ps[32][33];
    __shared__ float mrow[32], lrow[32], arow[32];
    const int tid = threadIdx.x;

    for (int e = tid; e < 32 * 24; e += 256) {
        int r = e / 24, c4 = (e % 24) * 4;
        int gq = q0 + r;
        float4 v = make_float4(0.f, 0.f, 0.f, 0.f);
        if (gq < Sq)
            v = *(const float4*)(Qp + (size_t)(b * Sq + gq) * qld + qoff + h * HD + c4);
        Qs[r][c4] = v.x; Qs[r][c4 + 1] = v.y; Qs[r][c4 + 2] = v.z; Qs[r][c4 + 3] = v.w;
    }
    if (tid < 32) { mrow[tid] = -3e38f; lrow[tid] = 0.f; }

    float o[12];
#pragma unroll
    for (int c = 0; c < 12; ++c) o[c] = 0.f;
    const int orow = tid & 31, oc0 = (tid >> 5) * 12;
    const int si = tid >> 3, sj0 = (tid & 7) * 4;
    __syncthreads();

    for (int k0 = 0; k0 < Sk; k0 += 32) {
        for (int e = tid; e < 32 * 24; e += 256) {
            int r = e / 24, c4 = (e % 24) * 4;
            int gk = k0 + r;
            float4 kv = make_float4(0.f, 0.f, 0.f, 0.f);
            float4 vv = make_float4(0.f, 0.f, 0.f, 0.f);
            if (gk < Sk) {
                kv = *(const float4*)(Kp + (size_t)(b * Sk + gk) * kld + koff + h * HD + c4);
                vv = *(const float4*)(Vp + (size_t)(b * Sk + gk) * vld + voff + h * HD + c4);
            }
            Ks[r][c4] = kv.x; Ks[r][c4 + 1] = kv.y; Ks[r][c4 + 2] = kv.z; Ks[r][c4 + 3] = kv.w;
            Vs[r][c4] = vv.x; Vs[r][c4 + 1] = vv.y; Vs[r][c4 + 2] = vv.z; Vs[r][c4 + 3] = vv.w;
        }
        __syncthreads();

        {
            float s0 = 0.f, s1 = 0.f, s2 = 0.f, s3 = 0.f;
#pragma unroll 4
            for (int d = 0; d < HD; ++d) {
                float qv = Qs[si][d];
                s0 = fmaf(qv, Ks[sj0 + 0][d], s0);
                s1 = fmaf(qv, Ks[sj0 + 1][d], s1);
                s2 = fmaf(qv, Ks[sj0 + 2][d], s2);
                s3 = fmaf(qv, Ks[sj0 + 3][d], s3);
            }
            float sv[4] = { s0, s1, s2, s3 };
            int gq = q0 + si;
#pragma unroll
            for (int jj = 0; jj < 4; ++jj) {
                int gk = k0 + sj0 + jj;
                float sc = sv[jj] * scale;
                bool ok = (gk < Sk);
                if (causal && gk > gq) ok = false;
                if (ok && lab && lab[b * Lz + gk + 1] == 0) ok = false;
                Ps[si][sj0 + jj] = ok ? sc : -3e38f;
            }
        }
        __syncthreads();

        if (tid < 32) {
            int i = tid;
            float mo = mrow[i];
            float mm = mo;
#pragma unroll
            for (int j = 0; j < 32; ++j) mm = fmaxf(mm, Ps[i][j]);
            float alpha = __expf(mo - mm);
            float ls = 0.f;
#pragma unroll
            for (int j = 0; j < 32; ++j) {
                float p = __expf(Ps[i][j] - mm);
                Ps[i][j] = p;
                ls += p;
            }
            lrow[i] = lrow[i] * alpha + ls;
            mrow[i] = mm;
            arow[i] = alpha;
        }
        __syncthreads();

        {
            float al = arow[orow];
#pragma unroll
            for (int c = 0; c < 12; ++c) o[c] *= al;
            for (int j = 0; j < 32; ++j) {
                float p = Ps[orow][j];
#pragma unroll
                for (int c = 0; c < 12; ++c)
                    o[c] = fmaf(p, Vs[j][oc0 + c], o[c]);
            }
        }
        __syncthreads();
    }

    int gq = q0 + orow;
    if (gq < Sq) {
        float invl = 1.f / lrow[orow];
        unsigned short* dst = Op + (size_t)(b * Sq + gq) * Dz + h * HD + oc0;
#pragma unroll
        for (int c = 0; c < 12; ++c) dst[c] = f2b(o[c] * invl);
    }
}

// ---------------------------------------------------------------------------
// LayerNorm over last dim (768); writes fp32 and optional bf16 copy.
// ---------------------------------------------------------------------------
__global__ __launch_bounds__(256) void ln_kernel(
    const float* __restrict__ X, float* __restrict__ Y,
    unsigned short* __restrict__ Ybf,
    const float* __restrict__ g, const float* __restrict__ bb)
{
    const int n = blockIdx.x;
    const int tid = threadIdx.x;
    const float* x = X + (size_t)n * Dz;
    float v0 = x[tid], v1 = x[tid + 256], v2 = x[tid + 512];
    float s = v0 + v1 + v2;
    float q = v0 * v0 + v1 * v1 + v2 * v2;
#pragma unroll
    for (int off = 32; off > 0; off >>= 1) {
        s += __shfl_down(s, off);
        q += __shfl_down(q, off);
    }
    __shared__ float sbuf[4], qbuf[4];
    __shared__ float mv[2];
    int wid = tid >> 6;
    if ((tid & 63) == 0) { sbuf[wid] = s; qbuf[wid] = q; }
    __syncthreads();
    if (tid == 0) {
        float ts = sbuf[0] + sbuf[1] + sbuf[2] + sbuf[3];
        float tq = qbuf[0] + qbuf[1] + qbuf[2] + qbuf[3];
        float mean = ts * (1.f / 768.f);
        float var = tq * (1.f / 768.f) - mean * mean;
        mv[0] = mean;
        mv[1] = rsqrtf(var + 1e-5f);
    }
    __syncthreads();
    float mean = mv[0], inv = mv[1];
    float* y = Y + (size_t)n * Dz;
    float r0 = (v0 - mean) * inv * g[tid]       + bb[tid];
    float r1 = (v1 - mean) * inv * g[tid + 256] + bb[tid + 256];
    float r2 = (v2 - mean) * inv * g[tid + 512] + bb[tid + 512];
    y[tid] = r0; y[tid + 256] = r1; y[tid + 512] = r2;
    if (Ybf) {
        unsigned short* yb = Ybf + (size_t)n * Dz;
        yb[tid] = f2b(r0); yb[tid + 256] = f2b(r1); yb[tid + 512] = f2b(r2);
    }
}

// ---------------------------------------------------------------------------
__global__ __launch_bounds__(256) void sumsq_kernel(
    const float* __restrict__ cb, float* __restrict__ out)
{
    const int c = blockIdx.x, tid = threadIdx.x;
    const float* x = cb + (size_t)c * Dz;
    float v0 = x[tid], v1 = x[tid + 256], v2 = x[tid + 512];
    float q = v0 * v0 + v1 * v1 + v2 * v2;
#pragma unroll
    for (int off = 32; off > 0; off >>= 1) q += __shfl_down(q, off);
    __shared__ float qbuf[4];
    int wid = tid >> 6;
    if ((tid & 63) == 0) qbuf[wid] = q;
    __syncthreads();
    if (tid == 0) out[c] = qbuf[0] + qbuf[1] + qbuf[2] + qbuf[3];
}

// ---------------------------------------------------------------------------
// VQ post: argmin, gather emb into H (fp32 + bf16), loss accumulate.
// ---------------------------------------------------------------------------
__global__ __launch_bounds__(256) void vq_post_kernel(
    const float* __restrict__ dots, const float* __restrict__ sumc2,
    const float* __restrict__ feats, const float* __restrict__ codebook,
    const float* __restrict__ emb, float* __restrict__ H,
    unsigned short* __restrict__ Hbf,
    float* __restrict__ loss)
{
    const int n = blockIdx.x, tid = threadIdx.x;
    float best = 3.4e38f; int bi = 0;
    for (int c = tid; c < Kc; c += 256) {
        float dct = sumc2[c] - 2.f * dots[(size_t)n * Kc + c];
        if (dct < best) { best = dct; bi = c; }
    }
#pragma unroll
    for (int off = 32; off > 0; off >>= 1) {
        float ov = __shfl_down(best, off);
        int   oi = __shfl_down(bi, off);
        if (ov < best || (ov == best && oi < bi)) { best = ov; bi = oi; }
    }
    __shared__ float vb[4]; __shared__ int ib[4];
    __shared__ int bidx;
    int wid = tid >> 6;
    if ((tid & 63) == 0) { vb[wid] = best; ib[wid] = bi; }
    __syncthreads();
    if (tid == 0) {
        float v = vb[0]; int i = ib[0];
        for (int w = 1; w < 4; ++w)
            if (vb[w] < v || (vb[w] == v && ib[w] < i)) { v = vb[w]; i = ib[w]; }
        bidx = i;
    }
    __syncthreads();
    const int c = bidx;
    float part = 0.f;
    for (int d = tid; d < Dz; d += 256) {
        float xv = feats[(size_t)n * Dz + d];
        float cv = codebook[(size_t)c * Dz + d];
        float df = cv - xv;
        part += df * df;
        float ev = emb[(size_t)c * Dz + d];
        H[(size_t)n * Dz + d] = ev;
        Hbf[(size_t)n * Dz + d] = f2b(ev);
    }
#pragma unroll
    for (int off = 32; off > 0; off >>= 1) part += __shfl_down(part, off);
    __shared__ float pb[4];
    if ((tid & 63) == 0) pb[wid] = part;
    __syncthreads();
    if (tid == 0) atomicAdd(loss, pb[0] + pb[1] + pb[2] + pb[3]);
}

// ---------------------------------------------------------------------------
__global__ __launch_bounds__(256) void dec_embed_kernel(
    const int* __restrict__ labels, const float* __restrict__ tok,
    float* __restrict__ Y, unsigned short* __restrict__ Ybf,
    float* __restrict__ tgt)
{
    const int t = blockIdx.x;
    const int b = t / Tz, pos = t % Tz;
    const int lab = labels[b * Lz + pos];
    const int tid = threadIdx.x;
    const float* src = tok + (size_t)lab * Dz;
    float* dst = Y + (size_t)t * Dz;
    unsigned short* dbf = Ybf + (size_t)t * Dz;
    float a = src[tid], b1 = src[tid + 256], c = src[tid + 512];
    dst[tid] = a; dst[tid + 256] = b1; dst[tid + 512] = c;
    dbf[tid] = f2b(a); dbf[tid + 256] = f2b(b1); dbf[tid + 512] = f2b(c);
    if (tid == 0) tgt[t] = (float)labels[b * Lz + pos + 1];
}

__global__ void zero_loss_kernel(float* loss) { *loss = 0.f; }

__global__ void finalize_kernel(const float* loss, float* out)
{
    out[0] = loss[0] * (0.25f / (float)(NTOK * Dz));
}

// ---------------------------------------------------------------------------
// fp32 -> bf16 conversion over up to 6 concatenated segments.
// ---------------------------------------------------------------------------
__global__ __launch_bounds__(256) void conv6_kernel(
    const float* p0, int n0, const float* p1, int n1,
    const float* p2, int n2, const float* p3, int n3,
    const float* p4, int n4, const float* p5, int n5,
    unsigned short* __restrict__ dst)
{
    const int total = n0 + n1 + n2 + n3 + n4 + n5;
    for (int i = blockIdx.x * blockDim.x + threadIdx.x; i < total;
         i += gridDim.x * blockDim.x) {
        int j = i; const float* p;
        if (j < n0) { p = p0; }
        else { j -= n0;
            if (j < n1) { p = p1; }
            else { j -= n1;
                if (j < n2) { p = p2; }
                else { j -= n2;
                    if (j < n3) { p = p3; }
                    else { j -= n3;
                        if (j < n4) { p = p4; }
                        else { j -= n4; p = p5; }
                    }
                }
            }
        }
        dst[i] = f2b(p[j]);
    }
}

// ---------------------------------------------------------------------------
extern "C" void kernel_launch(void* const* d_in, const int* in_sizes, int n_in,
                              void* d_out, int out_size, void* d_ws, size_t ws_size,
                              hipStream_t stream)
{
    bool sig = (n_in > 8 && in_sizes[8] == 9216);
    int I_eWqkv, I_ebqkv, I_eWo, I_ebo, I_eln1g, I_eln1b, I_eW1, I_eb1, I_eW2, I_eb2,
        I_eln2g, I_eln2b, I_sWqkv, I_sbqkv, I_sWo, I_sbo, I_cWqkv, I_cbqkv, I_cWo,
        I_cbo, I_dln1g, I_dln1b, I_dln2g, I_dln2b, I_dln3g, I_dln3b, I_dW1, I_db1,
        I_dW2, I_db2;
    if (sig) {
        I_eWqkv = 7; I_ebqkv = 8; I_eWo = 9; I_ebo = 10; I_eln1g = 11; I_eln1b = 12;
        I_eW1 = 13; I_eb1 = 14; I_eW2 = 15; I_eb2 = 16; I_eln2g = 17; I_eln2b = 18;
        I_sWqkv = 19; I_sbqkv = 20; I_sWo = 21; I_sbo = 22;
        I_cWqkv = 23; I_cbqkv = 24; I_cWo = 25; I_cbo = 26;
        I_dln1g = 27; I_dln1b = 28; I_dln2g = 29; I_dln2b = 30; I_dln3g = 31; I_dln3b = 32;
        I_dW1 = 33; I_db1 = 34; I_dW2 = 35; I_db2 = 36;
    } else {
        I_eWqkv = 7; I_sWqkv = 8; I_cWqkv = 9;
        I_ebqkv = 10; I_eWo = 11; I_ebo = 12; I_eln1g = 13; I_eln1b = 14;
        I_eW1 = 15; I_eb1 = 16; I_eW2 = 17; I_eb2 = 18; I_eln2g = 19; I_eln2b = 20;
        I_sbqkv = 21; I_sWo = 22; I_sbo = 23;
        I_cbqkv = 24; I_cWo = 25; I_cbo = 26;
        I_dln1g = 27; I_dln1b = 28; I_dln2g = 29; I_dln2b = 30; I_dln3g = 31; I_dln3b = 32;
        I_dW1 = 33; I_db1 = 34; I_dW2 = 35; I_db2 = 36;
    }

    const float* feats = (const float*)d_in[0];
    const int*   labels = (const int*)d_in[1];
    const float* cb    = (const float*)d_in[2];
    const float* emb   = (const float*)d_in[3];
    const float* tok   = (const float*)d_in[4];
    const float* fcW   = (const float*)d_in[5];
    const float* fcb   = (const float*)d_in[6];
    const float* eWqkv = (const float*)d_in[I_eWqkv];
    const float* ebqkv = (const float*)d_in[I_ebqkv];
    const float* eWo   = (const float*)d_in[I_eWo];
    const float* ebo   = (const float*)d_in[I_ebo];
    const float* eln1g = (const float*)d_in[I_eln1g];
    const float* eln1b = (const float*)d_in[I_eln1b];
    const float* eW1   = (const float*)d_in[I_eW1];
    const float* eb1   = (const float*)d_in[I_eb1];
    const float* eW2   = (const float*)d_in[I_eW2];
    const float* eb2   = (const float*)d_in[I_eb2];
    const float* eln2g = (const float*)d_in[I_eln2g];
    const float* eln2b = (const float*)d_in[I_eln2b];
    const float* sWqkv = (const float*)d_in[I_sWqkv];
    const float* sbqkv = (const float*)d_in[I_sbqkv];
    const float* sWo   = (const float*)d_in[I_sWo];
    const float* sbo   = (const float*)d_in[I_sbo];
    const float* cWqkv = (const float*)d_in[I_cWqkv];
    const float* cbqkv = (const float*)d_in[I_cbqkv];
    const float* cWo   = (const float*)d_in[I_cWo];
    const float* cbo   = (const float*)d_in[I_cbo];
    const float* dln1g = (const float*)d_in[I_dln1g];
    const float* dln1b = (const float*)d_in[I_dln1b];
    const float* dln2g = (const float*)d_in[I_dln2g];
    const float* dln2b = (const float*)d_in[I_dln2b];
    const float* dln3g = (const float*)d_in[I_dln3g];
    const float* dln3b = (const float*)d_in[I_dln3b];
    const float* dW1   = (const float*)d_in[I_dW1];
    const float* db1   = (const float*)d_in[I_db1];
    const float* dW2   = (const float*)d_in[I_dW2];
    const float* db2   = (const float*)d_in[I_db2];

    // ---- workspace layout ----
    float* ws    = (float*)d_ws;
    float* sumc2 = ws;                       // 512
    float* loss  = ws + 512;                 // 1
    float* Hb    = ws + 1024;                // 4800*768
    float* T1    = Hb + 3686400;             // 4800*768
    float* BIG   = T1 + 3686400;             // 4800*2304 (QKV enc / crossKV / dots)
    // decoder fp32 aliases inside T1 (3,010,560 <= 3,686,400)
    float* Yb    = T1;                       // 784*768
    float* T1d   = T1 + 602112;              // 784*768
    float* QKVd  = T1 + 1204224;             // 784*2304
    float* dots  = BIG;                      // 4800*512 (VQ stage only)

    unsigned short* bfbase = (unsigned short*)(ws + 18433024);
    unsigned short* Hb_bf  = bfbase;                     // 3,686,400
    unsigned short* ATT_bf = bfbase + 3686400;           // 3,686,400 (enc + dec attn out)
    unsigned short* FF_bf  = bfbase + 7372800;           // 7,372,800 (relu FF1 out)
    unsigned short* Yb_bf  = bfbase + 14745600;          // 602,112
    unsigned short* Wbuf   = bfbase + 15347712;          // 7,077,888 (per-layer weights)

    float* outF = (float*)d_out;

    auto gemmb = [&](const unsigned short* A, const unsigned short* W,
                     float* Cf, unsigned short* Cb, int ldc,
                     const float* bias, const float* resid, int ldr,
                     int relu, int M, int N, int Kd) {
        dim3 g((N + 127) / 128, (M + 127) / 128);
        gemm_bf16_kernel<<<g, 256, 0, stream>>>(A, W, Cf, Cb, ldc, bias, resid, ldr,
                                                relu, M, N, Kd);
    };

    const float scale = 0.1020620726159658f; // 1/sqrt(96)
    const float* Z = nullptr;

    // --- VQ stage (fp32; argmin must not see bf16 rounding) ---
    zero_loss_kernel<<<1, 1, 0, stream>>>(loss);
    sumsq_kernel<<<Kc, 256, 0, stream>>>(cb, sumc2);
    {
        dim3 g(4, 38);
        gemm_kernel<<<g, 256, 0, stream>>>(feats, Dz, cb, Dz, dots, Kc, NTOK, Kc, Dz);
    }
    vq_post_kernel<<<NTOK, 256, 0, stream>>>(dots, sumc2, feats, cb, emb, Hb, Hb_bf, loss);
    finalize_kernel<<<1, 1, 0, stream>>>(loss, outF + 3920000);

    // --- Encoder ---
    const int W_QKV = 2304 * 768, W_O = 768 * 768, W_F1 = 1536 * 768, W_F2 = 768 * 1536;
    for (int i = 0; i < 4; ++i) {
        // convert this layer's weights: [Wqkv | Wo | W1 | W2]
        conv6_kernel<<<1024, 256, 0, stream>>>(
            eWqkv + (size_t)i * W_QKV, W_QKV,
            eWo   + (size_t)i * W_O,   W_O,
            eW1   + (size_t)i * W_F1,  W_F1,
            eW2   + (size_t)i * W_F2,  W_F2,
            Z, 0, Z, 0, Wbuf);
        unsigned short* bWqkv = Wbuf;
        unsigned short* bWo   = Wbuf + W_QKV;
        unsigned short* bW1   = Wbuf + W_QKV + W_O;
        unsigned short* bW2   = Wbuf + W_QKV + W_O + W_F1;

        gemmb(Hb_bf, bWqkv, BIG, nullptr, 2304, ebqkv + i * 2304, Z, 0, 0, NTOK, 2304, Dz);
        attn_kernel<<<dim3(10, Hh, Bz), 256, 0, stream>>>(
            BIG, 2304, 0, BIG, 2304, 768, BIG, 2304, 1536, ATT_bf,
            Sz, Sz, scale, 0, nullptr);
        gemmb(ATT_bf, bWo, T1, nullptr, Dz, ebo + i * Dz, Hb, Dz, 0, NTOK, Dz, Dz);
        ln_kernel<<<NTOK, 256, 0, stream>>>(T1, Hb, Hb_bf, eln1g + i * Dz, eln1b + i * Dz);
        gemmb(Hb_bf, bW1, nullptr, FF_bf, 1536, eb1 + i * 1536, Z, 0, 1, NTOK, 1536, Dz);
        gemmb(FF_bf, bW2, T1, nullptr, Dz, eb2 + i * Dz, Hb, Dz, 0, NTOK, Dz, 1536);
        ln_kernel<<<NTOK, 256, 0, stream>>>(T1, Hb, Hb_bf, eln2g + i * Dz, eln2b + i * Dz);
    }
    // Hb/Hb_bf hold memory

    // --- Decoder ---
    dec_embed_kernel<<<NDTOK, 256, 0, stream>>>(labels, tok, Yb, Yb_bf, outF + 3920001);
    for (int i = 0; i < 4; ++i) {
        conv6_kernel<<<1024, 256, 0, stream>>>(
            sWqkv + (size_t)i * W_QKV, W_QKV,
            sWo   + (size_t)i * W_O,   W_O,
            cWqkv + (size_t)i * W_QKV, W_QKV,
            cWo   + (size_t)i * W_O,   W_O,
            dW1   + (size_t)i * W_F1,  W_F1,
            dW2   + (size_t)i * W_F2,  W_F2, Wbuf);
        unsigned short* bsWqkv = Wbuf;
        unsigned short* bsWo   = Wbuf + W_QKV;
        unsigned short* bcWqkv = Wbuf + W_QKV + W_O;
        unsigned short* bcWo   = Wbuf + 2 * W_QKV + W_O;
        unsigned short* bW1    = Wbuf + 2 * W_QKV + 2 * W_O;
        unsigned short* bW2    = Wbuf + 2 * W_QKV + 2 * W_O + W_F1;

        // self-attention (causal + key-padding)
        gemmb(Yb_bf, bsWqkv, QKVd, nullptr, 2304, sbqkv + i * 2304, Z, 0, 0, NDTOK, 2304, Dz);
        attn_kernel<<<dim3(2, Hh, Bz), 256, 0, stream>>>(
            QKVd, 2304, 0, QKVd, 2304, 768, QKVd, 2304, 1536, ATT_bf,
            Tz, Tz, scale, 1, labels);
        gemmb(ATT_bf, bsWo, T1d, nullptr, Dz, sbo + i * Dz, Yb, Dz, 0, NDTOK, Dz, Dz);
        ln_kernel<<<NDTOK, 256, 0, stream>>>(T1d, Yb, Yb_bf, dln1g + i * Dz, dln1b + i * Dz);
        // cross-attention
        gemmb(Yb_bf, bcWqkv, QKVd, nullptr, Dz, cbqkv + i * 2304, Z, 0, 0, NDTOK, Dz, Dz);
        gemmb(Hb_bf, bcWqkv + (size_t)768 * 768, BIG, nullptr, 1536,
              cbqkv + i * 2304 + 768, Z, 0, 0, NTOK, 1536, Dz);
        attn_kernel<<<dim3(2, Hh, Bz), 256, 0, stream>>>(
            QKVd, 768, 0, BIG, 1536, 0, BIG, 1536, 768, ATT_bf,
            Tz, Sz, scale, 0, nullptr);
        gemmb(ATT_bf, bcWo, T1d, nullptr, Dz, cbo + i * Dz, Yb, Dz, 0, NDTOK, Dz, Dz);
        ln_kernel<<<NDTOK, 256, 0, stream>>>(T1d, Yb, Yb_bf, dln2g + i * Dz, dln2b + i * Dz);
        // feed-forward
        gemmb(Yb_bf, bW1, nullptr, FF_bf, 1536, db1 + i * 1536, Z, 0, 1, NDTOK, 1536, Dz);
        gemmb(FF_bf, bW2, T1d, nullptr, Dz, db2 + i * Dz, Yb, Dz, 0, NDTOK, Dz, 1536);
        ln_kernel<<<NDTOK, 256, 0, stream>>>(T1d, Yb, Yb_bf, dln3g + i * Dz, dln3b + i * Dz);
    }

    // --- Final FC ---
    conv6_kernel<<<1024, 256, 0, stream>>>(fcW, Vz * Dz, Z, 0, Z, 0, Z, 0, Z, 0, Z, 0, Wbuf);
    gemmb(Yb_bf, Wbuf, outF, nullptr, Vz, fcb, Z, 0, 0, NDTOK, Vz, Dz);
}

// Round 3
// 3117.136 us; speedup vs baseline: 2.9532x; 1.1421x over previous
//
#include <hip/hip_runtime.h>
#include <hip/hip_bf16.h>

// Problem constants
#define Bz   16
#define Sz   300
#define Dz   768
#define Kc   512
#define Vz   5000
#define Hh   8
#define HD   96
#define Lz   50
#define Tz   49          // L-1
#define NTOK 4800        // B*S
#define NDTOK 784        // B*T

typedef short bf16x8 __attribute__((ext_vector_type(8)));
typedef float f32x4  __attribute__((ext_vector_type(4)));
typedef unsigned short us8 __attribute__((ext_vector_type(8)));

// RNE float->bf16 (finite inputs)
__device__ __forceinline__ unsigned short f2b(float f) {
    unsigned u = __float_as_uint(f);
    unsigned r = (u + 0x7fffu + ((u >> 16) & 1u)) >> 16;
    return (unsigned short)r;
}

__device__ __forceinline__ void glds16(const unsigned short* g, unsigned short* l) {
    __builtin_amdgcn_global_load_lds(
        (const __attribute__((address_space(1))) void*)g,
        (__attribute__((address_space(3))) void*)l, 16, 0, 0);
}

// ---------------------------------------------------------------------------
// bf16 MFMA GEMM (m97 structure): C[M,N] = A[M,K] * W[N,K]^T
// 128x128 tile, BK=32, 256 threads (4 waves, 2x2), 16x16x32 MFMA, 4x4 tiles/wave.
// ---------------------------------------------------------------------------
__global__ __launch_bounds__(256) void gemm_bf16_kernel(
    const unsigned short* __restrict__ A,   // [M x Kd]
    const unsigned short* __restrict__ Bw,  // [N x Kd]
    float* __restrict__ Cf,                 // fp32 out (or null)
    unsigned short* __restrict__ Cb,        // bf16 out (or null)
    int ldc,
    const float* __restrict__ bias,
    const float* __restrict__ resid, int ldr,
    int relu, int M, int N, int Kd)
{
    __shared__ unsigned short As[128 * 32];
    __shared__ unsigned short Bs[128 * 32];
    const int tid  = threadIdx.x;
    const int wave = tid >> 6, lane = tid & 63;
    const int row0 = blockIdx.y * 128, col0 = blockIdx.x * 128;

    const int c0 = wave * 2;
    const int srow = lane >> 2;
    const int skcol = (lane & 3) * 8;
    int rA0 = row0 + c0 * 16 + srow;        if (rA0 > M - 1) rA0 = M - 1;
    int rA1 = row0 + (c0 + 1) * 16 + srow;  if (rA1 > M - 1) rA1 = M - 1;
    int rB0 = col0 + c0 * 16 + srow;        if (rB0 > N - 1) rB0 = N - 1;
    int rB1 = col0 + (c0 + 1) * 16 + srow;  if (rB1 > N - 1) rB1 = N - 1;
    const unsigned short* pA0 = A + (size_t)rA0 * Kd + skcol;
    const unsigned short* pA1 = A + (size_t)rA1 * Kd + skcol;
    const unsigned short* pB0 = Bw + (size_t)rB0 * Kd + skcol;
    const unsigned short* pB1 = Bw + (size_t)rB1 * Kd + skcol;
    unsigned short* lA0 = &As[c0 * 512];
    unsigned short* lA1 = &As[(c0 + 1) * 512];
    unsigned short* lB0 = &Bs[c0 * 512];
    unsigned short* lB1 = &Bs[(c0 + 1) * 512];

    const int wr = (wave >> 1) * 64, wc = (wave & 1) * 64;
    const int fr = lane & 15;
    const int kq = (lane >> 4) * 8;

    f32x4 acc[4][4];
    const f32x4 zero = { 0.f, 0.f, 0.f, 0.f };
#pragma unroll
    for (int i = 0; i < 4; ++i)
#pragma unroll
        for (int j = 0; j < 4; ++j) acc[i][j] = zero;

    for (int k0 = 0; k0 < Kd; k0 += 32) {
        __syncthreads();
        glds16(pA0 + k0, lA0);
        glds16(pA1 + k0, lA1);
        glds16(pB0 + k0, lB0);
        glds16(pB1 + k0, lB1);
        __syncthreads();

        bf16x8 af[4], bfr[4];
#pragma unroll
        for (int i = 0; i < 4; ++i)
            af[i] = *(const bf16x8*)(const void*)(&As[(wr + i * 16 + fr) * 32 + kq]);
#pragma unroll
        for (int j = 0; j < 4; ++j)
            bfr[j] = *(const bf16x8*)(const void*)(&Bs[(wc + j * 16 + fr) * 32 + kq]);
#pragma unroll
        for (int i = 0; i < 4; ++i)
#pragma unroll
            for (int j = 0; j < 4; ++j)
                acc[i][j] = __builtin_amdgcn_mfma_f32_16x16x32_bf16(
                    af[i], bfr[j], acc[i][j], 0, 0, 0);
    }

    const int rbase = row0 + wr + ((lane >> 4) << 2);
    const int cbase = col0 + wc + (lane & 15);
#pragma unroll
    for (int i = 0; i < 4; ++i) {
#pragma unroll
        for (int r = 0; r < 4; ++r) {
            int row = rbase + i * 16 + r;
            if (row >= M) continue;
#pragma unroll
            for (int j = 0; j < 4; ++j) {
                int col = cbase + j * 16;
                if (col >= N) continue;
                float v = acc[i][j][r];
                if (bias)  v += bias[col];
                if (resid) v += resid[(size_t)row * ldr + col];
                if (relu)  v = fmaxf(v, 0.f);
                if (Cf) Cf[(size_t)row * ldc + col] = v;
                if (Cb) Cb[(size_t)row * ldc + col] = f2b(v);
            }
        }
    }
}

// ---------------------------------------------------------------------------
// fp32 tiled GEMM (VQ distance only): C[M,N] = A * Bw^T
// ---------------------------------------------------------------------------
__global__ __launch_bounds__(256) void gemm_kernel(
    const float* __restrict__ A, int lda,
    const float* __restrict__ Bw, int ldb,
    float* __restrict__ C, int ldc,
    int M, int N, int Kd)
{
    __shared__ float As[8][128];
    __shared__ float Bs[8][128];
    const int tid  = threadIdx.x;
    const int row0 = blockIdx.y * 128;
    const int col0 = blockIdx.x * 128;
    const int tx = tid & 15, ty = tid >> 4;
    const int lm = tid >> 1;
    const int lk = (tid & 1) * 4;

    float acc[8][8];
#pragma unroll
    for (int i = 0; i < 8; ++i)
#pragma unroll
        for (int j = 0; j < 8; ++j) acc[i][j] = 0.f;

    const int garow = row0 + lm;
    const int gbrow = col0 + lm;
    const float* Aptr = A + (size_t)garow * lda + lk;
    const float* Bptr = Bw + (size_t)gbrow * ldb + lk;

    for (int k0 = 0; k0 < Kd; k0 += 8) {
        float4 av = make_float4(0.f, 0.f, 0.f, 0.f);
        float4 bv = make_float4(0.f, 0.f, 0.f, 0.f);
        if (garow < M) av = *(const float4*)(Aptr + k0);
        if (gbrow < N) bv = *(const float4*)(Bptr + k0);
        As[lk + 0][lm] = av.x; As[lk + 1][lm] = av.y;
        As[lk + 2][lm] = av.z; As[lk + 3][lm] = av.w;
        Bs[lk + 0][lm] = bv.x; Bs[lk + 1][lm] = bv.y;
        Bs[lk + 2][lm] = bv.z; Bs[lk + 3][lm] = bv.w;
        __syncthreads();
#pragma unroll
        for (int kk = 0; kk < 8; ++kk) {
            float a[8], b[8];
#pragma unroll
            for (int i = 0; i < 8; ++i) a[i] = As[kk][ty * 8 + i];
#pragma unroll
            for (int j = 0; j < 8; ++j) b[j] = Bs[kk][tx * 8 + j];
#pragma unroll
            for (int i = 0; i < 8; ++i)
#pragma unroll
                for (int j = 0; j < 8; ++j)
                    acc[i][j] = fmaf(a[i], b[j], acc[i][j]);
        }
        __syncthreads();
    }

#pragma unroll
    for (int i = 0; i < 8; ++i) {
        int r = row0 + ty * 8 + i;
        if (r >= M) continue;
#pragma unroll
        for (int j = 0; j < 8; ++j) {
            int c = col0 + tx * 8 + j;
            if (c >= N) continue;
            C[(size_t)r * ldc + c] = acc[i][j];
        }
    }
}

// ---------------------------------------------------------------------------
// MFMA attention: one block = 32 q-rows x 1 head x 1 batch. bf16 Q/K/V in,
// bf16 O out. Full-row softmax (S <= 320). Scores fp32 in LDS, P bf16 in LDS.
// ---------------------------------------------------------------------------
#define SC_LD 324   // fp32 score row stride
#define P_LD  328   // bf16 P row stride
#define QK_LD 104   // bf16 Q/K/V tile row stride

__global__ __launch_bounds__(256) void attn_mfma_kernel(
    const unsigned short* __restrict__ Qp, int qld, int qoff,
    const unsigned short* __restrict__ Kp, int kld, int koff,
    const unsigned short* __restrict__ Vp, int vld, int voff,
    unsigned short* __restrict__ Op,
    int Sq, int Sk, float scale, int causal,
    const int* __restrict__ lab)
{
    const int qt = blockIdx.x, h = blockIdx.y, b = blockIdx.z;
    const int q0 = qt * 32;
    __shared__ __align__(16) unsigned short Qs[32 * QK_LD];
    __shared__ __align__(16) unsigned short KV[32 * QK_LD];
    __shared__ __align__(16) float Sc[32 * SC_LD];
    __shared__ __align__(16) unsigned short Pb[32 * P_LD];
    __shared__ float rinv[32];

    const int tid = threadIdx.x;
    const int wave = tid >> 6, lane = tid & 63;
    const int fr = lane & 15, quad = lane >> 4;
    const int nst = (Sk + 31) / 32;          // 32-row K/V staging tiles
    const int cmax = nst * 32;               // padded key count (<= 320)

    // ---- load Q tile (32 x 96) ----
    for (int e = tid; e < 384; e += 256) {
        int r = e / 12, c8 = (e % 12) * 8;
        int gq = q0 + r; if (gq >= Sq) gq = Sq - 1;
        us8 v = *(const us8*)(Qp + (size_t)(b * Sq + gq) * qld + qoff + h * HD + c8);
        *(us8*)(&Qs[r * QK_LD + c8]) = v;
    }

    // ---- phase 1: scores = Q K^T ----
    const int mi = wave & 1;                 // M-frag (rows mi*16..+15)
    const int sw = wave >> 1;                // 16-col subtile within staged 32
    for (int it = 0; it < nst; ++it) {
        int s0 = it * 32;
        __syncthreads();
        for (int e = tid; e < 384; e += 256) {
            int r = e / 12, c8 = (e % 12) * 8;
            int gk = s0 + r; if (gk >= Sk) gk = Sk - 1;
            us8 v = *(const us8*)(Kp + (size_t)(b * Sk + gk) * kld + koff + h * HD + c8);
            *(us8*)(&KV[r * QK_LD + c8]) = v;
        }
        __syncthreads();
        f32x4 acc = { 0.f, 0.f, 0.f, 0.f };
#pragma unroll
        for (int kk = 0; kk < 3; ++kk) {
            bf16x8 a = *(const bf16x8*)(const void*)(&Qs[(mi * 16 + fr) * QK_LD + kk * 32 + quad * 8]);
            bf16x8 bb = *(const bf16x8*)(const void*)(&KV[(sw * 16 + fr) * QK_LD + kk * 32 + quad * 8]);
            acc = __builtin_amdgcn_mfma_f32_16x16x32_bf16(a, bb, acc, 0, 0, 0);
        }
        float* dst = &Sc[(mi * 16 + quad * 4) * SC_LD + s0 + sw * 16 + fr];
#pragma unroll
        for (int r = 0; r < 4; ++r) dst[r * SC_LD] = acc[r];
    }
    __syncthreads();

    // ---- phase 2: masked softmax per row, P -> bf16 ----
    {
        const int r = tid >> 3, sub = tid & 7;
        const int gq = q0 + r;
        float mx = -3e38f;
        for (int c = sub; c < cmax; c += 8) {
            float v = Sc[r * SC_LD + c];
            bool ok = (c < Sk);
            if (causal && c > gq) ok = false;
            if (ok && lab && lab[b * Lz + c + 1] == 0) ok = false;
            v = ok ? v * scale : -3e38f;
            Sc[r * SC_LD + c] = v;
            mx = fmaxf(mx, v);
        }
#pragma unroll
        for (int off = 4; off > 0; off >>= 1) mx = fmaxf(mx, __shfl_xor(mx, off));
        float sum = 0.f;
        for (int c = sub; c < cmax; c += 8) {
            float p = __expf(Sc[r * SC_LD + c] - mx);
            sum += p;
            Pb[r * P_LD + c] = f2b(p);
        }
#pragma unroll
        for (int off = 4; off > 0; off >>= 1) sum += __shfl_xor(sum, off);
        if (sub == 0) rinv[r] = 1.f / sum;
    }

    // ---- phase 3: O = P V ----
    // wave tasks: M-frag mi, N-frags ni = (wave>>1)*3 + {0,1,2}  (96 = 6 frags)
    const int nbase = (wave >> 1) * 3;
    f32x4 oacc[3];
#pragma unroll
    for (int t = 0; t < 3; ++t) oacc[t] = (f32x4){ 0.f, 0.f, 0.f, 0.f };

    for (int it = 0; it < nst; ++it) {
        int s0 = it * 32;
        __syncthreads();
        for (int e = tid; e < 384; e += 256) {
            int r = e / 12, c8 = (e % 12) * 8;
            int gk = s0 + r; if (gk >= Sk) gk = Sk - 1;
            us8 v = *(const us8*)(Vp + (size_t)(b * Sk + gk) * vld + voff + h * HD + c8);
            *(us8*)(&KV[r * QK_LD + c8]) = v;
        }
        __syncthreads();
        bf16x8 a = *(const bf16x8*)(const void*)(&Pb[(mi * 16 + fr) * P_LD + s0 + quad * 8]);
#pragma unroll
        for (int t = 0; t < 3; ++t) {
            const int dcol = (nbase + t) * 16 + fr;
            bf16x8 bv;
#pragma unroll
            for (int j = 0; j < 8; ++j)
                bv[j] = (short)KV[(quad * 8 + j) * QK_LD + dcol];
            oacc[t] = __builtin_amdgcn_mfma_f32_16x16x32_bf16(a, bv, oacc[t], 0, 0, 0);
        }
    }

    // ---- store ----
#pragma unroll
    for (int t = 0; t < 3; ++t) {
#pragma unroll
        for (int r = 0; r < 4; ++r) {
            int lrow = mi * 16 + quad * 4 + r;
            int grow = q0 + lrow;
            if (grow >= Sq) continue;
            int col = h * HD + (nbase + t) * 16 + fr;
            Op[(size_t)(b * Sq + grow) * Dz + col] = f2b(oacc[t][r] * rinv[lrow]);
        }
    }
}

// ---------------------------------------------------------------------------
// LayerNorm over last dim (768); writes fp32 and optional bf16 copy.
// ---------------------------------------------------------------------------
__global__ __launch_bounds__(256) void ln_kernel(
    const float* __restrict__ X, float* __restrict__ Y,
    unsigned short* __restrict__ Ybf,
    const float* __restrict__ g, const float* __restrict__ bb)
{
    const int n = blockIdx.x;
    const int tid = threadIdx.x;
    const float* x = X + (size_t)n * Dz;
    float v0 = x[tid], v1 = x[tid + 256], v2 = x[tid + 512];
    float s = v0 + v1 + v2;
    float q = v0 * v0 + v1 * v1 + v2 * v2;
#pragma unroll
    for (int off = 32; off > 0; off >>= 1) {
        s += __shfl_down(s, off);
        q += __shfl_down(q, off);
    }
    __shared__ float sbuf[4], qbuf[4];
    __shared__ float mv[2];
    int wid = tid >> 6;
    if ((tid & 63) == 0) { sbuf[wid] = s; qbuf[wid] = q; }
    __syncthreads();
    if (tid == 0) {
        float ts = sbuf[0] + sbuf[1] + sbuf[2] + sbuf[3];
        float tq = qbuf[0] + qbuf[1] + qbuf[2] + qbuf[3];
        float mean = ts * (1.f / 768.f);
        float var = tq * (1.f / 768.f) - mean * mean;
        mv[0] = mean;
        mv[1] = rsqrtf(var + 1e-5f);
    }
    __syncthreads();
    float mean = mv[0], inv = mv[1];
    float* y = Y + (size_t)n * Dz;
    float r0 = (v0 - mean) * inv * g[tid]       + bb[tid];
    float r1 = (v1 - mean) * inv * g[tid + 256] + bb[tid + 256];
    float r2 = (v2 - mean) * inv * g[tid + 512] + bb[tid + 512];
    y[tid] = r0; y[tid + 256] = r1; y[tid + 512] = r2;
    if (Ybf) {
        unsigned short* yb = Ybf + (size_t)n * Dz;
        yb[tid] = f2b(r0); yb[tid + 256] = f2b(r1); yb[tid + 512] = f2b(r2);
    }
}

// ---------------------------------------------------------------------------
__global__ __launch_bounds__(256) void sumsq_kernel(
    const float* __restrict__ cb, float* __restrict__ out)
{
    const int c = blockIdx.x, tid = threadIdx.x;
    const float* x = cb + (size_t)c * Dz;
    float v0 = x[tid], v1 = x[tid + 256], v2 = x[tid + 512];
    float q = v0 * v0 + v1 * v1 + v2 * v2;
#pragma unroll
    for (int off = 32; off > 0; off >>= 1) q += __shfl_down(q, off);
    __shared__ float qbuf[4];
    int wid = tid >> 6;
    if ((tid & 63) == 0) qbuf[wid] = q;
    __syncthreads();
    if (tid == 0) out[c] = qbuf[0] + qbuf[1] + qbuf[2] + qbuf[3];
}

// ---------------------------------------------------------------------------
__global__ __launch_bounds__(256) void vq_post_kernel(
    const float* __restrict__ dots, const float* __restrict__ sumc2,
    const float* __restrict__ feats, const float* __restrict__ codebook,
    const float* __restrict__ emb, float* __restrict__ H,
    unsigned short* __restrict__ Hbf,
    float* __restrict__ loss)
{
    const int n = blockIdx.x, tid = threadIdx.x;
    float best = 3.4e38f; int bi = 0;
    for (int c = tid; c < Kc; c += 256) {
        float dct = sumc2[c] - 2.f * dots[(size_t)n * Kc + c];
        if (dct < best) { best = dct; bi = c; }
    }
#pragma unroll
    for (int off = 32; off > 0; off >>= 1) {
        float ov = __shfl_down(best, off);
        int   oi = __shfl_down(bi, off);
        if (ov < best || (ov == best && oi < bi)) { best = ov; bi = oi; }
    }
    __shared__ float vb[4]; __shared__ int ib[4];
    __shared__ int bidx;
    int wid = tid >> 6;
    if ((tid & 63) == 0) { vb[wid] = best; ib[wid] = bi; }
    __syncthreads();
    if (tid == 0) {
        float v = vb[0]; int i = ib[0];
        for (int w = 1; w < 4; ++w)
            if (vb[w] < v || (vb[w] == v && ib[w] < i)) { v = vb[w]; i = ib[w]; }
        bidx = i;
    }
    __syncthreads();
    const int c = bidx;
    float part = 0.f;
    for (int d = tid; d < Dz; d += 256) {
        float xv = feats[(size_t)n * Dz + d];
        float cv = codebook[(size_t)c * Dz + d];
        float df = cv - xv;
        part += df * df;
        float ev = emb[(size_t)c * Dz + d];
        H[(size_t)n * Dz + d] = ev;
        Hbf[(size_t)n * Dz + d] = f2b(ev);
    }
#pragma unroll
    for (int off = 32; off > 0; off >>= 1) part += __shfl_down(part, off);
    __shared__ float pb[4];
    if ((tid & 63) == 0) pb[wid] = part;
    __syncthreads();
    if (tid == 0) atomicAdd(loss, pb[0] + pb[1] + pb[2] + pb[3]);
}

// ---------------------------------------------------------------------------
__global__ __launch_bounds__(256) void dec_embed_kernel(
    const int* __restrict__ labels, const float* __restrict__ tok,
    float* __restrict__ Y, unsigned short* __restrict__ Ybf,
    float* __restrict__ tgt)
{
    const int t = blockIdx.x;
    const int b = t / Tz, pos = t % Tz;
    const int lab = labels[b * Lz + pos];
    const int tid = threadIdx.x;
    const float* src = tok + (size_t)lab * Dz;
    float* dst = Y + (size_t)t * Dz;
    unsigned short* dbf = Ybf + (size_t)t * Dz;
    float a = src[tid], b1 = src[tid + 256], c = src[tid + 512];
    dst[tid] = a; dst[tid + 256] = b1; dst[tid + 512] = c;
    dbf[tid] = f2b(a); dbf[tid + 256] = f2b(b1); dbf[tid + 512] = f2b(c);
    if (tid == 0) tgt[t] = (float)labels[b * Lz + pos + 1];
}

__global__ void zero_loss_kernel(float* loss) { *loss = 0.f; }

__global__ void finalize_kernel(const float* loss, float* out)
{
    out[0] = loss[0] * (0.25f / (float)(NTOK * Dz));
}

// ---------------------------------------------------------------------------
__global__ __launch_bounds__(256) void conv6_kernel(
    const float* p0, int n0, const float* p1, int n1,
    const float* p2, int n2, const float* p3, int n3,
    const float* p4, int n4, const float* p5, int n5,
    unsigned short* __restrict__ dst)
{
    const int total = n0 + n1 + n2 + n3 + n4 + n5;
    for (int i = blockIdx.x * blockDim.x + threadIdx.x; i < total;
         i += gridDim.x * blockDim.x) {
        int j = i; const float* p;
        if (j < n0) { p = p0; }
        else { j -= n0;
            if (j < n1) { p = p1; }
            else { j -= n1;
                if (j < n2) { p = p2; }
                else { j -= n2;
                    if (j < n3) { p = p3; }
                    else { j -= n3;
                        if (j < n4) { p = p4; }
                        else { j -= n4; p = p5; }
                    }
                }
            }
        }
        dst[i] = f2b(p[j]);
    }
}

// ---------------------------------------------------------------------------
extern "C" void kernel_launch(void* const* d_in, const int* in_sizes, int n_in,
                              void* d_out, int out_size, void* d_ws, size_t ws_size,
                              hipStream_t stream)
{
    bool sig = (n_in > 8 && in_sizes[8] == 9216);
    int I_eWqkv, I_ebqkv, I_eWo, I_ebo, I_eln1g, I_eln1b, I_eW1, I_eb1, I_eW2, I_eb2,
        I_eln2g, I_eln2b, I_sWqkv, I_sbqkv, I_sWo, I_sbo, I_cWqkv, I_cbqkv, I_cWo,
        I_cbo, I_dln1g, I_dln1b, I_dln2g, I_dln2b, I_dln3g, I_dln3b, I_dW1, I_db1,
        I_dW2, I_db2;
    if (sig) {
        I_eWqkv = 7; I_ebqkv = 8; I_eWo = 9; I_ebo = 10; I_eln1g = 11; I_eln1b = 12;
        I_eW1 = 13; I_eb1 = 14; I_eW2 = 15; I_eb2 = 16; I_eln2g = 17; I_eln2b = 18;
        I_sWqkv = 19; I_sbqkv = 20; I_sWo = 21; I_sbo = 22;
        I_cWqkv = 23; I_cbqkv = 24; I_cWo = 25; I_cbo = 26;
        I_dln1g = 27; I_dln1b = 28; I_dln2g = 29; I_dln2b = 30; I_dln3g = 31; I_dln3b = 32;
        I_dW1 = 33; I_db1 = 34; I_dW2 = 35; I_db2 = 36;
    } else {
        I_eWqkv = 7; I_sWqkv = 8; I_cWqkv = 9;
        I_ebqkv = 10; I_eWo = 11; I_ebo = 12; I_eln1g = 13; I_eln1b = 14;
        I_eW1 = 15; I_eb1 = 16; I_eW2 = 17; I_eb2 = 18; I_eln2g = 19; I_eln2b = 20;
        I_sbqkv = 21; I_sWo = 22; I_sbo = 23;
        I_cbqkv = 24; I_cWo = 25; I_cbo = 26;
        I_dln1g = 27; I_dln1b = 28; I_dln2g = 29; I_dln2b = 30; I_dln3g = 31; I_dln3b = 32;
        I_dW1 = 33; I_db1 = 34; I_dW2 = 35; I_db2 = 36;
    }

    const float* feats = (const float*)d_in[0];
    const int*   labels = (const int*)d_in[1];
    const float* cb    = (const float*)d_in[2];
    const float* emb   = (const float*)d_in[3];
    const float* tok   = (const float*)d_in[4];
    const float* fcW   = (const float*)d_in[5];
    const float* fcb   = (const float*)d_in[6];
    const float* eWqkv = (const float*)d_in[I_eWqkv];
    const float* ebqkv = (const float*)d_in[I_ebqkv];
    const float* eWo   = (const float*)d_in[I_eWo];
    const float* ebo   = (const float*)d_in[I_ebo];
    const float* eln1g = (const float*)d_in[I_eln1g];
    const float* eln1b = (const float*)d_in[I_eln1b];
    const float* eW1   = (const float*)d_in[I_eW1];
    const float* eb1   = (const float*)d_in[I_eb1];
    const float* eW2   = (const float*)d_in[I_eW2];
    const float* eb2   = (const float*)d_in[I_eb2];
    const float* eln2g = (const float*)d_in[I_eln2g];
    const float* eln2b = (const float*)d_in[I_eln2b];
    const float* sWqkv = (const float*)d_in[I_sWqkv];
    const float* sbqkv = (const float*)d_in[I_sbqkv];
    const float* sWo   = (const float*)d_in[I_sWo];
    const float* sbo   = (const float*)d_in[I_sbo];
    const float* cWqkv = (const float*)d_in[I_cWqkv];
    const float* cbqkv = (const float*)d_in[I_cbqkv];
    const float* cWo   = (const float*)d_in[I_cWo];
    const float* cbo   = (const float*)d_in[I_cbo];
    const float* dln1g = (const float*)d_in[I_dln1g];
    const float* dln1b = (const float*)d_in[I_dln1b];
    const float* dln2g = (const float*)d_in[I_dln2g];
    const float* dln2b = (const float*)d_in[I_dln2b];
    const float* dln3g = (const float*)d_in[I_dln3g];
    const float* dln3b = (const float*)d_in[I_dln3b];
    const float* dW1   = (const float*)d_in[I_dW1];
    const float* db1   = (const float*)d_in[I_db1];
    const float* dW2   = (const float*)d_in[I_dW2];
    const float* db2   = (const float*)d_in[I_db2];

    // ---- workspace layout ----
    float* ws    = (float*)d_ws;
    float* sumc2 = ws;                       // 512
    float* loss  = ws + 512;                 // 1
    float* Hb    = ws + 1024;                // 4800*768
    float* T1    = ws + 3687424;             // 4800*768
    float* dots  = ws + 7373824;             // 4800*512
    // decoder fp32 aliases inside T1
    float* Yb    = T1;                       // 784*768
    float* T1d   = T1 + 602112;              // 784*768

    unsigned short* bfbase = (unsigned short*)(ws + 9831424);
    unsigned short* Hb_bf  = bfbase;                     // 3,686,400
    unsigned short* ATT_bf = bfbase + 3686400;           // 3,686,400
    unsigned short* FF_bf  = bfbase + 7372800;           // 7,372,800
    unsigned short* Yb_bf  = bfbase + 14745600;          // 602,112
    unsigned short* Wbuf   = bfbase + 15347712;          // 7,077,888
    unsigned short* QKV_bf = bfbase + 22425600;          // 11,059,200 (enc QKV)
    // decoder aliases inside QKV_bf
    unsigned short* QKVd_bf = QKV_bf;                    // 784*2304
    unsigned short* Qc_bf   = QKV_bf + 1806336;          // 784*768
    unsigned short* CKV_bf  = QKV_bf + 2408448;          // 4800*1536

    float* outF = (float*)d_out;

    auto gemmb = [&](const unsigned short* A, const unsigned short* W,
                     float* Cf, unsigned short* Cb, int ldc,
                     const float* bias, const float* resid, int ldr,
                     int relu, int M, int N, int Kd) {
        dim3 g((N + 127) / 128, (M + 127) / 128);
        gemm_bf16_kernel<<<g, 256, 0, stream>>>(A, W, Cf, Cb, ldc, bias, resid, ldr,
                                                relu, M, N, Kd);
    };

    const float scale = 0.1020620726159658f; // 1/sqrt(96)
    const float* Z = nullptr;

    // --- VQ stage (fp32; argmin must not see bf16 rounding) ---
    zero_loss_kernel<<<1, 1, 0, stream>>>(loss);
    sumsq_kernel<<<Kc, 256, 0, stream>>>(cb, sumc2);
    {
        dim3 g(4, 38);
        gemm_kernel<<<g, 256, 0, stream>>>(feats, Dz, cb, Dz, dots, Kc, NTOK, Kc, Dz);
    }
    vq_post_kernel<<<NTOK, 256, 0, stream>>>(dots, sumc2, feats, cb, emb, Hb, Hb_bf, loss);
    finalize_kernel<<<1, 1, 0, stream>>>(loss, outF + 3920000);

    // --- Encoder ---
    const int W_QKV = 2304 * 768, W_O = 768 * 768, W_F1 = 1536 * 768, W_F2 = 768 * 1536;
    for (int i = 0; i < 4; ++i) {
        conv6_kernel<<<1024, 256, 0, stream>>>(
            eWqkv + (size_t)i * W_QKV, W_QKV,
            eWo   + (size_t)i * W_O,   W_O,
            eW1   + (size_t)i * W_F1,  W_F1,
            eW2   + (size_t)i * W_F2,  W_F2,
            Z, 0, Z, 0, Wbuf);
        unsigned short* bWqkv = Wbuf;
        unsigned short* bWo   = Wbuf + W_QKV;
        unsigned short* bW1   = Wbuf + W_QKV + W_O;
        unsigned short* bW2   = Wbuf + W_QKV + W_O + W_F1;

        gemmb(Hb_bf, bWqkv, nullptr, QKV_bf, 2304, ebqkv + i * 2304, Z, 0, 0, NTOK, 2304, Dz);
        attn_mfma_kernel<<<dim3(10, Hh, Bz), 256, 0, stream>>>(
            QKV_bf, 2304, 0, QKV_bf, 2304, 768, QKV_bf, 2304, 1536, ATT_bf,
            Sz, Sz, scale, 0, nullptr);
        gemmb(ATT_bf, bWo, T1, nullptr, Dz, ebo + i * Dz, Hb, Dz, 0, NTOK, Dz, Dz);
        ln_kernel<<<NTOK, 256, 0, stream>>>(T1, Hb, Hb_bf, eln1g + i * Dz, eln1b + i * Dz);
        gemmb(Hb_bf, bW1, nullptr, FF_bf, 1536, eb1 + i * 1536, Z, 0, 1, NTOK, 1536, Dz);
        gemmb(FF_bf, bW2, T1, nullptr, Dz, eb2 + i * Dz, Hb, Dz, 0, NTOK, Dz, 1536);
        ln_kernel<<<NTOK, 256, 0, stream>>>(T1, Hb, Hb_bf, eln2g + i * Dz, eln2b + i * Dz);
    }
    // Hb/Hb_bf hold memory

    // --- Decoder ---
    dec_embed_kernel<<<NDTOK, 256, 0, stream>>>(labels, tok, Yb, Yb_bf, outF + 3920001);
    for (int i = 0; i < 4; ++i) {
        conv6_kernel<<<1024, 256, 0, stream>>>(
            sWqkv + (size_t)i * W_QKV, W_QKV,
            sWo   + (size_t)i * W_O,   W_O,
            cWqkv + (size_t)i * W_QKV, W_QKV,
            cWo   + (size_t)i * W_O,   W_O,
            dW1   + (size_t)i * W_F1,  W_F1,
            dW2   + (size_t)i * W_F2,  W_F2, Wbuf);
        unsigned short* bsWqkv = Wbuf;
        unsigned short* bsWo   = Wbuf + W_QKV;
        unsigned short* bcWqkv = Wbuf + W_QKV + W_O;
        unsigned short* bcWo   = Wbuf + 2 * W_QKV + W_O;
        unsigned short* bW1    = Wbuf + 2 * W_QKV + 2 * W_O;
        unsigned short* bW2    = Wbuf + 2 * W_QKV + 2 * W_O + W_F1;

        // self-attention (causal + key-padding)
        gemmb(Yb_bf, bsWqkv, nullptr, QKVd_bf, 2304, sbqkv + i * 2304, Z, 0, 0, NDTOK, 2304, Dz);
        attn_mfma_kernel<<<dim3(2, Hh, Bz), 256, 0, stream>>>(
            QKVd_bf, 2304, 0, QKVd_bf, 2304, 768, QKVd_bf, 2304, 1536, ATT_bf,
            Tz, Tz, scale, 1, labels);
        gemmb(ATT_bf, bsWo, T1d, nullptr, Dz, sbo + i * Dz, Yb, Dz, 0, NDTOK, Dz, Dz);
        ln_kernel<<<NDTOK, 256, 0, stream>>>(T1d, Yb, Yb_bf, dln1g + i * Dz, dln1b + i * Dz);
        // cross-attention
        gemmb(Yb_bf, bcWqkv, nullptr, Qc_bf, Dz, cbqkv + i * 2304, Z, 0, 0, NDTOK, Dz, Dz);
        gemmb(Hb_bf, bcWqkv + (size_t)768 * 768, nullptr, CKV_bf, 1536,
              cbqkv + i * 2304 + 768, Z, 0, 0, NTOK, 1536, Dz);
        attn_mfma_kernel<<<dim3(2, Hh, Bz), 256, 0, stream>>>(
            Qc_bf, 768, 0, CKV_bf, 1536, 0, CKV_bf, 1536, 768, ATT_bf,
            Tz, Sz, scale, 0, nullptr);
        gemmb(ATT_bf, bcWo, T1d, nullptr, Dz, cbo + i * Dz, Yb, Dz, 0, NDTOK, Dz, Dz);
        ln_kernel<<<NDTOK, 256, 0, stream>>>(T1d, Yb, Yb_bf, dln2g + i * Dz, dln2b + i * Dz);
        // feed-forward
        gemmb(Yb_bf, bW1, nullptr, FF_bf, 1536, db1 + i * 1536, Z, 0, 1, NDTOK, 1536, Dz);
        gemmb(FF_bf, bW2, T1d, nullptr, Dz, db2 + i * Dz, Yb, Dz, 0, NDTOK, Dz, 1536);
        ln_kernel<<<NDTOK, 256, 0, stream>>>(T1d, Yb, Yb_bf, dln3g + i * Dz, dln3b + i * Dz);
    }

    // --- Final FC ---
    conv6_kernel<<<1024, 256, 0, stream>>>(fcW, Vz * Dz, Z, 0, Z, 0, Z, 0, Z, 0, Z, 0, Wbuf);
    gemmb(Yb_bf, Wbuf, outF, nullptr, Vz, fcb, Z, 0, 0, NDTOK, Vz, Dz);
}

// Round 4
// 2485.844 us; speedup vs baseline: 3.7032x; 1.2540x over previous
//
#include <hip/hip_runtime.h>
#include <hip/hip_bf16.h>

// Problem constants
#define Bz   16
#define Sz   300
#define Dz   768
#define Kc   512
#define Vz   5000
#define Hh   8
#define HD   96
#define Lz   50
#define Tz   49          // L-1
#define NTOK 4800        // B*S
#define NDTOK 784        // B*T

typedef short bf16x8 __attribute__((ext_vector_type(8)));
typedef float f32x4  __attribute__((ext_vector_type(4)));
typedef unsigned short us8 __attribute__((ext_vector_type(8)));

// RNE float->bf16 (finite inputs)
__device__ __forceinline__ unsigned short f2b(float f) {
    unsigned u = __float_as_uint(f);
    unsigned r = (u + 0x7fffu + ((u >> 16) & 1u)) >> 16;
    return (unsigned short)r;
}

__device__ __forceinline__ void glds16(const unsigned short* g, unsigned short* l) {
    __builtin_amdgcn_global_load_lds(
        (const __attribute__((address_space(1))) void*)g,
        (__attribute__((address_space(3))) void*)l, 16, 0, 0);
}

// ---------------------------------------------------------------------------
// bf16 MFMA GEMM, 128x128 tile, BK=32 (m97 structure): C = A * W^T
// ---------------------------------------------------------------------------
__global__ __launch_bounds__(256) void gemm_bf16_kernel(
    const unsigned short* __restrict__ A,   // [M x Kd]
    const unsigned short* __restrict__ Bw,  // [N x Kd]
    float* __restrict__ Cf,                 // fp32 out (or null)
    unsigned short* __restrict__ Cb,        // bf16 out (or null)
    int ldc,
    const float* __restrict__ bias,
    const float* __restrict__ resid, int ldr,
    int relu, int M, int N, int Kd)
{
    __shared__ unsigned short As[128 * 32];
    __shared__ unsigned short Bs[128 * 32];
    const int tid  = threadIdx.x;
    const int wave = tid >> 6, lane = tid & 63;
    const int row0 = blockIdx.y * 128, col0 = blockIdx.x * 128;

    const int c0 = wave * 2;
    const int srow = lane >> 2;
    const int skcol = (lane & 3) * 8;
    int rA0 = row0 + c0 * 16 + srow;        if (rA0 > M - 1) rA0 = M - 1;
    int rA1 = row0 + (c0 + 1) * 16 + srow;  if (rA1 > M - 1) rA1 = M - 1;
    int rB0 = col0 + c0 * 16 + srow;        if (rB0 > N - 1) rB0 = N - 1;
    int rB1 = col0 + (c0 + 1) * 16 + srow;  if (rB1 > N - 1) rB1 = N - 1;
    const unsigned short* pA0 = A + (size_t)rA0 * Kd + skcol;
    const unsigned short* pA1 = A + (size_t)rA1 * Kd + skcol;
    const unsigned short* pB0 = Bw + (size_t)rB0 * Kd + skcol;
    const unsigned short* pB1 = Bw + (size_t)rB1 * Kd + skcol;
    unsigned short* lA0 = &As[c0 * 512];
    unsigned short* lA1 = &As[(c0 + 1) * 512];
    unsigned short* lB0 = &Bs[c0 * 512];
    unsigned short* lB1 = &Bs[(c0 + 1) * 512];

    const int wr = (wave >> 1) * 64, wc = (wave & 1) * 64;
    const int fr = lane & 15;
    const int kq = (lane >> 4) * 8;

    f32x4 acc[4][4];
    const f32x4 zero = { 0.f, 0.f, 0.f, 0.f };
#pragma unroll
    for (int i = 0; i < 4; ++i)
#pragma unroll
        for (int j = 0; j < 4; ++j) acc[i][j] = zero;

    for (int k0 = 0; k0 < Kd; k0 += 32) {
        __syncthreads();
        glds16(pA0 + k0, lA0);
        glds16(pA1 + k0, lA1);
        glds16(pB0 + k0, lB0);
        glds16(pB1 + k0, lB1);
        __syncthreads();

        bf16x8 af[4], bfr[4];
#pragma unroll
        for (int i = 0; i < 4; ++i)
            af[i] = *(const bf16x8*)(const void*)(&As[(wr + i * 16 + fr) * 32 + kq]);
#pragma unroll
        for (int j = 0; j < 4; ++j)
            bfr[j] = *(const bf16x8*)(const void*)(&Bs[(wc + j * 16 + fr) * 32 + kq]);
#pragma unroll
        for (int i = 0; i < 4; ++i)
#pragma unroll
            for (int j = 0; j < 4; ++j)
                acc[i][j] = __builtin_amdgcn_mfma_f32_16x16x32_bf16(
                    af[i], bfr[j], acc[i][j], 0, 0, 0);
    }

    const int rbase = row0 + wr + ((lane >> 4) << 2);
    const int cbase = col0 + wc + (lane & 15);
#pragma unroll
    for (int i = 0; i < 4; ++i) {
#pragma unroll
        for (int r = 0; r < 4; ++r) {
            int row = rbase + i * 16 + r;
            if (row >= M) continue;
#pragma unroll
            for (int j = 0; j < 4; ++j) {
                int col = cbase + j * 16;
                if (col >= N) continue;
                float v = acc[i][j][r];
                if (bias)  v += bias[col];
                if (resid) v += resid[(size_t)row * ldr + col];
                if (relu)  v = fmaxf(v, 0.f);
                if (Cf) Cf[(size_t)row * ldc + col] = v;
                if (Cb) Cb[(size_t)row * ldc + col] = f2b(v);
            }
        }
    }
}

// ---------------------------------------------------------------------------
// bf16 MFMA GEMM, 64x64 tile, BK=32 — for small-M (decoder) matrices.
// wave w: rows w*16..w*16+15 of the tile, all 4 col-frags.
// ---------------------------------------------------------------------------
__global__ __launch_bounds__(256) void gemm_bf16_64_kernel(
    const unsigned short* __restrict__ A,
    const unsigned short* __restrict__ Bw,
    float* __restrict__ Cf, unsigned short* __restrict__ Cb, int ldc,
    const float* __restrict__ bias,
    const float* __restrict__ resid, int ldr,
    int relu, int M, int N, int Kd)
{
    __shared__ unsigned short As[64 * 32];
    __shared__ unsigned short Bs[64 * 32];
    const int tid = threadIdx.x, wave = tid >> 6, lane = tid & 63;
    const int row0 = blockIdx.y * 64, col0 = blockIdx.x * 64;
    const int fr = lane & 15, quad = lane >> 4;

    // staging: wave w covers rows [w*16, w*16+16) x 32 cols of each tile
    const int sr = lane >> 2;          // 0..15
    const int sc = (lane & 3) * 8;     // 0..24
    int ra = row0 + wave * 16 + sr;  if (ra > M - 1) ra = M - 1;
    int rb = col0 + wave * 16 + sr;  if (rb > N - 1) rb = N - 1;
    const unsigned short* pA = A + (size_t)ra * Kd + sc;
    const unsigned short* pB = Bw + (size_t)rb * Kd + sc;
    unsigned short* lA = &As[wave * 512];
    unsigned short* lB = &Bs[wave * 512];

    f32x4 acc[4];
    const f32x4 zero = { 0.f, 0.f, 0.f, 0.f };
#pragma unroll
    for (int j = 0; j < 4; ++j) acc[j] = zero;

    for (int k0 = 0; k0 < Kd; k0 += 32) {
        __syncthreads();
        glds16(pA + k0, lA);
        glds16(pB + k0, lB);
        __syncthreads();
        bf16x8 a = *(const bf16x8*)(const void*)(&As[(wave * 16 + fr) * 32 + quad * 8]);
#pragma unroll
        for (int j = 0; j < 4; ++j) {
            bf16x8 b = *(const bf16x8*)(const void*)(&Bs[(j * 16 + fr) * 32 + quad * 8]);
            acc[j] = __builtin_amdgcn_mfma_f32_16x16x32_bf16(a, b, acc[j], 0, 0, 0);
        }
    }

    const int rbase = row0 + wave * 16 + quad * 4;
    const int cbase = col0 + fr;
#pragma unroll
    for (int r = 0; r < 4; ++r) {
        int row = rbase + r;
        if (row >= M) continue;
#pragma unroll
        for (int j = 0; j < 4; ++j) {
            int col = cbase + j * 16;
            if (col >= N) continue;
            float v = acc[j][r];
            if (bias)  v += bias[col];
            if (resid) v += resid[(size_t)row * ldr + col];
            if (relu)  v = fmaxf(v, 0.f);
            if (Cf) Cf[(size_t)row * ldc + col] = v;
            if (Cb) Cb[(size_t)row * ldc + col] = f2b(v);
        }
    }
}

// ---------------------------------------------------------------------------
// fp32 VQ distance GEMM: dots[4800 x 512] = feats * codebook^T.
// 64x64 tiles, BK=16 -> 600 blocks. Dims divide exactly; no edge code.
// ---------------------------------------------------------------------------
__global__ __launch_bounds__(256) void vq_gemm_kernel(
    const float* __restrict__ A,   // [4800 x 768]
    const float* __restrict__ Bw,  // [512 x 768]
    float* __restrict__ C)         // [4800 x 512]
{
    __shared__ float As[16][64];
    __shared__ float Bs[16][64];
    const int tid = threadIdx.x;
    const int row0 = blockIdx.y * 64, col0 = blockIdx.x * 64;
    const int tx = tid & 15, ty = tid >> 4;
    const int lm = tid >> 2, lk = (tid & 3) * 4;

    float acc[4][4];
#pragma unroll
    for (int i = 0; i < 4; ++i)
#pragma unroll
        for (int j = 0; j < 4; ++j) acc[i][j] = 0.f;

    const float* Ap = A + (size_t)(row0 + lm) * Dz + lk;
    const float* Bp = Bw + (size_t)(col0 + lm) * Dz + lk;

    for (int k0 = 0; k0 < Dz; k0 += 16) {
        float4 av = *(const float4*)(Ap + k0);
        float4 bv = *(const float4*)(Bp + k0);
        __syncthreads();
        As[lk + 0][lm] = av.x; As[lk + 1][lm] = av.y;
        As[lk + 2][lm] = av.z; As[lk + 3][lm] = av.w;
        Bs[lk + 0][lm] = bv.x; Bs[lk + 1][lm] = bv.y;
        Bs[lk + 2][lm] = bv.z; Bs[lk + 3][lm] = bv.w;
        __syncthreads();
#pragma unroll
        for (int kk = 0; kk < 16; ++kk) {
            float4 a4 = *(const float4*)&As[kk][ty * 4];
            float4 b4 = *(const float4*)&Bs[kk][tx * 4];
            float a[4] = { a4.x, a4.y, a4.z, a4.w };
            float b[4] = { b4.x, b4.y, b4.z, b4.w };
#pragma unroll
            for (int i = 0; i < 4; ++i)
#pragma unroll
                for (int j = 0; j < 4; ++j)
                    acc[i][j] = fmaf(a[i], b[j], acc[i][j]);
        }
    }

#pragma unroll
    for (int i = 0; i < 4; ++i)
#pragma unroll
        for (int j = 0; j < 4; ++j)
            C[(size_t)(row0 + ty * 4 + i) * Kc + col0 + tx * 4 + j] = acc[i][j];
}

// ---------------------------------------------------------------------------
// MFMA attention: one block = 32 q-rows x 1 head x 1 batch. bf16 in/out.
// Full-row softmax. Phase 3 stages V transposed (XOR-swizzled) for b128 reads.
// ---------------------------------------------------------------------------
#define SC_LD 324   // fp32 score row stride
#define P_LD  328   // bf16 P row stride
#define QK_LD 104   // bf16 Q/K tile row stride
#define VT_LD 40    // bf16 V^T row stride (96 rows x 40)

__global__ __launch_bounds__(256) void attn_mfma_kernel(
    const unsigned short* __restrict__ Qp, int qld, int qoff,
    const unsigned short* __restrict__ Kp, int kld, int koff,
    const unsigned short* __restrict__ Vp, int vld, int voff,
    unsigned short* __restrict__ Op,
    int Sq, int Sk, float scale, int causal,
    const int* __restrict__ lab)
{
    const int qt = blockIdx.x, h = blockIdx.y, b = blockIdx.z;
    const int q0 = qt * 32;
    __shared__ __align__(16) unsigned short Qs[32 * QK_LD];
    __shared__ __align__(16) unsigned short KVu[96 * VT_LD];  // >= 32*QK_LD too
    __shared__ __align__(16) float Sc[32 * SC_LD];
    __shared__ __align__(16) unsigned short Pb[32 * P_LD];
    __shared__ float rinv[32];

    const int tid = threadIdx.x;
    const int wave = tid >> 6, lane = tid & 63;
    const int fr = lane & 15, quad = lane >> 4;
    const int nst = (Sk + 31) / 32;
    const int cmax = nst * 32;

    // ---- load Q tile (32 x 96) ----
    for (int e = tid; e < 384; e += 256) {
        int r = e / 12, c8 = (e % 12) * 8;
        int gq = q0 + r; if (gq >= Sq) gq = Sq - 1;
        us8 v = *(const us8*)(Qp + (size_t)(b * Sq + gq) * qld + qoff + h * HD + c8);
        *(us8*)(&Qs[r * QK_LD + c8]) = v;
    }

    // ---- phase 1: scores = Q K^T ----
    const int mi = wave & 1;
    const int sw = wave >> 1;
    for (int it = 0; it < nst; ++it) {
        int s0 = it * 32;
        __syncthreads();
        for (int e = tid; e < 384; e += 256) {
            int r = e / 12, c8 = (e % 12) * 8;
            int gk = s0 + r; if (gk >= Sk) gk = Sk - 1;
            us8 v = *(const us8*)(Kp + (size_t)(b * Sk + gk) * kld + koff + h * HD + c8);
            *(us8*)(&KVu[r * QK_LD + c8]) = v;
        }
        __syncthreads();
        f32x4 acc = { 0.f, 0.f, 0.f, 0.f };
#pragma unroll
        for (int kk = 0; kk < 3; ++kk) {
            bf16x8 a = *(const bf16x8*)(const void*)(&Qs[(mi * 16 + fr) * QK_LD + kk * 32 + quad * 8]);
            bf16x8 bb = *(const bf16x8*)(const void*)(&KVu[(sw * 16 + fr) * QK_LD + kk * 32 + quad * 8]);
            acc = __builtin_amdgcn_mfma_f32_16x16x32_bf16(a, bb, acc, 0, 0, 0);
        }
        float* dst = &Sc[(mi * 16 + quad * 4) * SC_LD + s0 + sw * 16 + fr];
#pragma unroll
        for (int r = 0; r < 4; ++r) dst[r * SC_LD] = acc[r];
    }
    __syncthreads();

    // ---- phase 2: masked softmax per row, P -> bf16 ----
    {
        const int r = tid >> 3, sub = tid & 7;
        const int gq = q0 + r;
        float mx = -3e38f;
        for (int c = sub; c < cmax; c += 8) {
            float v = Sc[r * SC_LD + c];
            bool ok = (c < Sk);
            if (causal && c > gq) ok = false;
            if (ok && lab && lab[b * Lz + c + 1] == 0) ok = false;
            v = ok ? v * scale : -3e38f;
            Sc[r * SC_LD + c] = v;
            mx = fmaxf(mx, v);
        }
#pragma unroll
        for (int off = 4; off > 0; off >>= 1) mx = fmaxf(mx, __shfl_xor(mx, off));
        float sum = 0.f;
        for (int c = sub; c < cmax; c += 8) {
            float p = __expf(Sc[r * SC_LD + c] - mx);
            sum += p;
            Pb[r * P_LD + c] = f2b(p);
        }
#pragma unroll
        for (int off = 4; off > 0; off >>= 1) sum += __shfl_xor(sum, off);
        if (sub == 0) rinv[r] = 1.f / sum;
    }

    // ---- phase 3: O = P V  (V staged transposed, XOR-swizzled) ----
    const int nbase = (wave >> 1) * 3;
    f32x4 oacc[3];
#pragma unroll
    for (int t = 0; t < 3; ++t) oacc[t] = (f32x4){ 0.f, 0.f, 0.f, 0.f };

    for (int it = 0; it < nst; ++it) {
        int s0 = it * 32;
        __syncthreads();
        for (int e = tid; e < 384; e += 256) {
            int r = e / 12, c8 = (e % 12) * 8;
            int gk = s0 + r; if (gk >= Sk) gk = Sk - 1;
            us8 v = *(const us8*)(Vp + (size_t)(b * Sk + gk) * vld + voff + h * HD + c8);
            const int f = ((c8 >> 3) & 3) << 3;      // const per thread (c8 mult of 8)
            const int rx = r ^ f;
#pragma unroll
            for (int j = 0; j < 8; ++j)
                KVu[(c8 + j) * VT_LD + rx] = v[j];   // VT[col][row^f(col)]
        }
        __syncthreads();
        bf16x8 a = *(const bf16x8*)(const void*)(&Pb[(mi * 16 + fr) * P_LD + s0 + quad * 8]);
#pragma unroll
        for (int t = 0; t < 3; ++t) {
            const int dcol = (nbase + t) * 16 + fr;
            const int f2 = ((dcol >> 3) & 3) << 3;
            bf16x8 bv = *(const bf16x8*)(const void*)(&KVu[dcol * VT_LD + ((quad * 8) ^ f2)]);
            oacc[t] = __builtin_amdgcn_mfma_f32_16x16x32_bf16(a, bv, oacc[t], 0, 0, 0);
        }
    }

    // ---- store ----
#pragma unroll
    for (int t = 0; t < 3; ++t) {
#pragma unroll
        for (int r = 0; r < 4; ++r) {
            int lrow = mi * 16 + quad * 4 + r;
            int grow = q0 + lrow;
            if (grow >= Sq) continue;
            int col = h * HD + (nbase + t) * 16 + fr;
            Op[(size_t)(b * Sq + grow) * Dz + col] = f2b(oacc[t][r] * rinv[lrow]);
        }
    }
}

// ---------------------------------------------------------------------------
// LayerNorm over last dim (768); writes fp32 and optional bf16 copy.
// ---------------------------------------------------------------------------
__global__ __launch_bounds__(256) void ln_kernel(
    const float* __restrict__ X, float* __restrict__ Y,
    unsigned short* __restrict__ Ybf,
    const float* __restrict__ g, const float* __restrict__ bb)
{
    const int n = blockIdx.x;
    const int tid = threadIdx.x;
    const float* x = X + (size_t)n * Dz;
    float v0 = x[tid], v1 = x[tid + 256], v2 = x[tid + 512];
    float s = v0 + v1 + v2;
    float q = v0 * v0 + v1 * v1 + v2 * v2;
#pragma unroll
    for (int off = 32; off > 0; off >>= 1) {
        s += __shfl_down(s, off);
        q += __shfl_down(q, off);
    }
    __shared__ float sbuf[4], qbuf[4];
    __shared__ float mv[2];
    int wid = tid >> 6;
    if ((tid & 63) == 0) { sbuf[wid] = s; qbuf[wid] = q; }
    __syncthreads();
    if (tid == 0) {
        float ts = sbuf[0] + sbuf[1] + sbuf[2] + sbuf[3];
        float tq = qbuf[0] + qbuf[1] + qbuf[2] + qbuf[3];
        float mean = ts * (1.f / 768.f);
        float var = tq * (1.f / 768.f) - mean * mean;
        mv[0] = mean;
        mv[1] = rsqrtf(var + 1e-5f);
    }
    __syncthreads();
    float mean = mv[0], inv = mv[1];
    float* y = Y + (size_t)n * Dz;
    float r0 = (v0 - mean) * inv * g[tid]       + bb[tid];
    float r1 = (v1 - mean) * inv * g[tid + 256] + bb[tid + 256];
    float r2 = (v2 - mean) * inv * g[tid + 512] + bb[tid + 512];
    y[tid] = r0; y[tid + 256] = r1; y[tid + 512] = r2;
    if (Ybf) {
        unsigned short* yb = Ybf + (size_t)n * Dz;
        yb[tid] = f2b(r0); yb[tid + 256] = f2b(r1); yb[tid + 512] = f2b(r2);
    }
}

// ---------------------------------------------------------------------------
__global__ __launch_bounds__(256) void sumsq_kernel(
    const float* __restrict__ cb, float* __restrict__ out)
{
    const int c = blockIdx.x, tid = threadIdx.x;
    const float* x = cb + (size_t)c * Dz;
    float v0 = x[tid], v1 = x[tid + 256], v2 = x[tid + 512];
    float q = v0 * v0 + v1 * v1 + v2 * v2;
#pragma unroll
    for (int off = 32; off > 0; off >>= 1) q += __shfl_down(q, off);
    __shared__ float qbuf[4];
    int wid = tid >> 6;
    if ((tid & 63) == 0) qbuf[wid] = q;
    __syncthreads();
    if (tid == 0) out[c] = qbuf[0] + qbuf[1] + qbuf[2] + qbuf[3];
}

// ---------------------------------------------------------------------------
__global__ __launch_bounds__(256) void vq_post_kernel(
    const float* __restrict__ dots, const float* __restrict__ sumc2,
    const float* __restrict__ feats, const float* __restrict__ codebook,
    const float* __restrict__ emb, float* __restrict__ H,
    unsigned short* __restrict__ Hbf,
    float* __restrict__ loss)
{
    const int n = blockIdx.x, tid = threadIdx.x;
    float best = 3.4e38f; int bi = 0;
    for (int c = tid; c < Kc; c += 256) {
        float dct = sumc2[c] - 2.f * dots[(size_t)n * Kc + c];
        if (dct < best) { best = dct; bi = c; }
    }
#pragma unroll
    for (int off = 32; off > 0; off >>= 1) {
        float ov = __shfl_down(best, off);
        int   oi = __shfl_down(bi, off);
        if (ov < best || (ov == best && oi < bi)) { best = ov; bi = oi; }
    }
    __shared__ float vb[4]; __shared__ int ib[4];
    __shared__ int bidx;
    int wid = tid >> 6;
    if ((tid & 63) == 0) { vb[wid] = best; ib[wid] = bi; }
    __syncthreads();
    if (tid == 0) {
        float v = vb[0]; int i = ib[0];
        for (int w = 1; w < 4; ++w)
            if (vb[w] < v || (vb[w] == v && ib[w] < i)) { v = vb[w]; i = ib[w]; }
        bidx = i;
    }
    __syncthreads();
    const int c = bidx;
    float part = 0.f;
    for (int d = tid; d < Dz; d += 256) {
        float xv = feats[(size_t)n * Dz + d];
        float cv = codebook[(size_t)c * Dz + d];
        float df = cv - xv;
        part += df * df;
        float ev = emb[(size_t)c * Dz + d];
        H[(size_t)n * Dz + d] = ev;
        Hbf[(size_t)n * Dz + d] = f2b(ev);
    }
#pragma unroll
    for (int off = 32; off > 0; off >>= 1) part += __shfl_down(part, off);
    __shared__ float pb[4];
    if ((tid & 63) == 0) pb[wid] = part;
    __syncthreads();
    if (tid == 0) atomicAdd(loss, pb[0] + pb[1] + pb[2] + pb[3]);
}

// ---------------------------------------------------------------------------
__global__ __launch_bounds__(256) void dec_embed_kernel(
    const int* __restrict__ labels, const float* __restrict__ tok,
    float* __restrict__ Y, unsigned short* __restrict__ Ybf,
    float* __restrict__ tgt)
{
    const int t = blockIdx.x;
    const int b = t / Tz, pos = t % Tz;
    const int lab = labels[b * Lz + pos];
    const int tid = threadIdx.x;
    const float* src = tok + (size_t)lab * Dz;
    float* dst = Y + (size_t)t * Dz;
    unsigned short* dbf = Ybf + (size_t)t * Dz;
    float a = src[tid], b1 = src[tid + 256], c = src[tid + 512];
    dst[tid] = a; dst[tid + 256] = b1; dst[tid + 512] = c;
    dbf[tid] = f2b(a); dbf[tid + 256] = f2b(b1); dbf[tid + 512] = f2b(c);
    if (tid == 0) tgt[t] = (float)labels[b * Lz + pos + 1];
}

__global__ void zero_loss_kernel(float* loss) { *loss = 0.f; }

__global__ void finalize_kernel(const float* loss, float* out)
{
    out[0] = loss[0] * (0.25f / (float)(NTOK * Dz));
}

// ---------------------------------------------------------------------------
__global__ __launch_bounds__(256) void conv6_kernel(
    const float* p0, int n0, const float* p1, int n1,
    const float* p2, int n2, const float* p3, int n3,
    const float* p4, int n4, const float* p5, int n5,
    unsigned short* __restrict__ dst)
{
    const int total = n0 + n1 + n2 + n3 + n4 + n5;
    for (int i = blockIdx.x * blockDim.x + threadIdx.x; i < total;
         i += gridDim.x * blockDim.x) {
        int j = i; const float* p;
        if (j < n0) { p = p0; }
        else { j -= n0;
            if (j < n1) { p = p1; }
            else { j -= n1;
                if (j < n2) { p = p2; }
                else { j -= n2;
                    if (j < n3) { p = p3; }
                    else { j -= n3;
                        if (j < n4) { p = p4; }
                        else { j -= n4; p = p5; }
                    }
                }
            }
        }
        dst[i] = f2b(p[j]);
    }
}

// ---------------------------------------------------------------------------
extern "C" void kernel_launch(void* const* d_in, const int* in_sizes, int n_in,
                              void* d_out, int out_size, void* d_ws, size_t ws_size,
                              hipStream_t stream)
{
    bool sig = (n_in > 8 && in_sizes[8] == 9216);
    int I_eWqkv, I_ebqkv, I_eWo, I_ebo, I_eln1g, I_eln1b, I_eW1, I_eb1, I_eW2, I_eb2,
        I_eln2g, I_eln2b, I_sWqkv, I_sbqkv, I_sWo, I_sbo, I_cWqkv, I_cbqkv, I_cWo,
        I_cbo, I_dln1g, I_dln1b, I_dln2g, I_dln2b, I_dln3g, I_dln3b, I_dW1, I_db1,
        I_dW2, I_db2;
    if (sig) {
        I_eWqkv = 7; I_ebqkv = 8; I_eWo = 9; I_ebo = 10; I_eln1g = 11; I_eln1b = 12;
        I_eW1 = 13; I_eb1 = 14; I_eW2 = 15; I_eb2 = 16; I_eln2g = 17; I_eln2b = 18;
        I_sWqkv = 19; I_sbqkv = 20; I_sWo = 21; I_sbo = 22;
        I_cWqkv = 23; I_cbqkv = 24; I_cWo = 25; I_cbo = 26;
        I_dln1g = 27; I_dln1b = 28; I_dln2g = 29; I_dln2b = 30; I_dln3g = 31; I_dln3b = 32;
        I_dW1 = 33; I_db1 = 34; I_dW2 = 35; I_db2 = 36;
    } else {
        I_eWqkv = 7; I_sWqkv = 8; I_cWqkv = 9;
        I_ebqkv = 10; I_eWo = 11; I_ebo = 12; I_eln1g = 13; I_eln1b = 14;
        I_eW1 = 15; I_eb1 = 16; I_eW2 = 17; I_eb2 = 18; I_eln2g = 19; I_eln2b = 20;
        I_sbqkv = 21; I_sWo = 22; I_sbo = 23;
        I_cbqkv = 24; I_cWo = 25; I_cbo = 26;
        I_dln1g = 27; I_dln1b = 28; I_dln2g = 29; I_dln2b = 30; I_dln3g = 31; I_dln3b = 32;
        I_dW1 = 33; I_db1 = 34; I_dW2 = 35; I_db2 = 36;
    }

    const float* feats = (const float*)d_in[0];
    const int*   labels = (const int*)d_in[1];
    const float* cb    = (const float*)d_in[2];
    const float* emb   = (const float*)d_in[3];
    const float* tok   = (const float*)d_in[4];
    const float* fcW   = (const float*)d_in[5];
    const float* fcb   = (const float*)d_in[6];
    const float* eWqkv = (const float*)d_in[I_eWqkv];
    const float* ebqkv = (const float*)d_in[I_ebqkv];
    const float* eWo   = (const float*)d_in[I_eWo];
    const float* ebo   = (const float*)d_in[I_ebo];
    const float* eln1g = (const float*)d_in[I_eln1g];
    const float* eln1b = (const float*)d_in[I_eln1b];
    const float* eW1   = (const float*)d_in[I_eW1];
    const float* eb1   = (const float*)d_in[I_eb1];
    const float* eW2   = (const float*)d_in[I_eW2];
    const float* eb2   = (const float*)d_in[I_eb2];
    const float* eln2g = (const float*)d_in[I_eln2g];
    const float* eln2b = (const float*)d_in[I_eln2b];
    const float* sWqkv = (const float*)d_in[I_sWqkv];
    const float* sbqkv = (const float*)d_in[I_sbqkv];
    const float* sWo   = (const float*)d_in[I_sWo];
    const float* sbo   = (const float*)d_in[I_sbo];
    const float* cWqkv = (const float*)d_in[I_cWqkv];
    const float* cbqkv = (const float*)d_in[I_cbqkv];
    const float* cWo   = (const float*)d_in[I_cWo];
    const float* cbo   = (const float*)d_in[I_cbo];
    const float* dln1g = (const float*)d_in[I_dln1g];
    const float* dln1b = (const float*)d_in[I_dln1b];
    const float* dln2g = (const float*)d_in[I_dln2g];
    const float* dln2b = (const float*)d_in[I_dln2b];
    const float* dln3g = (const float*)d_in[I_dln3g];
    const float* dln3b = (const float*)d_in[I_dln3b];
    const float* dW1   = (const float*)d_in[I_dW1];
    const float* db1   = (const float*)d_in[I_db1];
    const float* dW2   = (const float*)d_in[I_dW2];
    const float* db2   = (const float*)d_in[I_db2];

    // ---- workspace layout ----
    float* ws    = (float*)d_ws;
    float* sumc2 = ws;                       // 512
    float* loss  = ws + 512;                 // 1
    float* Hb    = ws + 1024;                // 4800*768
    float* T1    = ws + 3687424;             // 4800*768
    float* dots  = ws + 7373824;             // 4800*512
    float* Yb    = T1;                       // 784*768
    float* T1d   = T1 + 602112;              // 784*768

    unsigned short* bfbase = (unsigned short*)(ws + 9831424);
    unsigned short* Hb_bf  = bfbase;                     // 3,686,400
    unsigned short* ATT_bf = bfbase + 3686400;           // 3,686,400
    unsigned short* FF_bf  = bfbase + 7372800;           // 7,372,800
    unsigned short* Yb_bf  = bfbase + 14745600;          // 602,112
    unsigned short* Wbuf   = bfbase + 15347712;          // 7,077,888
    unsigned short* QKV_bf = bfbase + 22425600;          // 11,059,200
    unsigned short* QKVd_bf = QKV_bf;                    // 784*2304
    unsigned short* Qc_bf   = QKV_bf + 1806336;          // 784*768
    unsigned short* CKV_bf  = QKV_bf + 2408448;          // 4800*1536

    float* outF = (float*)d_out;

    auto gemmb = [&](const unsigned short* A, const unsigned short* W,
                     float* Cf, unsigned short* Cb, int ldc,
                     const float* bias, const float* resid, int ldr,
                     int relu, int M, int N, int Kd) {
        dim3 g((N + 127) / 128, (M + 127) / 128);
        gemm_bf16_kernel<<<g, 256, 0, stream>>>(A, W, Cf, Cb, ldc, bias, resid, ldr,
                                                relu, M, N, Kd);
    };
    auto gemmb64 = [&](const unsigned short* A, const unsigned short* W,
                       float* Cf, unsigned short* Cb, int ldc,
                       const float* bias, const float* resid, int ldr,
                       int relu, int M, int N, int Kd) {
        dim3 g((N + 63) / 64, (M + 63) / 64);
        gemm_bf16_64_kernel<<<g, 256, 0, stream>>>(A, W, Cf, Cb, ldc, bias, resid, ldr,
                                                   relu, M, N, Kd);
    };

    const float scale = 0.1020620726159658f; // 1/sqrt(96)
    const float* Z = nullptr;

    // --- VQ stage (fp32; argmin must not see bf16 rounding) ---
    zero_loss_kernel<<<1, 1, 0, stream>>>(loss);
    sumsq_kernel<<<Kc, 256, 0, stream>>>(cb, sumc2);
    vq_gemm_kernel<<<dim3(8, 75), 256, 0, stream>>>(feats, cb, dots);
    vq_post_kernel<<<NTOK, 256, 0, stream>>>(dots, sumc2, feats, cb, emb, Hb, Hb_bf, loss);
    finalize_kernel<<<1, 1, 0, stream>>>(loss, outF + 3920000);

    // --- Encoder ---
    const int W_QKV = 2304 * 768, W_O = 768 * 768, W_F1 = 1536 * 768, W_F2 = 768 * 1536;
    for (int i = 0; i < 4; ++i) {
        conv6_kernel<<<1024, 256, 0, stream>>>(
            eWqkv + (size_t)i * W_QKV, W_QKV,
            eWo   + (size_t)i * W_O,   W_O,
            eW1   + (size_t)i * W_F1,  W_F1,
            eW2   + (size_t)i * W_F2,  W_F2,
            Z, 0, Z, 0, Wbuf);
        unsigned short* bWqkv = Wbuf;
        unsigned short* bWo   = Wbuf + W_QKV;
        unsigned short* bW1   = Wbuf + W_QKV + W_O;
        unsigned short* bW2   = Wbuf + W_QKV + W_O + W_F1;

        gemmb(Hb_bf, bWqkv, nullptr, QKV_bf, 2304, ebqkv + i * 2304, Z, 0, 0, NTOK, 2304, Dz);
        attn_mfma_kernel<<<dim3(10, Hh, Bz), 256, 0, stream>>>(
            QKV_bf, 2304, 0, QKV_bf, 2304, 768, QKV_bf, 2304, 1536, ATT_bf,
            Sz, Sz, scale, 0, nullptr);
        gemmb(ATT_bf, bWo, T1, nullptr, Dz, ebo + i * Dz, Hb, Dz, 0, NTOK, Dz, Dz);
        ln_kernel<<<NTOK, 256, 0, stream>>>(T1, Hb, Hb_bf, eln1g + i * Dz, eln1b + i * Dz);
        gemmb(Hb_bf, bW1, nullptr, FF_bf, 1536, eb1 + i * 1536, Z, 0, 1, NTOK, 1536, Dz);
        gemmb(FF_bf, bW2, T1, nullptr, Dz, eb2 + i * Dz, Hb, Dz, 0, NTOK, Dz, 1536);
        ln_kernel<<<NTOK, 256, 0, stream>>>(T1, Hb, Hb_bf, eln2g + i * Dz, eln2b + i * Dz);
    }

    // --- Decoder ---
    dec_embed_kernel<<<NDTOK, 256, 0, stream>>>(labels, tok, Yb, Yb_bf, outF + 3920001);
    for (int i = 0; i < 4; ++i) {
        conv6_kernel<<<1024, 256, 0, stream>>>(
            sWqkv + (size_t)i * W_QKV, W_QKV,
            sWo   + (size_t)i * W_O,   W_O,
            cWqkv + (size_t)i * W_QKV, W_QKV,
            cWo   + (size_t)i * W_O,   W_O,
            dW1   + (size_t)i * W_F1,  W_F1,
            dW2   + (size_t)i * W_F2,  W_F2, Wbuf);
        unsigned short* bsWqkv = Wbuf;
        unsigned short* bsWo   = Wbuf + W_QKV;
        unsigned short* bcWqkv = Wbuf + W_QKV + W_O;
        unsigned short* bcWo   = Wbuf + 2 * W_QKV + W_O;
        unsigned short* bW1    = Wbuf + 2 * W_QKV + 2 * W_O;
        unsigned short* bW2    = Wbuf + 2 * W_QKV + 2 * W_O + W_F1;

        // self-attention (causal + key-padding)
        gemmb64(Yb_bf, bsWqkv, nullptr, QKVd_bf, 2304, sbqkv + i * 2304, Z, 0, 0, NDTOK, 2304, Dz);
        attn_mfma_kernel<<<dim3(2, Hh, Bz), 256, 0, stream>>>(
            QKVd_bf, 2304, 0, QKVd_bf, 2304, 768, QKVd_bf, 2304, 1536, ATT_bf,
            Tz, Tz, scale, 1, labels);
        gemmb64(ATT_bf, bsWo, T1d, nullptr, Dz, sbo + i * Dz, Yb, Dz, 0, NDTOK, Dz, Dz);
        ln_kernel<<<NDTOK, 256, 0, stream>>>(T1d, Yb, Yb_bf, dln1g + i * Dz, dln1b + i * Dz);
        // cross-attention
        gemmb64(Yb_bf, bcWqkv, nullptr, Qc_bf, Dz, cbqkv + i * 2304, Z, 0, 0, NDTOK, Dz, Dz);
        gemmb(Hb_bf, bcWqkv + (size_t)768 * 768, nullptr, CKV_bf, 1536,
              cbqkv + i * 2304 + 768, Z, 0, 0, NTOK, 1536, Dz);
        attn_mfma_kernel<<<dim3(2, Hh, Bz), 256, 0, stream>>>(
            Qc_bf, 768, 0, CKV_bf, 1536, 0, CKV_bf, 1536, 768, ATT_bf,
            Tz, Sz, scale, 0, nullptr);
        gemmb64(ATT_bf, bcWo, T1d, nullptr, Dz, cbo + i * Dz, Yb, Dz, 0, NDTOK, Dz, Dz);
        ln_kernel<<<NDTOK, 256, 0, stream>>>(T1d, Yb, Yb_bf, dln2g + i * Dz, dln2b + i * Dz);
        // feed-forward
        gemmb64(Yb_bf, bW1, nullptr, FF_bf, 1536, db1 + i * 1536, Z, 0, 1, NDTOK, 1536, Dz);
        gemmb64(FF_bf, bW2, T1d, nullptr, Dz, db2 + i * Dz, Yb, Dz, 0, NDTOK, Dz, 1536);
        ln_kernel<<<NDTOK, 256, 0, stream>>>(T1d, Yb, Yb_bf, dln3g + i * Dz, dln3b + i * Dz);
    }

    // --- Final FC ---
    conv6_kernel<<<1024, 256, 0, stream>>>(fcW, Vz * Dz, Z, 0, Z, 0, Z, 0, Z, 0, Z, 0, Wbuf);
    gemmb64(Yb_bf, Wbuf, outF, nullptr, Vz, fcb, Z, 0, 0, NDTOK, Vz, Dz);
}

// Round 5
// 2341.319 us; speedup vs baseline: 3.9318x; 1.0617x over previous
//
#include <hip/hip_runtime.h>
#include <hip/hip_bf16.h>

// Problem constants
#define Bz   16
#define Sz   300
#define Dz   768
#define Kc   512
#define Vz   5000
#define Hh   8
#define HD   96
#define Lz   50
#define Tz   49          // L-1
#define NTOK 4800        // B*S
#define NDTOK 784        // B*T

typedef short bf16x8 __attribute__((ext_vector_type(8)));
typedef float f32x4  __attribute__((ext_vector_type(4)));
typedef unsigned short us8 __attribute__((ext_vector_type(8)));

// RNE float->bf16 (finite inputs)
__device__ __forceinline__ unsigned short f2b(float f) {
    unsigned u = __float_as_uint(f);
    unsigned r = (u + 0x7fffu + ((u >> 16) & 1u)) >> 16;
    return (unsigned short)r;
}
__device__ __forceinline__ float b2f(unsigned short h) {
    return __uint_as_float(((unsigned)h) << 16);
}

__device__ __forceinline__ void glds16(const unsigned short* g, unsigned short* l) {
    __builtin_amdgcn_global_load_lds(
        (const __attribute__((address_space(1))) void*)g,
        (__attribute__((address_space(3))) void*)l, 16, 0, 0);
}

// ---------------------------------------------------------------------------
// bf16 MFMA GEMM, 128x128 tile, BK=32 (m97 structure): C = A * W^T
// ---------------------------------------------------------------------------
__global__ __launch_bounds__(256) void gemm_bf16_kernel(
    const unsigned short* __restrict__ A,   // [M x Kd]
    const unsigned short* __restrict__ Bw,  // [N x Kd]
    float* __restrict__ Cf,                 // fp32 out (or null)
    unsigned short* __restrict__ Cb,        // bf16 out (or null)
    int ldc,
    const float* __restrict__ bias,
    const float* __restrict__ resid, int ldr,
    int relu, int M, int N, int Kd)
{
    __shared__ unsigned short As[128 * 32];
    __shared__ unsigned short Bs[128 * 32];
    const int tid  = threadIdx.x;
    const int wave = tid >> 6, lane = tid & 63;
    const int row0 = blockIdx.y * 128, col0 = blockIdx.x * 128;

    const int c0 = wave * 2;
    const int srow = lane >> 2;
    const int skcol = (lane & 3) * 8;
    int rA0 = row0 + c0 * 16 + srow;        if (rA0 > M - 1) rA0 = M - 1;
    int rA1 = row0 + (c0 + 1) * 16 + srow;  if (rA1 > M - 1) rA1 = M - 1;
    int rB0 = col0 + c0 * 16 + srow;        if (rB0 > N - 1) rB0 = N - 1;
    int rB1 = col0 + (c0 + 1) * 16 + srow;  if (rB1 > N - 1) rB1 = N - 1;
    const unsigned short* pA0 = A + (size_t)rA0 * Kd + skcol;
    const unsigned short* pA1 = A + (size_t)rA1 * Kd + skcol;
    const unsigned short* pB0 = Bw + (size_t)rB0 * Kd + skcol;
    const unsigned short* pB1 = Bw + (size_t)rB1 * Kd + skcol;
    unsigned short* lA0 = &As[c0 * 512];
    unsigned short* lA1 = &As[(c0 + 1) * 512];
    unsigned short* lB0 = &Bs[c0 * 512];
    unsigned short* lB1 = &Bs[(c0 + 1) * 512];

    const int wr = (wave >> 1) * 64, wc = (wave & 1) * 64;
    const int fr = lane & 15;
    const int kq = (lane >> 4) * 8;

    f32x4 acc[4][4];
    const f32x4 zero = { 0.f, 0.f, 0.f, 0.f };
#pragma unroll
    for (int i = 0; i < 4; ++i)
#pragma unroll
        for (int j = 0; j < 4; ++j) acc[i][j] = zero;

    for (int k0 = 0; k0 < Kd; k0 += 32) {
        __syncthreads();
        glds16(pA0 + k0, lA0);
        glds16(pA1 + k0, lA1);
        glds16(pB0 + k0, lB0);
        glds16(pB1 + k0, lB1);
        __syncthreads();

        bf16x8 af[4], bfr[4];
#pragma unroll
        for (int i = 0; i < 4; ++i)
            af[i] = *(const bf16x8*)(const void*)(&As[(wr + i * 16 + fr) * 32 + kq]);
#pragma unroll
        for (int j = 0; j < 4; ++j)
            bfr[j] = *(const bf16x8*)(const void*)(&Bs[(wc + j * 16 + fr) * 32 + kq]);
#pragma unroll
        for (int i = 0; i < 4; ++i)
#pragma unroll
            for (int j = 0; j < 4; ++j)
                acc[i][j] = __builtin_amdgcn_mfma_f32_16x16x32_bf16(
                    af[i], bfr[j], acc[i][j], 0, 0, 0);
    }

    const int rbase = row0 + wr + ((lane >> 4) << 2);
    const int cbase = col0 + wc + (lane & 15);
#pragma unroll
    for (int i = 0; i < 4; ++i) {
#pragma unroll
        for (int r = 0; r < 4; ++r) {
            int row = rbase + i * 16 + r;
            if (row >= M) continue;
#pragma unroll
            for (int j = 0; j < 4; ++j) {
                int col = cbase + j * 16;
                if (col >= N) continue;
                float v = acc[i][j][r];
                if (bias)  v += bias[col];
                if (resid) v += resid[(size_t)row * ldr + col];
                if (relu)  v = fmaxf(v, 0.f);
                if (Cf) Cf[(size_t)row * ldc + col] = v;
                if (Cb) Cb[(size_t)row * ldc + col] = f2b(v);
            }
        }
    }
}

// ---------------------------------------------------------------------------
// bf16 MFMA GEMM, 32x64 tile, BK=32 — max occupancy for small-M matrices.
// Waves 0/1 stage A (16 rows each); waves 2/3 stage B (2x16 rows each).
// Wave w computes frag (m = w&1, n-group = w>>1, 2 col-frags).
// ---------------------------------------------------------------------------
__global__ __launch_bounds__(256) void gemm_bf16_32_kernel(
    const unsigned short* __restrict__ A,
    const unsigned short* __restrict__ Bw,
    float* __restrict__ Cf, unsigned short* __restrict__ Cb, int ldc,
    const float* __restrict__ bias,
    const float* __restrict__ resid, int ldr,
    int relu, int M, int N, int Kd)
{
    __shared__ unsigned short As[32 * 32];
    __shared__ unsigned short Bs[64 * 32];
    const int tid = threadIdx.x, wave = tid >> 6, lane = tid & 63;
    const int row0 = blockIdx.y * 32, col0 = blockIdx.x * 64;
    const int fr = lane & 15, quad = lane >> 4;
    const int sr = lane >> 2;          // 0..15
    const int sc = (lane & 3) * 8;

    const unsigned short* pA = nullptr;
    const unsigned short* pB0 = nullptr;
    const unsigned short* pB1 = nullptr;
    unsigned short* lA = nullptr;
    unsigned short* lB0 = nullptr;
    unsigned short* lB1 = nullptr;
    if (wave < 2) {
        int ra = row0 + wave * 16 + sr; if (ra > M - 1) ra = M - 1;
        pA = A + (size_t)ra * Kd + sc;
        lA = &As[wave * 512];
    } else {
        int w2 = wave - 2;
        int rb0 = col0 + w2 * 16 + sr;       if (rb0 > N - 1) rb0 = N - 1;
        int rb1 = col0 + 32 + w2 * 16 + sr;  if (rb1 > N - 1) rb1 = N - 1;
        pB0 = Bw + (size_t)rb0 * Kd + sc;
        pB1 = Bw + (size_t)rb1 * Kd + sc;
        lB0 = &Bs[w2 * 512];
        lB1 = &Bs[1024 + w2 * 512];
    }

    f32x4 acc[2];
    acc[0] = (f32x4){ 0.f, 0.f, 0.f, 0.f };
    acc[1] = (f32x4){ 0.f, 0.f, 0.f, 0.f };

    const int mrow = (wave & 1) * 16 + fr;
    const int ng = (wave >> 1) * 32;

    for (int k0 = 0; k0 < Kd; k0 += 32) {
        __syncthreads();
        if (wave < 2) {
            glds16(pA + k0, lA);
        } else {
            glds16(pB0 + k0, lB0);
            glds16(pB1 + k0, lB1);
        }
        __syncthreads();
        bf16x8 a = *(const bf16x8*)(const void*)(&As[mrow * 32 + quad * 8]);
#pragma unroll
        for (int t = 0; t < 2; ++t) {
            bf16x8 b = *(const bf16x8*)(const void*)(&Bs[(ng + t * 16 + fr) * 32 + quad * 8]);
            acc[t] = __builtin_amdgcn_mfma_f32_16x16x32_bf16(a, b, acc[t], 0, 0, 0);
        }
    }

    const int rbase = row0 + (wave & 1) * 16 + quad * 4;
    const int cbase = col0 + ng + fr;
#pragma unroll
    for (int r = 0; r < 4; ++r) {
        int row = rbase + r;
        if (row >= M) continue;
#pragma unroll
        for (int t = 0; t < 2; ++t) {
            int col = cbase + t * 16;
            if (col >= N) continue;
            float v = acc[t][r];
            if (bias)  v += bias[col];
            if (resid) v += resid[(size_t)row * ldr + col];
            if (relu)  v = fmaxf(v, 0.f);
            if (Cf) Cf[(size_t)row * ldc + col] = v;
            if (Cb) Cb[(size_t)row * ldc + col] = f2b(v);
        }
    }
}

// ---------------------------------------------------------------------------
// VQ split: x -> (hi, lo) bf16, written K-concatenated.
// pattern 0 (A): [hi | hi | lo]   pattern 1 (B): [hi | lo | hi]
// ---------------------------------------------------------------------------
__global__ __launch_bounds__(256) void vq_split_kernel(
    const float* __restrict__ src, unsigned short* __restrict__ dst,
    int nrows, int pattern)
{
    int i = blockIdx.x * 256 + threadIdx.x;
    if (i >= nrows * Dz) return;
    int r = i / Dz, c = i % Dz;
    float x = src[i];
    unsigned short h = f2b(x);
    unsigned short l = f2b(x - b2f(h));
    unsigned short* d = dst + (size_t)r * 2304 + c;
    if (pattern == 0) { d[0] = h; d[768] = h; d[1536] = l; }
    else              { d[0] = h; d[768] = l; d[1536] = h; }
}

// ---------------------------------------------------------------------------
// MFMA attention: one block = 32 q-rows x 1 head x 1 batch. bf16 in/out.
// Full-row softmax. Phase 3 stages V transposed (XOR-swizzled) for b128 reads.
// ---------------------------------------------------------------------------
#define SC_LD 324   // fp32 score row stride
#define P_LD  328   // bf16 P row stride
#define QK_LD 104   // bf16 Q/K tile row stride
#define VT_LD 40    // bf16 V^T row stride (96 rows x 40)

__global__ __launch_bounds__(256) void attn_mfma_kernel(
    const unsigned short* __restrict__ Qp, int qld, int qoff,
    const unsigned short* __restrict__ Kp, int kld, int koff,
    const unsigned short* __restrict__ Vp, int vld, int voff,
    unsigned short* __restrict__ Op,
    int Sq, int Sk, float scale, int causal,
    const int* __restrict__ lab)
{
    const int qt = blockIdx.x, h = blockIdx.y, b = blockIdx.z;
    const int q0 = qt * 32;
    __shared__ __align__(16) unsigned short Qs[32 * QK_LD];
    __shared__ __align__(16) unsigned short KVu[96 * VT_LD];
    __shared__ __align__(16) float Sc[32 * SC_LD];
    __shared__ __align__(16) unsigned short Pb[32 * P_LD];
    __shared__ float rinv[32];

    const int tid = threadIdx.x;
    const int wave = tid >> 6, lane = tid & 63;
    const int fr = lane & 15, quad = lane >> 4;
    const int nst = (Sk + 31) / 32;
    const int cmax = nst * 32;

    for (int e = tid; e < 384; e += 256) {
        int r = e / 12, c8 = (e % 12) * 8;
        int gq = q0 + r; if (gq >= Sq) gq = Sq - 1;
        us8 v = *(const us8*)(Qp + (size_t)(b * Sq + gq) * qld + qoff + h * HD + c8);
        *(us8*)(&Qs[r * QK_LD + c8]) = v;
    }

    const int mi = wave & 1;
    const int sw = wave >> 1;
    for (int it = 0; it < nst; ++it) {
        int s0 = it * 32;
        __syncthreads();
        for (int e = tid; e < 384; e += 256) {
            int r = e / 12, c8 = (e % 12) * 8;
            int gk = s0 + r; if (gk >= Sk) gk = Sk - 1;
            us8 v = *(const us8*)(Kp + (size_t)(b * Sk + gk) * kld + koff + h * HD + c8);
            *(us8*)(&KVu[r * QK_LD + c8]) = v;
        }
        __syncthreads();
        f32x4 acc = { 0.f, 0.f, 0.f, 0.f };
#pragma unroll
        for (int kk = 0; kk < 3; ++kk) {
            bf16x8 a = *(const bf16x8*)(const void*)(&Qs[(mi * 16 + fr) * QK_LD + kk * 32 + quad * 8]);
            bf16x8 bb = *(const bf16x8*)(const void*)(&KVu[(sw * 16 + fr) * QK_LD + kk * 32 + quad * 8]);
            acc = __builtin_amdgcn_mfma_f32_16x16x32_bf16(a, bb, acc, 0, 0, 0);
        }
        float* dst = &Sc[(mi * 16 + quad * 4) * SC_LD + s0 + sw * 16 + fr];
#pragma unroll
        for (int r = 0; r < 4; ++r) dst[r * SC_LD] = acc[r];
    }
    __syncthreads();

    {
        const int r = tid >> 3, sub = tid & 7;
        const int gq = q0 + r;
        float mx = -3e38f;
        for (int c = sub; c < cmax; c += 8) {
            float v = Sc[r * SC_LD + c];
            bool ok = (c < Sk);
            if (causal && c > gq) ok = false;
            if (ok && lab && lab[b * Lz + c + 1] == 0) ok = false;
            v = ok ? v * scale : -3e38f;
            Sc[r * SC_LD + c] = v;
            mx = fmaxf(mx, v);
        }
#pragma unroll
        for (int off = 4; off > 0; off >>= 1) mx = fmaxf(mx, __shfl_xor(mx, off));
        float sum = 0.f;
        for (int c = sub; c < cmax; c += 8) {
            float p = __expf(Sc[r * SC_LD + c] - mx);
            sum += p;
            Pb[r * P_LD + c] = f2b(p);
        }
#pragma unroll
        for (int off = 4; off > 0; off >>= 1) sum += __shfl_xor(sum, off);
        if (sub == 0) rinv[r] = 1.f / sum;
    }

    const int nbase = (wave >> 1) * 3;
    f32x4 oacc[3];
#pragma unroll
    for (int t = 0; t < 3; ++t) oacc[t] = (f32x4){ 0.f, 0.f, 0.f, 0.f };

    for (int it = 0; it < nst; ++it) {
        int s0 = it * 32;
        __syncthreads();
        for (int e = tid; e < 384; e += 256) {
            int r = e / 12, c8 = (e % 12) * 8;
            int gk = s0 + r; if (gk >= Sk) gk = Sk - 1;
            us8 v = *(const us8*)(Vp + (size_t)(b * Sk + gk) * vld + voff + h * HD + c8);
            const int f = ((c8 >> 3) & 3) << 3;
            const int rx = r ^ f;
#pragma unroll
            for (int j = 0; j < 8; ++j)
                KVu[(c8 + j) * VT_LD + rx] = v[j];
        }
        __syncthreads();
        bf16x8 a = *(const bf16x8*)(const void*)(&Pb[(mi * 16 + fr) * P_LD + s0 + quad * 8]);
#pragma unroll
        for (int t = 0; t < 3; ++t) {
            const int dcol = (nbase + t) * 16 + fr;
            const int f2 = ((dcol >> 3) & 3) << 3;
            bf16x8 bv = *(const bf16x8*)(const void*)(&KVu[dcol * VT_LD + ((quad * 8) ^ f2)]);
            oacc[t] = __builtin_amdgcn_mfma_f32_16x16x32_bf16(a, bv, oacc[t], 0, 0, 0);
        }
    }

#pragma unroll
    for (int t = 0; t < 3; ++t) {
#pragma unroll
        for (int r = 0; r < 4; ++r) {
            int lrow = mi * 16 + quad * 4 + r;
            int grow = q0 + lrow;
            if (grow >= Sq) continue;
            int col = h * HD + (nbase + t) * 16 + fr;
            Op[(size_t)(b * Sq + grow) * Dz + col] = f2b(oacc[t][r] * rinv[lrow]);
        }
    }
}

// ---------------------------------------------------------------------------
// LayerNorm over last dim (768); writes fp32 and optional bf16 copy.
// ---------------------------------------------------------------------------
__global__ __launch_bounds__(256) void ln_kernel(
    const float* __restrict__ X, float* __restrict__ Y,
    unsigned short* __restrict__ Ybf,
    const float* __restrict__ g, const float* __restrict__ bb)
{
    const int n = blockIdx.x;
    const int tid = threadIdx.x;
    const float* x = X + (size_t)n * Dz;
    float v0 = x[tid], v1 = x[tid + 256], v2 = x[tid + 512];
    float s = v0 + v1 + v2;
    float q = v0 * v0 + v1 * v1 + v2 * v2;
#pragma unroll
    for (int off = 32; off > 0; off >>= 1) {
        s += __shfl_down(s, off);
        q += __shfl_down(q, off);
    }
    __shared__ float sbuf[4], qbuf[4];
    __shared__ float mv[2];
    int wid = tid >> 6;
    if ((tid & 63) == 0) { sbuf[wid] = s; qbuf[wid] = q; }
    __syncthreads();
    if (tid == 0) {
        float ts = sbuf[0] + sbuf[1] + sbuf[2] + sbuf[3];
        float tq = qbuf[0] + qbuf[1] + qbuf[2] + qbuf[3];
        float mean = ts * (1.f / 768.f);
        float var = tq * (1.f / 768.f) - mean * mean;
        mv[0] = mean;
        mv[1] = rsqrtf(var + 1e-5f);
    }
    __syncthreads();
    float mean = mv[0], inv = mv[1];
    float* y = Y + (size_t)n * Dz;
    float r0 = (v0 - mean) * inv * g[tid]       + bb[tid];
    float r1 = (v1 - mean) * inv * g[tid + 256] + bb[tid + 256];
    float r2 = (v2 - mean) * inv * g[tid + 512] + bb[tid + 512];
    y[tid] = r0; y[tid + 256] = r1; y[tid + 512] = r2;
    if (Ybf) {
        unsigned short* yb = Ybf + (size_t)n * Dz;
        yb[tid] = f2b(r0); yb[tid + 256] = f2b(r1); yb[tid + 512] = f2b(r2);
    }
}

// ---------------------------------------------------------------------------
// Codebook row sum of squares; block 0 also zeroes the loss accumulator.
// ---------------------------------------------------------------------------
__global__ __launch_bounds__(256) void sumsq_kernel(
    const float* __restrict__ cb, float* __restrict__ out, float* __restrict__ loss)
{
    const int c = blockIdx.x, tid = threadIdx.x;
    if (c == 0 && tid == 0) *loss = 0.f;
    const float* x = cb + (size_t)c * Dz;
    float v0 = x[tid], v1 = x[tid + 256], v2 = x[tid + 512];
    float q = v0 * v0 + v1 * v1 + v2 * v2;
#pragma unroll
    for (int off = 32; off > 0; off >>= 1) q += __shfl_down(q, off);
    __shared__ float qbuf[4];
    int wid = tid >> 6;
    if ((tid & 63) == 0) qbuf[wid] = q;
    __syncthreads();
    if (tid == 0) out[c] = qbuf[0] + qbuf[1] + qbuf[2] + qbuf[3];
}

// ---------------------------------------------------------------------------
__global__ __launch_bounds__(256) void vq_post_kernel(
    const float* __restrict__ dots, const float* __restrict__ sumc2,
    const float* __restrict__ feats, const float* __restrict__ codebook,
    const float* __restrict__ emb, float* __restrict__ H,
    unsigned short* __restrict__ Hbf,
    float* __restrict__ loss)
{
    const int n = blockIdx.x, tid = threadIdx.x;
    float best = 3.4e38f; int bi = 0;
    for (int c = tid; c < Kc; c += 256) {
        float dct = sumc2[c] - 2.f * dots[(size_t)n * Kc + c];
        if (dct < best) { best = dct; bi = c; }
    }
#pragma unroll
    for (int off = 32; off > 0; off >>= 1) {
        float ov = __shfl_down(best, off);
        int   oi = __shfl_down(bi, off);
        if (ov < best || (ov == best && oi < bi)) { best = ov; bi = oi; }
    }
    __shared__ float vb[4]; __shared__ int ib[4];
    __shared__ int bidx;
    int wid = tid >> 6;
    if ((tid & 63) == 0) { vb[wid] = best; ib[wid] = bi; }
    __syncthreads();
    if (tid == 0) {
        float v = vb[0]; int i = ib[0];
        for (int w = 1; w < 4; ++w)
            if (vb[w] < v || (vb[w] == v && ib[w] < i)) { v = vb[w]; i = ib[w]; }
        bidx = i;
    }
    __syncthreads();
    const int c = bidx;
    float part = 0.f;
    for (int d = tid; d < Dz; d += 256) {
        float xv = feats[(size_t)n * Dz + d];
        float cv = codebook[(size_t)c * Dz + d];
        float df = cv - xv;
        part += df * df;
        float ev = emb[(size_t)c * Dz + d];
        H[(size_t)n * Dz + d] = ev;
        Hbf[(size_t)n * Dz + d] = f2b(ev);
    }
#pragma unroll
    for (int off = 32; off > 0; off >>= 1) part += __shfl_down(part, off);
    __shared__ float pb[4];
    if ((tid & 63) == 0) pb[wid] = part;
    __syncthreads();
    if (tid == 0) atomicAdd(loss, pb[0] + pb[1] + pb[2] + pb[3]);
}

// ---------------------------------------------------------------------------
__global__ __launch_bounds__(256) void dec_embed_kernel(
    const int* __restrict__ labels, const float* __restrict__ tok,
    float* __restrict__ Y, unsigned short* __restrict__ Ybf,
    float* __restrict__ tgt)
{
    const int t = blockIdx.x;
    const int b = t / Tz, pos = t % Tz;
    const int lab = labels[b * Lz + pos];
    const int tid = threadIdx.x;
    const float* src = tok + (size_t)lab * Dz;
    float* dst = Y + (size_t)t * Dz;
    unsigned short* dbf = Ybf + (size_t)t * Dz;
    float a = src[tid], b1 = src[tid + 256], c = src[tid + 512];
    dst[tid] = a; dst[tid + 256] = b1; dst[tid + 512] = c;
    dbf[tid] = f2b(a); dbf[tid + 256] = f2b(b1); dbf[tid + 512] = f2b(c);
    if (tid == 0) tgt[t] = (float)labels[b * Lz + pos + 1];
}

__global__ void finalize_kernel(const float* loss, float* out)
{
    out[0] = loss[0] * (0.25f / (float)(NTOK * Dz));
}

// ---------------------------------------------------------------------------
// fp32 -> bf16 conversion over up to 6 concatenated segments, float4-wide.
// All segment sizes are multiples of 4.
// ---------------------------------------------------------------------------
__global__ __launch_bounds__(256) void conv6_kernel(
    const float* p0, int n0, const float* p1, int n1,
    const float* p2, int n2, const float* p3, int n3,
    const float* p4, int n4, const float* p5, int n5,
    unsigned short* __restrict__ dst)
{
    const int m0 = n0 >> 2, m1 = n1 >> 2, m2 = n2 >> 2,
              m3 = n3 >> 2, m4 = n4 >> 2, m5 = n5 >> 2;
    const int total4 = m0 + m1 + m2 + m3 + m4 + m5;
    for (int i = blockIdx.x * blockDim.x + threadIdx.x; i < total4;
         i += gridDim.x * blockDim.x) {
        int j = i; const float* p;
        if (j < m0) { p = p0; }
        else { j -= m0;
            if (j < m1) { p = p1; }
            else { j -= m1;
                if (j < m2) { p = p2; }
                else { j -= m2;
                    if (j < m3) { p = p3; }
                    else { j -= m3;
                        if (j < m4) { p = p4; }
                        else { j -= m4; p = p5; }
                    }
                }
            }
        }
        float4 v = ((const float4*)p)[j];
        ushort4 o;
        o.x = f2b(v.x); o.y = f2b(v.y); o.z = f2b(v.z); o.w = f2b(v.w);
        ((ushort4*)dst)[i] = o;
    }
}

// ---------------------------------------------------------------------------
extern "C" void kernel_launch(void* const* d_in, const int* in_sizes, int n_in,
                              void* d_out, int out_size, void* d_ws, size_t ws_size,
                              hipStream_t stream)
{
    bool sig = (n_in > 8 && in_sizes[8] == 9216);
    int I_eWqkv, I_ebqkv, I_eWo, I_ebo, I_eln1g, I_eln1b, I_eW1, I_eb1, I_eW2, I_eb2,
        I_eln2g, I_eln2b, I_sWqkv, I_sbqkv, I_sWo, I_sbo, I_cWqkv, I_cbqkv, I_cWo,
        I_cbo, I_dln1g, I_dln1b, I_dln2g, I_dln2b, I_dln3g, I_dln3b, I_dW1, I_db1,
        I_dW2, I_db2;
    if (sig) {
        I_eWqkv = 7; I_ebqkv = 8; I_eWo = 9; I_ebo = 10; I_eln1g = 11; I_eln1b = 12;
        I_eW1 = 13; I_eb1 = 14; I_eW2 = 15; I_eb2 = 16; I_eln2g = 17; I_eln2b = 18;
        I_sWqkv = 19; I_sbqkv = 20; I_sWo = 21; I_sbo = 22;
        I_cWqkv = 23; I_cbqkv = 24; I_cWo = 25; I_cbo = 26;
        I_dln1g = 27; I_dln1b = 28; I_dln2g = 29; I_dln2b = 30; I_dln3g = 31; I_dln3b = 32;
        I_dW1 = 33; I_db1 = 34; I_dW2 = 35; I_db2 = 36;
    } else {
        I_eWqkv = 7; I_sWqkv = 8; I_cWqkv = 9;
        I_ebqkv = 10; I_eWo = 11; I_ebo = 12; I_eln1g = 13; I_eln1b = 14;
        I_eW1 = 15; I_eb1 = 16; I_eW2 = 17; I_eb2 = 18; I_eln2g = 19; I_eln2b = 20;
        I_sbqkv = 21; I_sWo = 22; I_sbo = 23;
        I_cbqkv = 24; I_cWo = 25; I_cbo = 26;
        I_dln1g = 27; I_dln1b = 28; I_dln2g = 29; I_dln2b = 30; I_dln3g = 31; I_dln3b = 32;
        I_dW1 = 33; I_db1 = 34; I_dW2 = 35; I_db2 = 36;
    }

    const float* feats = (const float*)d_in[0];
    const int*   labels = (const int*)d_in[1];
    const float* cb    = (const float*)d_in[2];
    const float* emb   = (const float*)d_in[3];
    const float* tok   = (const float*)d_in[4];
    const float* fcW   = (const float*)d_in[5];
    const float* fcb   = (const float*)d_in[6];
    const float* eWqkv = (const float*)d_in[I_eWqkv];
    const float* ebqkv = (const float*)d_in[I_ebqkv];
    const float* eWo   = (const float*)d_in[I_eWo];
    const float* ebo   = (const float*)d_in[I_ebo];
    const float* eln1g = (const float*)d_in[I_eln1g];
    const float* eln1b = (const float*)d_in[I_eln1b];
    const float* eW1   = (const float*)d_in[I_eW1];
    const float* eb1   = (const float*)d_in[I_eb1];
    const float* eW2   = (const float*)d_in[I_eW2];
    const float* eb2   = (const float*)d_in[I_eb2];
    const float* eln2g = (const float*)d_in[I_eln2g];
    const float* eln2b = (const float*)d_in[I_eln2b];
    const float* sWqkv = (const float*)d_in[I_sWqkv];
    const float* sbqkv = (const float*)d_in[I_sbqkv];
    const float* sWo   = (const float*)d_in[I_sWo];
    const float* sbo   = (const float*)d_in[I_sbo];
    const float* cWqkv = (const float*)d_in[I_cWqkv];
    const float* cbqkv = (const float*)d_in[I_cbqkv];
    const float* cWo   = (const float*)d_in[I_cWo];
    const float* cbo   = (const float*)d_in[I_cbo];
    const float* dln1g = (const float*)d_in[I_dln1g];
    const float* dln1b = (const float*)d_in[I_dln1b];
    const float* dln2g = (const float*)d_in[I_dln2g];
    const float* dln2b = (const float*)d_in[I_dln2b];
    const float* dln3g = (const float*)d_in[I_dln3g];
    const float* dln3b = (const float*)d_in[I_dln3b];
    const float* dW1   = (const float*)d_in[I_dW1];
    const float* db1   = (const float*)d_in[I_db1];
    const float* dW2   = (const float*)d_in[I_dW2];
    const float* db2   = (const float*)d_in[I_db2];

    // ---- workspace layout ----
    float* ws    = (float*)d_ws;
    float* sumc2 = ws;                       // 512
    float* loss  = ws + 512;                 // 1
    float* Hb    = ws + 1024;                // 4800*768
    float* T1    = ws + 3687424;             // 4800*768
    float* dots  = ws + 7373824;             // 4800*512
    float* Yb    = T1;                       // 784*768
    float* T1d   = T1 + 602112;              // 784*768

    unsigned short* bfbase = (unsigned short*)(ws + 9831424);
    unsigned short* Hb_bf  = bfbase;                     // 3,686,400
    unsigned short* ATT_bf = bfbase + 3686400;           // 3,686,400
    unsigned short* FF_bf  = bfbase + 7372800;           // 7,372,800
    unsigned short* Yb_bf  = bfbase + 14745600;          // 602,112
    unsigned short* Wbuf   = bfbase + 15347712;          // 7,077,888
    unsigned short* QKV_bf = bfbase + 22425600;          // 11,059,200
    unsigned short* QKVd_bf = QKV_bf;                    // 784*2304
    unsigned short* Qc_bf   = QKV_bf + 1806336;          // 784*768
    unsigned short* CKV_bf  = QKV_bf + 2408448;          // 4800*1536
    // VQ split buffers (used before encoder; alias QKV_bf / FF_bf)
    unsigned short* Asplit  = QKV_bf;                    // 4800*2304
    unsigned short* Bsplit  = FF_bf;                     // 512*2304

    float* outF = (float*)d_out;

    auto gemmb = [&](const unsigned short* A, const unsigned short* W,
                     float* Cf, unsigned short* Cb, int ldc,
                     const float* bias, const float* resid, int ldr,
                     int relu, int M, int N, int Kd) {
        dim3 g((N + 127) / 128, (M + 127) / 128);
        gemm_bf16_kernel<<<g, 256, 0, stream>>>(A, W, Cf, Cb, ldc, bias, resid, ldr,
                                                relu, M, N, Kd);
    };
    auto gemmb32 = [&](const unsigned short* A, const unsigned short* W,
                       float* Cf, unsigned short* Cb, int ldc,
                       const float* bias, const float* resid, int ldr,
                       int relu, int M, int N, int Kd) {
        dim3 g((N + 63) / 64, (M + 31) / 32);
        gemm_bf16_32_kernel<<<g, 256, 0, stream>>>(A, W, Cf, Cb, ldc, bias, resid, ldr,
                                                   relu, M, N, Kd);
    };

    const float scale = 0.1020620726159658f; // 1/sqrt(96)
    const float* Z = nullptr;

    // --- VQ stage: dots via split hi/lo bf16 MFMA (K-concat 3x768) ---
    sumsq_kernel<<<Kc, 256, 0, stream>>>(cb, sumc2, loss);
    vq_split_kernel<<<(NTOK * Dz + 255) / 256, 256, 0, stream>>>(feats, Asplit, NTOK, 0);
    vq_split_kernel<<<(Kc * Dz + 255) / 256, 256, 0, stream>>>(cb, Bsplit, Kc, 1);
    gemmb32(Asplit, Bsplit, dots, nullptr, Kc, Z, Z, 0, 0, NTOK, Kc, 2304);
    vq_post_kernel<<<NTOK, 256, 0, stream>>>(dots, sumc2, feats, cb, emb, Hb, Hb_bf, loss);
    finalize_kernel<<<1, 1, 0, stream>>>(loss, outF + 3920000);

    // --- Encoder ---
    const int W_QKV = 2304 * 768, W_O = 768 * 768, W_F1 = 1536 * 768, W_F2 = 768 * 1536;
    for (int i = 0; i < 4; ++i) {
        conv6_kernel<<<2048, 256, 0, stream>>>(
            eWqkv + (size_t)i * W_QKV, W_QKV,
            eWo   + (size_t)i * W_O,   W_O,
            eW1   + (size_t)i * W_F1,  W_F1,
            eW2   + (size_t)i * W_F2,  W_F2,
            Z, 0, Z, 0, Wbuf);
        unsigned short* bWqkv = Wbuf;
        unsigned short* bWo   = Wbuf + W_QKV;
        unsigned short* bW1   = Wbuf + W_QKV + W_O;
        unsigned short* bW2   = Wbuf + W_QKV + W_O + W_F1;

        gemmb(Hb_bf, bWqkv, nullptr, QKV_bf, 2304, ebqkv + i * 2304, Z, 0, 0, NTOK, 2304, Dz);
        attn_mfma_kernel<<<dim3(10, Hh, Bz), 256, 0, stream>>>(
            QKV_bf, 2304, 0, QKV_bf, 2304, 768, QKV_bf, 2304, 1536, ATT_bf,
            Sz, Sz, scale, 0, nullptr);
        gemmb(ATT_bf, bWo, T1, nullptr, Dz, ebo + i * Dz, Hb, Dz, 0, NTOK, Dz, Dz);
        ln_kernel<<<NTOK, 256, 0, stream>>>(T1, Hb, Hb_bf, eln1g + i * Dz, eln1b + i * Dz);
        gemmb(Hb_bf, bW1, nullptr, FF_bf, 1536, eb1 + i * 1536, Z, 0, 1, NTOK, 1536, Dz);
        gemmb(FF_bf, bW2, T1, nullptr, Dz, eb2 + i * Dz, Hb, Dz, 0, NTOK, Dz, 1536);
        ln_kernel<<<NTOK, 256, 0, stream>>>(T1, Hb, Hb_bf, eln2g + i * Dz, eln2b + i * Dz);
    }

    // --- Decoder ---
    dec_embed_kernel<<<NDTOK, 256, 0, stream>>>(labels, tok, Yb, Yb_bf, outF + 3920001);
    for (int i = 0; i < 4; ++i) {
        conv6_kernel<<<2048, 256, 0, stream>>>(
            sWqkv + (size_t)i * W_QKV, W_QKV,
            sWo   + (size_t)i * W_O,   W_O,
            cWqkv + (size_t)i * W_QKV, W_QKV,
            cWo   + (size_t)i * W_O,   W_O,
            dW1   + (size_t)i * W_F1,  W_F1,
            dW2   + (size_t)i * W_F2,  W_F2, Wbuf);
        unsigned short* bsWqkv = Wbuf;
        unsigned short* bsWo   = Wbuf + W_QKV;
        unsigned short* bcWqkv = Wbuf + W_QKV + W_O;
        unsigned short* bcWo   = Wbuf + 2 * W_QKV + W_O;
        unsigned short* bW1    = Wbuf + 2 * W_QKV + 2 * W_O;
        unsigned short* bW2    = Wbuf + 2 * W_QKV + 2 * W_O + W_F1;

        // self-attention (causal + key-padding)
        gemmb32(Yb_bf, bsWqkv, nullptr, QKVd_bf, 2304, sbqkv + i * 2304, Z, 0, 0, NDTOK, 2304, Dz);
        attn_mfma_kernel<<<dim3(2, Hh, Bz), 256, 0, stream>>>(
            QKVd_bf, 2304, 0, QKVd_bf, 2304, 768, QKVd_bf, 2304, 1536, ATT_bf,
            Tz, Tz, scale, 1, labels);
        gemmb32(ATT_bf, bsWo, T1d, nullptr, Dz, sbo + i * Dz, Yb, Dz, 0, NDTOK, Dz, Dz);
        ln_kernel<<<NDTOK, 256, 0, stream>>>(T1d, Yb, Yb_bf, dln1g + i * Dz, dln1b + i * Dz);
        // cross-attention
        gemmb32(Yb_bf, bcWqkv, nullptr, Qc_bf, Dz, cbqkv + i * 2304, Z, 0, 0, NDTOK, Dz, Dz);
        gemmb(Hb_bf, bcWqkv + (size_t)768 * 768, nullptr, CKV_bf, 1536,
              cbqkv + i * 2304 + 768, Z, 0, 0, NTOK, 1536, Dz);
        attn_mfma_kernel<<<dim3(2, Hh, Bz), 256, 0, stream>>>(
            Qc_bf, 768, 0, CKV_bf, 1536, 0, CKV_bf, 1536, 768, ATT_bf,
            Tz, Sz, scale, 0, nullptr);
        gemmb32(ATT_bf, bcWo, T1d, nullptr, Dz, cbo + i * Dz, Yb, Dz, 0, NDTOK, Dz, Dz);
        ln_kernel<<<NDTOK, 256, 0, stream>>>(T1d, Yb, Yb_bf, dln2g + i * Dz, dln2b + i * Dz);
        // feed-forward
        gemmb32(Yb_bf, bW1, nullptr, FF_bf, 1536, db1 + i * 1536, Z, 0, 1, NDTOK, 1536, Dz);
        gemmb32(FF_bf, bW2, T1d, nullptr, Dz, db2 + i * Dz, Yb, Dz, 0, NDTOK, Dz, 1536);
        ln_kernel<<<NDTOK, 256, 0, stream>>>(T1d, Yb, Yb_bf, dln3g + i * Dz, dln3b + i * Dz);
    }

    // --- Final FC ---
    conv6_kernel<<<2048, 256, 0, stream>>>(fcW, Vz * Dz, Z, 0, Z, 0, Z, 0, Z, 0, Z, 0, Wbuf);
    gemmb32(Yb_bf, Wbuf, outF, nullptr, Vz, fcb, Z, 0, 0, NDTOK, Vz, Dz);
}

// Round 6
// 2144.717 us; speedup vs baseline: 4.2922x; 1.0917x over previous
//
#include <hip/hip_runtime.h>
#include <hip/hip_bf16.h>

// Problem constants
#define Bz   16
#define Sz   300
#define Dz   768
#define Kc   512
#define Vz   5000
#define Hh   8
#define HD   96
#define Lz   50
#define Tz   49          // L-1
#define NTOK 4800        // B*S
#define NDTOK 784        // B*T

typedef short bf16x8 __attribute__((ext_vector_type(8)));
typedef float f32x4  __attribute__((ext_vector_type(4)));
typedef unsigned short us8 __attribute__((ext_vector_type(8)));

// RNE float->bf16 (finite inputs)
__device__ __forceinline__ unsigned short f2b(float f) {
    unsigned u = __float_as_uint(f);
    unsigned r = (u + 0x7fffu + ((u >> 16) & 1u)) >> 16;
    return (unsigned short)r;
}
__device__ __forceinline__ float b2f(unsigned short h) {
    return __uint_as_float(((unsigned)h) << 16);
}

__device__ __forceinline__ void glds16(const unsigned short* g, unsigned short* l) {
    __builtin_amdgcn_global_load_lds(
        (const __attribute__((address_space(1))) void*)g,
        (__attribute__((address_space(3))) void*)l, 16, 0, 0);
}

// ---------------------------------------------------------------------------
// bf16 MFMA GEMM, 128x128 tile, BK=32 (m97 structure): C = A * W^T
// ---------------------------------------------------------------------------
__global__ __launch_bounds__(256) void gemm_bf16_kernel(
    const unsigned short* __restrict__ A,   // [M x Kd]
    const unsigned short* __restrict__ Bw,  // [N x Kd]
    float* __restrict__ Cf,                 // fp32 out (or null)
    unsigned short* __restrict__ Cb,        // bf16 out (or null)
    int ldc,
    const float* __restrict__ bias,
    const float* __restrict__ resid, int ldr,
    int relu, int M, int N, int Kd)
{
    __shared__ unsigned short As[128 * 32];
    __shared__ unsigned short Bs[128 * 32];
    const int tid  = threadIdx.x;
    const int wave = tid >> 6, lane = tid & 63;
    const int row0 = blockIdx.y * 128, col0 = blockIdx.x * 128;

    const int c0 = wave * 2;
    const int srow = lane >> 2;
    const int skcol = (lane & 3) * 8;
    int rA0 = row0 + c0 * 16 + srow;        if (rA0 > M - 1) rA0 = M - 1;
    int rA1 = row0 + (c0 + 1) * 16 + srow;  if (rA1 > M - 1) rA1 = M - 1;
    int rB0 = col0 + c0 * 16 + srow;        if (rB0 > N - 1) rB0 = N - 1;
    int rB1 = col0 + (c0 + 1) * 16 + srow;  if (rB1 > N - 1) rB1 = N - 1;
    const unsigned short* pA0 = A + (size_t)rA0 * Kd + skcol;
    const unsigned short* pA1 = A + (size_t)rA1 * Kd + skcol;
    const unsigned short* pB0 = Bw + (size_t)rB0 * Kd + skcol;
    const unsigned short* pB1 = Bw + (size_t)rB1 * Kd + skcol;
    unsigned short* lA0 = &As[c0 * 512];
    unsigned short* lA1 = &As[(c0 + 1) * 512];
    unsigned short* lB0 = &Bs[c0 * 512];
    unsigned short* lB1 = &Bs[(c0 + 1) * 512];

    const int wr = (wave >> 1) * 64, wc = (wave & 1) * 64;
    const int fr = lane & 15;
    const int kq = (lane >> 4) * 8;

    f32x4 acc[4][4];
    const f32x4 zero = { 0.f, 0.f, 0.f, 0.f };
#pragma unroll
    for (int i = 0; i < 4; ++i)
#pragma unroll
        for (int j = 0; j < 4; ++j) acc[i][j] = zero;

    for (int k0 = 0; k0 < Kd; k0 += 32) {
        __syncthreads();
        glds16(pA0 + k0, lA0);
        glds16(pA1 + k0, lA1);
        glds16(pB0 + k0, lB0);
        glds16(pB1 + k0, lB1);
        __syncthreads();

        bf16x8 af[4], bfr[4];
#pragma unroll
        for (int i = 0; i < 4; ++i)
            af[i] = *(const bf16x8*)(const void*)(&As[(wr + i * 16 + fr) * 32 + kq]);
#pragma unroll
        for (int j = 0; j < 4; ++j)
            bfr[j] = *(const bf16x8*)(const void*)(&Bs[(wc + j * 16 + fr) * 32 + kq]);
#pragma unroll
        for (int i = 0; i < 4; ++i)
#pragma unroll
            for (int j = 0; j < 4; ++j)
                acc[i][j] = __builtin_amdgcn_mfma_f32_16x16x32_bf16(
                    af[i], bfr[j], acc[i][j], 0, 0, 0);
    }

    const int rbase = row0 + wr + ((lane >> 4) << 2);
    const int cbase = col0 + wc + (lane & 15);
#pragma unroll
    for (int i = 0; i < 4; ++i) {
#pragma unroll
        for (int r = 0; r < 4; ++r) {
            int row = rbase + i * 16 + r;
            if (row >= M) continue;
#pragma unroll
            for (int j = 0; j < 4; ++j) {
                int col = cbase + j * 16;
                if (col >= N) continue;
                float v = acc[i][j][r];
                if (bias)  v += bias[col];
                if (resid) v += resid[(size_t)row * ldr + col];
                if (relu)  v = fmaxf(v, 0.f);
                if (Cf) Cf[(size_t)row * ldc + col] = v;
                if (Cb) Cb[(size_t)row * ldc + col] = f2b(v);
            }
        }
    }
}

// ---------------------------------------------------------------------------
// bf16 MFMA GEMM, 32x64 tile, BK=32 — max occupancy for small-M matrices.
// ---------------------------------------------------------------------------
__global__ __launch_bounds__(256) void gemm_bf16_32_kernel(
    const unsigned short* __restrict__ A,
    const unsigned short* __restrict__ Bw,
    float* __restrict__ Cf, unsigned short* __restrict__ Cb, int ldc,
    const float* __restrict__ bias,
    const float* __restrict__ resid, int ldr,
    int relu, int M, int N, int Kd)
{
    __shared__ unsigned short As[32 * 32];
    __shared__ unsigned short Bs[64 * 32];
    const int tid = threadIdx.x, wave = tid >> 6, lane = tid & 63;
    const int row0 = blockIdx.y * 32, col0 = blockIdx.x * 64;
    const int fr = lane & 15, quad = lane >> 4;
    const int sr = lane >> 2;          // 0..15
    const int sc = (lane & 3) * 8;

    const unsigned short* pA = nullptr;
    const unsigned short* pB0 = nullptr;
    const unsigned short* pB1 = nullptr;
    unsigned short* lA = nullptr;
    unsigned short* lB0 = nullptr;
    unsigned short* lB1 = nullptr;
    if (wave < 2) {
        int ra = row0 + wave * 16 + sr; if (ra > M - 1) ra = M - 1;
        pA = A + (size_t)ra * Kd + sc;
        lA = &As[wave * 512];
    } else {
        int w2 = wave - 2;
        int rb0 = col0 + w2 * 16 + sr;       if (rb0 > N - 1) rb0 = N - 1;
        int rb1 = col0 + 32 + w2 * 16 + sr;  if (rb1 > N - 1) rb1 = N - 1;
        pB0 = Bw + (size_t)rb0 * Kd + sc;
        pB1 = Bw + (size_t)rb1 * Kd + sc;
        lB0 = &Bs[w2 * 512];
        lB1 = &Bs[1024 + w2 * 512];
    }

    f32x4 acc[2];
    acc[0] = (f32x4){ 0.f, 0.f, 0.f, 0.f };
    acc[1] = (f32x4){ 0.f, 0.f, 0.f, 0.f };

    const int mrow = (wave & 1) * 16 + fr;
    const int ng = (wave >> 1) * 32;

    for (int k0 = 0; k0 < Kd; k0 += 32) {
        __syncthreads();
        if (wave < 2) {
            glds16(pA + k0, lA);
        } else {
            glds16(pB0 + k0, lB0);
            glds16(pB1 + k0, lB1);
        }
        __syncthreads();
        bf16x8 a = *(const bf16x8*)(const void*)(&As[mrow * 32 + quad * 8]);
#pragma unroll
        for (int t = 0; t < 2; ++t) {
            bf16x8 b = *(const bf16x8*)(const void*)(&Bs[(ng + t * 16 + fr) * 32 + quad * 8]);
            acc[t] = __builtin_amdgcn_mfma_f32_16x16x32_bf16(a, b, acc[t], 0, 0, 0);
        }
    }

    const int rbase = row0 + (wave & 1) * 16 + quad * 4;
    const int cbase = col0 + ng + fr;
#pragma unroll
    for (int r = 0; r < 4; ++r) {
        int row = rbase + r;
        if (row >= M) continue;
#pragma unroll
        for (int t = 0; t < 2; ++t) {
            int col = cbase + t * 16;
            if (col >= N) continue;
            float v = acc[t][r];
            if (bias)  v += bias[col];
            if (resid) v += resid[(size_t)row * ldr + col];
            if (relu)  v = fmaxf(v, 0.f);
            if (Cf) Cf[(size_t)row * ldc + col] = v;
            if (Cb) Cb[(size_t)row * ldc + col] = f2b(v);
        }
    }
}

// ---------------------------------------------------------------------------
// VQ split: x -> (hi, lo) bf16, written K-concatenated.
// pattern 0 (A): [hi | hi | lo]   pattern 1 (B): [hi | lo | hi]
// ---------------------------------------------------------------------------
__global__ __launch_bounds__(256) void vq_split_kernel(
    const float* __restrict__ src, unsigned short* __restrict__ dst,
    int nrows, int pattern)
{
    int i = blockIdx.x * 256 + threadIdx.x;
    if (i >= nrows * Dz) return;
    int r = i / Dz, c = i % Dz;
    float x = src[i];
    unsigned short h = f2b(x);
    unsigned short l = f2b(x - b2f(h));
    unsigned short* d = dst + (size_t)r * 2304 + c;
    if (pattern == 0) { d[0] = h; d[768] = h; d[1536] = l; }
    else              { d[0] = h; d[768] = l; d[1536] = h; }
}

// ---------------------------------------------------------------------------
// Single-pass online-softmax MFMA attention.
// One block = 64 q-rows x 1 head x 1 batch; wave w owns q-rows w*16..+15.
// Scores live in registers; row reductions via shfl_xor (within-wave).
// P transposes through per-wave Pb rows; V staged transposed (XOR swizzle).
// LDS = 32 KB -> 4 blocks/CU.
// ---------------------------------------------------------------------------
#define AQ_LD 104   // Qs row stride (u16)
#define AK_LD 104   // Ks row stride (u16)
#define VT_LD 40    // V^T row stride (u16)
#define AP_LD 40    // Pb row stride (u16)

__global__ __launch_bounds__(256) void attn_mfma_kernel(
    const unsigned short* __restrict__ Qp, int qld, int qoff,
    const unsigned short* __restrict__ Kp, int kld, int koff,
    const unsigned short* __restrict__ Vp, int vld, int voff,
    unsigned short* __restrict__ Op,
    int Sq, int Sk, float scale, int causal,
    const int* __restrict__ lab)
{
    const int qt = blockIdx.x, h = blockIdx.y, b = blockIdx.z;
    const int q0 = qt * 64;
    __shared__ __align__(16) unsigned short Qs[64 * AQ_LD];  // 13312 B
    __shared__ __align__(16) unsigned short Ks[32 * AK_LD];  //  6656 B
    __shared__ __align__(16) unsigned short VT[96 * VT_LD];  //  7680 B
    __shared__ __align__(16) unsigned short Pb[64 * AP_LD];  //  5120 B

    const int tid = threadIdx.x;
    const int wave = tid >> 6, lane = tid & 63;
    const int fr = lane & 15, quad = lane >> 4;
    const int nst = (Sk + 31) / 32;

    // ---- load Q tile (64 x 96) ----
    for (int e = tid; e < 768; e += 256) {
        int r = e / 12, c8 = (e % 12) * 8;
        int gq = q0 + r; if (gq >= Sq) gq = Sq - 1;
        us8 v = *(const us8*)(Qp + (size_t)(b * Sq + gq) * qld + qoff + h * HD + c8);
        *(us8*)(&Qs[r * AQ_LD + c8]) = v;
    }

    // online state (rows quad*4+r of this wave's 16)
    float mrow[4], lrow[4];
#pragma unroll
    for (int r = 0; r < 4; ++r) { mrow[r] = -3e38f; lrow[r] = 0.f; }
    f32x4 oacc[6];
#pragma unroll
    for (int n = 0; n < 6; ++n) oacc[n] = (f32x4){ 0.f, 0.f, 0.f, 0.f };

    const int lrow_base = wave * 16 + quad * 4;

    for (int it = 0; it < nst; ++it) {
        const int s0 = it * 32;
        // ---- stage K (row-major) + V (transposed, XOR-swizzled) ----
        for (int e = tid; e < 384; e += 256) {
            int r = e / 12, c8 = (e % 12) * 8;
            int gk = s0 + r; if (gk >= Sk) gk = Sk - 1;
            us8 kv = *(const us8*)(Kp + (size_t)(b * Sk + gk) * kld + koff + h * HD + c8);
            *(us8*)(&Ks[r * AK_LD + c8]) = kv;
            us8 vv = *(const us8*)(Vp + (size_t)(b * Sk + gk) * vld + voff + h * HD + c8);
            const int f = ((c8 >> 3) & 3) << 3;
            const int rx = r ^ f;
#pragma unroll
            for (int j = 0; j < 8; ++j)
                VT[(c8 + j) * VT_LD + rx] = vv[j];
        }
        __syncthreads();

        // ---- scores: this wave's 16 rows x 32 cols ----
        f32x4 sc[2];
        sc[0] = (f32x4){ 0.f, 0.f, 0.f, 0.f };
        sc[1] = (f32x4){ 0.f, 0.f, 0.f, 0.f };
#pragma unroll
        for (int kk = 0; kk < 3; ++kk) {
            bf16x8 a = *(const bf16x8*)(const void*)(&Qs[(wave * 16 + fr) * AQ_LD + kk * 32 + quad * 8]);
#pragma unroll
            for (int t = 0; t < 2; ++t) {
                bf16x8 bb = *(const bf16x8*)(const void*)(&Ks[(t * 16 + fr) * AK_LD + kk * 32 + quad * 8]);
                sc[t] = __builtin_amdgcn_mfma_f32_16x16x32_bf16(a, bb, sc[t], 0, 0, 0);
            }
        }

        // ---- mask + scale in registers ----
        bool cv[2];
#pragma unroll
        for (int t = 0; t < 2; ++t) {
            int col = s0 + t * 16 + fr;
            bool ok = (col < Sk);
            if (ok && lab && lab[b * Lz + col + 1] == 0) ok = false;
            cv[t] = ok;
        }
#pragma unroll
        for (int r = 0; r < 4; ++r) {
            int gq = q0 + lrow_base + r;
#pragma unroll
            for (int t = 0; t < 2; ++t) {
                int col = s0 + t * 16 + fr;
                bool ok = cv[t] && (!causal || col <= gq);
                sc[t][r] = ok ? sc[t][r] * scale : -3e38f;
            }
        }

        // ---- online softmax update (row reductions over fr lanes) ----
        float p0[4], p1[4];
#pragma unroll
        for (int r = 0; r < 4; ++r) {
            float mx = fmaxf(sc[0][r], sc[1][r]);
#pragma unroll
            for (int off = 1; off < 16; off <<= 1) mx = fmaxf(mx, __shfl_xor(mx, off));
            float mnew = fmaxf(mrow[r], mx);
            float alpha = __expf(mrow[r] - mnew);
            float a0 = __expf(sc[0][r] - mnew);
            float a1 = __expf(sc[1][r] - mnew);
            float sum = a0 + a1;
#pragma unroll
            for (int off = 1; off < 16; off <<= 1) sum += __shfl_xor(sum, off);
            lrow[r] = lrow[r] * alpha + sum;
            mrow[r] = mnew;
            p0[r] = a0; p1[r] = a1;
#pragma unroll
            for (int n = 0; n < 6; ++n) oacc[n][r] *= alpha;
        }

        // ---- P -> LDS (own-wave rows only; no barrier needed) ----
#pragma unroll
        for (int r = 0; r < 4; ++r) {
            Pb[(lrow_base + r) * AP_LD + fr]      = f2b(p0[r]);
            Pb[(lrow_base + r) * AP_LD + 16 + fr] = f2b(p1[r]);
        }

        // ---- PV: A = own P rows (A-layout), B = V^T ----
        bf16x8 a = *(const bf16x8*)(const void*)(&Pb[(wave * 16 + fr) * AP_LD + quad * 8]);
#pragma unroll
        for (int n = 0; n < 6; ++n) {
            const int dcol = n * 16 + fr;
            const int f2 = ((dcol >> 3) & 3) << 3;
            bf16x8 bv = *(const bf16x8*)(const void*)(&VT[dcol * VT_LD + ((quad * 8) ^ f2)]);
            oacc[n] = __builtin_amdgcn_mfma_f32_16x16x32_bf16(a, bv, oacc[n], 0, 0, 0);
        }
        __syncthreads();
    }

    // ---- store ----
#pragma unroll
    for (int r = 0; r < 4; ++r) {
        int grow = q0 + lrow_base + r;
        if (grow >= Sq) continue;
        float inv = 1.f / lrow[r];
#pragma unroll
        for (int n = 0; n < 6; ++n) {
            int col = h * HD + n * 16 + fr;
            Op[(size_t)(b * Sq + grow) * Dz + col] = f2b(oacc[n][r] * inv);
        }
    }
}

// ---------------------------------------------------------------------------
// LayerNorm over last dim (768); writes fp32 and optional bf16 copy.
// ---------------------------------------------------------------------------
__global__ __launch_bounds__(256) void ln_kernel(
    const float* __restrict__ X, float* __restrict__ Y,
    unsigned short* __restrict__ Ybf,
    const float* __restrict__ g, const float* __restrict__ bb)
{
    const int n = blockIdx.x;
    const int tid = threadIdx.x;
    const float* x = X + (size_t)n * Dz;
    float v0 = x[tid], v1 = x[tid + 256], v2 = x[tid + 512];
    float s = v0 + v1 + v2;
    float q = v0 * v0 + v1 * v1 + v2 * v2;
#pragma unroll
    for (int off = 32; off > 0; off >>= 1) {
        s += __shfl_down(s, off);
        q += __shfl_down(q, off);
    }
    __shared__ float sbuf[4], qbuf[4];
    __shared__ float mv[2];
    int wid = tid >> 6;
    if ((tid & 63) == 0) { sbuf[wid] = s; qbuf[wid] = q; }
    __syncthreads();
    if (tid == 0) {
        float ts = sbuf[0] + sbuf[1] + sbuf[2] + sbuf[3];
        float tq = qbuf[0] + qbuf[1] + qbuf[2] + qbuf[3];
        float mean = ts * (1.f / 768.f);
        float var = tq * (1.f / 768.f) - mean * mean;
        mv[0] = mean;
        mv[1] = rsqrtf(var + 1e-5f);
    }
    __syncthreads();
    float mean = mv[0], inv = mv[1];
    float* y = Y + (size_t)n * Dz;
    float r0 = (v0 - mean) * inv * g[tid]       + bb[tid];
    float r1 = (v1 - mean) * inv * g[tid + 256] + bb[tid + 256];
    float r2 = (v2 - mean) * inv * g[tid + 512] + bb[tid + 512];
    y[tid] = r0; y[tid + 256] = r1; y[tid + 512] = r2;
    if (Ybf) {
        unsigned short* yb = Ybf + (size_t)n * Dz;
        yb[tid] = f2b(r0); yb[tid + 256] = f2b(r1); yb[tid + 512] = f2b(r2);
    }
}

// ---------------------------------------------------------------------------
// Codebook row sum of squares; block 0 also zeroes the loss accumulator.
// ---------------------------------------------------------------------------
__global__ __launch_bounds__(256) void sumsq_kernel(
    const float* __restrict__ cb, float* __restrict__ out, float* __restrict__ loss)
{
    const int c = blockIdx.x, tid = threadIdx.x;
    if (c == 0 && tid == 0) *loss = 0.f;
    const float* x = cb + (size_t)c * Dz;
    float v0 = x[tid], v1 = x[tid + 256], v2 = x[tid + 512];
    float q = v0 * v0 + v1 * v1 + v2 * v2;
#pragma unroll
    for (int off = 32; off > 0; off >>= 1) q += __shfl_down(q, off);
    __shared__ float qbuf[4];
    int wid = tid >> 6;
    if ((tid & 63) == 0) qbuf[wid] = q;
    __syncthreads();
    if (tid == 0) out[c] = qbuf[0] + qbuf[1] + qbuf[2] + qbuf[3];
}

// ---------------------------------------------------------------------------
__global__ __launch_bounds__(256) void vq_post_kernel(
    const float* __restrict__ dots, const float* __restrict__ sumc2,
    const float* __restrict__ feats, const float* __restrict__ codebook,
    const float* __restrict__ emb, float* __restrict__ H,
    unsigned short* __restrict__ Hbf,
    float* __restrict__ loss)
{
    const int n = blockIdx.x, tid = threadIdx.x;
    float best = 3.4e38f; int bi = 0;
    for (int c = tid; c < Kc; c += 256) {
        float dct = sumc2[c] - 2.f * dots[(size_t)n * Kc + c];
        if (dct < best) { best = dct; bi = c; }
    }
#pragma unroll
    for (int off = 32; off > 0; off >>= 1) {
        float ov = __shfl_down(best, off);
        int   oi = __shfl_down(bi, off);
        if (ov < best || (ov == best && oi < bi)) { best = ov; bi = oi; }
    }
    __shared__ float vb[4]; __shared__ int ib[4];
    __shared__ int bidx;
    int wid = tid >> 6;
    if ((tid & 63) == 0) { vb[wid] = best; ib[wid] = bi; }
    __syncthreads();
    if (tid == 0) {
        float v = vb[0]; int i = ib[0];
        for (int w = 1; w < 4; ++w)
            if (vb[w] < v || (vb[w] == v && ib[w] < i)) { v = vb[w]; i = ib[w]; }
        bidx = i;
    }
    __syncthreads();
    const int c = bidx;
    float part = 0.f;
    for (int d = tid; d < Dz; d += 256) {
        float xv = feats[(size_t)n * Dz + d];
        float cv = codebook[(size_t)c * Dz + d];
        float df = cv - xv;
        part += df * df;
        float ev = emb[(size_t)c * Dz + d];
        H[(size_t)n * Dz + d] = ev;
        Hbf[(size_t)n * Dz + d] = f2b(ev);
    }
#pragma unroll
    for (int off = 32; off > 0; off >>= 1) part += __shfl_down(part, off);
    __shared__ float pb[4];
    if ((tid & 63) == 0) pb[wid] = part;
    __syncthreads();
    if (tid == 0) atomicAdd(loss, pb[0] + pb[1] + pb[2] + pb[3]);
}

// ---------------------------------------------------------------------------
__global__ __launch_bounds__(256) void dec_embed_kernel(
    const int* __restrict__ labels, const float* __restrict__ tok,
    float* __restrict__ Y, unsigned short* __restrict__ Ybf,
    float* __restrict__ tgt)
{
    const int t = blockIdx.x;
    const int b = t / Tz, pos = t % Tz;
    const int lab = labels[b * Lz + pos];
    const int tid = threadIdx.x;
    const float* src = tok + (size_t)lab * Dz;
    float* dst = Y + (size_t)t * Dz;
    unsigned short* dbf = Ybf + (size_t)t * Dz;
    float a = src[tid], b1 = src[tid + 256], c = src[tid + 512];
    dst[tid] = a; dst[tid + 256] = b1; dst[tid + 512] = c;
    dbf[tid] = f2b(a); dbf[tid + 256] = f2b(b1); dbf[tid + 512] = f2b(c);
    if (tid == 0) tgt[t] = (float)labels[b * Lz + pos + 1];
}

__global__ void finalize_kernel(const float* loss, float* out)
{
    out[0] = loss[0] * (0.25f / (float)(NTOK * Dz));
}

// ---------------------------------------------------------------------------
// fp32 -> bf16 conversion over up to 6 concatenated segments, float4-wide.
// ---------------------------------------------------------------------------
__global__ __launch_bounds__(256) void conv6_kernel(
    const float* p0, int n0, const float* p1, int n1,
    const float* p2, int n2, const float* p3, int n3,
    const float* p4, int n4, const float* p5, int n5,
    unsigned short* __restrict__ dst)
{
    const int m0 = n0 >> 2, m1 = n1 >> 2, m2 = n2 >> 2,
              m3 = n3 >> 2, m4 = n4 >> 2, m5 = n5 >> 2;
    const int total4 = m0 + m1 + m2 + m3 + m4 + m5;
    for (int i = blockIdx.x * blockDim.x + threadIdx.x; i < total4;
         i += gridDim.x * blockDim.x) {
        int j = i; const float* p;
        if (j < m0) { p = p0; }
        else { j -= m0;
            if (j < m1) { p = p1; }
            else { j -= m1;
                if (j < m2) { p = p2; }
                else { j -= m2;
                    if (j < m3) { p = p3; }
                    else { j -= m3;
                        if (j < m4) { p = p4; }
                        else { j -= m4; p = p5; }
                    }
                }
            }
        }
        float4 v = ((const float4*)p)[j];
        ushort4 o;
        o.x = f2b(v.x); o.y = f2b(v.y); o.z = f2b(v.z); o.w = f2b(v.w);
        ((ushort4*)dst)[i] = o;
    }
}

// ---------------------------------------------------------------------------
extern "C" void kernel_launch(void* const* d_in, const int* in_sizes, int n_in,
                              void* d_out, int out_size, void* d_ws, size_t ws_size,
                              hipStream_t stream)
{
    bool sig = (n_in > 8 && in_sizes[8] == 9216);
    int I_eWqkv, I_ebqkv, I_eWo, I_ebo, I_eln1g, I_eln1b, I_eW1, I_eb1, I_eW2, I_eb2,
        I_eln2g, I_eln2b, I_sWqkv, I_sbqkv, I_sWo, I_sbo, I_cWqkv, I_cbqkv, I_cWo,
        I_cbo, I_dln1g, I_dln1b, I_dln2g, I_dln2b, I_dln3g, I_dln3b, I_dW1, I_db1,
        I_dW2, I_db2;
    if (sig) {
        I_eWqkv = 7; I_ebqkv = 8; I_eWo = 9; I_ebo = 10; I_eln1g = 11; I_eln1b = 12;
        I_eW1 = 13; I_eb1 = 14; I_eW2 = 15; I_eb2 = 16; I_eln2g = 17; I_eln2b = 18;
        I_sWqkv = 19; I_sbqkv = 20; I_sWo = 21; I_sbo = 22;
        I_cWqkv = 23; I_cbqkv = 24; I_cWo = 25; I_cbo = 26;
        I_dln1g = 27; I_dln1b = 28; I_dln2g = 29; I_dln2b = 30; I_dln3g = 31; I_dln3b = 32;
        I_dW1 = 33; I_db1 = 34; I_dW2 = 35; I_db2 = 36;
    } else {
        I_eWqkv = 7; I_sWqkv = 8; I_cWqkv = 9;
        I_ebqkv = 10; I_eWo = 11; I_ebo = 12; I_eln1g = 13; I_eln1b = 14;
        I_eW1 = 15; I_eb1 = 16; I_eW2 = 17; I_eb2 = 18; I_eln2g = 19; I_eln2b = 20;
        I_sbqkv = 21; I_sWo = 22; I_sbo = 23;
        I_cbqkv = 24; I_cWo = 25; I_cbo = 26;
        I_dln1g = 27; I_dln1b = 28; I_dln2g = 29; I_dln2b = 30; I_dln3g = 31; I_dln3b = 32;
        I_dW1 = 33; I_db1 = 34; I_dW2 = 35; I_db2 = 36;
    }

    const float* feats = (const float*)d_in[0];
    const int*   labels = (const int*)d_in[1];
    const float* cb    = (const float*)d_in[2];
    const float* emb   = (const float*)d_in[3];
    const float* tok   = (const float*)d_in[4];
    const float* fcW   = (const float*)d_in[5];
    const float* fcb   = (const float*)d_in[6];
    const float* eWqkv = (const float*)d_in[I_eWqkv];
    const float* ebqkv = (const float*)d_in[I_ebqkv];
    const float* eWo   = (const float*)d_in[I_eWo];
    const float* ebo   = (const float*)d_in[I_ebo];
    const float* eln1g = (const float*)d_in[I_eln1g];
    const float* eln1b = (const float*)d_in[I_eln1b];
    const float* eW1   = (const float*)d_in[I_eW1];
    const float* eb1   = (const float*)d_in[I_eb1];
    const float* eW2   = (const float*)d_in[I_eW2];
    const float* eb2   = (const float*)d_in[I_eb2];
    const float* eln2g = (const float*)d_in[I_eln2g];
    const float* eln2b = (const float*)d_in[I_eln2b];
    const float* sWqkv = (const float*)d_in[I_sWqkv];
    const float* sbqkv = (const float*)d_in[I_sbqkv];
    const float* sWo   = (const float*)d_in[I_sWo];
    const float* sbo   = (const float*)d_in[I_sbo];
    const float* cWqkv = (const float*)d_in[I_cWqkv];
    const float* cbqkv = (const float*)d_in[I_cbqkv];
    const float* cWo   = (const float*)d_in[I_cWo];
    const float* cbo   = (const float*)d_in[I_cbo];
    const float* dln1g = (const float*)d_in[I_dln1g];
    const float* dln1b = (const float*)d_in[I_dln1b];
    const float* dln2g = (const float*)d_in[I_dln2g];
    const float* dln2b = (const float*)d_in[I_dln2b];
    const float* dln3g = (const float*)d_in[I_dln3g];
    const float* dln3b = (const float*)d_in[I_dln3b];
    const float* dW1   = (const float*)d_in[I_dW1];
    const float* db1   = (const float*)d_in[I_db1];
    const float* dW2   = (const float*)d_in[I_dW2];
    const float* db2   = (const float*)d_in[I_db2];

    // ---- workspace layout ----
    float* ws    = (float*)d_ws;
    float* sumc2 = ws;                       // 512
    float* loss  = ws + 512;                 // 1
    float* Hb    = ws + 1024;                // 4800*768
    float* T1    = ws + 3687424;             // 4800*768
    float* dots  = ws + 7373824;             // 4800*512
    float* Yb    = T1;                       // 784*768
    float* T1d   = T1 + 602112;              // 784*768

    unsigned short* bfbase = (unsigned short*)(ws + 9831424);
    unsigned short* Hb_bf  = bfbase;                     // 3,686,400
    unsigned short* ATT_bf = bfbase + 3686400;           // 3,686,400
    unsigned short* FF_bf  = bfbase + 7372800;           // 7,372,800
    unsigned short* Yb_bf  = bfbase + 14745600;          // 602,112
    unsigned short* Wbuf   = bfbase + 15347712;          // 7,077,888
    unsigned short* QKV_bf = bfbase + 22425600;          // 11,059,200
    unsigned short* QKVd_bf = QKV_bf;                    // 784*2304
    unsigned short* Qc_bf   = QKV_bf + 1806336;          // 784*768
    unsigned short* CKV_bf  = QKV_bf + 2408448;          // 4800*1536
    unsigned short* Asplit  = QKV_bf;                    // 4800*2304 (VQ stage)
    unsigned short* Bsplit  = FF_bf;                     // 512*2304

    float* outF = (float*)d_out;

    auto gemmb = [&](const unsigned short* A, const unsigned short* W,
                     float* Cf, unsigned short* Cb, int ldc,
                     const float* bias, const float* resid, int ldr,
                     int relu, int M, int N, int Kd) {
        dim3 g((N + 127) / 128, (M + 127) / 128);
        gemm_bf16_kernel<<<g, 256, 0, stream>>>(A, W, Cf, Cb, ldc, bias, resid, ldr,
                                                relu, M, N, Kd);
    };
    auto gemmb32 = [&](const unsigned short* A, const unsigned short* W,
                       float* Cf, unsigned short* Cb, int ldc,
                       const float* bias, const float* resid, int ldr,
                       int relu, int M, int N, int Kd) {
        dim3 g((N + 63) / 64, (M + 31) / 32);
        gemm_bf16_32_kernel<<<g, 256, 0, stream>>>(A, W, Cf, Cb, ldc, bias, resid, ldr,
                                                   relu, M, N, Kd);
    };

    const float scale = 0.1020620726159658f; // 1/sqrt(96)
    const float* Z = nullptr;

    // --- VQ stage: dots via split hi/lo bf16 MFMA (K-concat 3x768) ---
    sumsq_kernel<<<Kc, 256, 0, stream>>>(cb, sumc2, loss);
    vq_split_kernel<<<(NTOK * Dz + 255) / 256, 256, 0, stream>>>(feats, Asplit, NTOK, 0);
    vq_split_kernel<<<(Kc * Dz + 255) / 256, 256, 0, stream>>>(cb, Bsplit, Kc, 1);
    gemmb32(Asplit, Bsplit, dots, nullptr, Kc, Z, Z, 0, 0, NTOK, Kc, 2304);
    vq_post_kernel<<<NTOK, 256, 0, stream>>>(dots, sumc2, feats, cb, emb, Hb, Hb_bf, loss);
    finalize_kernel<<<1, 1, 0, stream>>>(loss, outF + 3920000);

    // --- Encoder ---
    const int W_QKV = 2304 * 768, W_O = 768 * 768, W_F1 = 1536 * 768, W_F2 = 768 * 1536;
    for (int i = 0; i < 4; ++i) {
        conv6_kernel<<<2048, 256, 0, stream>>>(
            eWqkv + (size_t)i * W_QKV, W_QKV,
            eWo   + (size_t)i * W_O,   W_O,
            eW1   + (size_t)i * W_F1,  W_F1,
            eW2   + (size_t)i * W_F2,  W_F2,
            Z, 0, Z, 0, Wbuf);
        unsigned short* bWqkv = Wbuf;
        unsigned short* bWo   = Wbuf + W_QKV;
        unsigned short* bW1   = Wbuf + W_QKV + W_O;
        unsigned short* bW2   = Wbuf + W_QKV + W_O + W_F1;

        gemmb(Hb_bf, bWqkv, nullptr, QKV_bf, 2304, ebqkv + i * 2304, Z, 0, 0, NTOK, 2304, Dz);
        attn_mfma_kernel<<<dim3(5, Hh, Bz), 256, 0, stream>>>(
            QKV_bf, 2304, 0, QKV_bf, 2304, 768, QKV_bf, 2304, 1536, ATT_bf,
            Sz, Sz, scale, 0, nullptr);
        gemmb(ATT_bf, bWo, T1, nullptr, Dz, ebo + i * Dz, Hb, Dz, 0, NTOK, Dz, Dz);
        ln_kernel<<<NTOK, 256, 0, stream>>>(T1, Hb, Hb_bf, eln1g + i * Dz, eln1b + i * Dz);
        gemmb(Hb_bf, bW1, nullptr, FF_bf, 1536, eb1 + i * 1536, Z, 0, 1, NTOK, 1536, Dz);
        gemmb(FF_bf, bW2, T1, nullptr, Dz, eb2 + i * Dz, Hb, Dz, 0, NTOK, Dz, 1536);
        ln_kernel<<<NTOK, 256, 0, stream>>>(T1, Hb, Hb_bf, eln2g + i * Dz, eln2b + i * Dz);
    }

    // --- Decoder ---
    dec_embed_kernel<<<NDTOK, 256, 0, stream>>>(labels, tok, Yb, Yb_bf, outF + 3920001);
    for (int i = 0; i < 4; ++i) {
        conv6_kernel<<<2048, 256, 0, stream>>>(
            sWqkv + (size_t)i * W_QKV, W_QKV,
            sWo   + (size_t)i * W_O,   W_O,
            cWqkv + (size_t)i * W_QKV, W_QKV,
            cWo   + (size_t)i * W_O,   W_O,
            dW1   + (size_t)i * W_F1,  W_F1,
            dW2   + (size_t)i * W_F2,  W_F2, Wbuf);
        unsigned short* bsWqkv = Wbuf;
        unsigned short* bsWo   = Wbuf + W_QKV;
        unsigned short* bcWqkv = Wbuf + W_QKV + W_O;
        unsigned short* bcWo   = Wbuf + 2 * W_QKV + W_O;
        unsigned short* bW1    = Wbuf + 2 * W_QKV + 2 * W_O;
        unsigned short* bW2    = Wbuf + 2 * W_QKV + 2 * W_O + W_F1;

        // self-attention (causal + key-padding)
        gemmb32(Yb_bf, bsWqkv, nullptr, QKVd_bf, 2304, sbqkv + i * 2304, Z, 0, 0, NDTOK, 2304, Dz);
        attn_mfma_kernel<<<dim3(1, Hh, Bz), 256, 0, stream>>>(
            QKVd_bf, 2304, 0, QKVd_bf, 2304, 768, QKVd_bf, 2304, 1536, ATT_bf,
            Tz, Tz, scale, 1, labels);
        gemmb32(ATT_bf, bsWo, T1d, nullptr, Dz, sbo + i * Dz, Yb, Dz, 0, NDTOK, Dz, Dz);
        ln_kernel<<<NDTOK, 256, 0, stream>>>(T1d, Yb, Yb_bf, dln1g + i * Dz, dln1b + i * Dz);
        // cross-attention
        gemmb32(Yb_bf, bcWqkv, nullptr, Qc_bf, Dz, cbqkv + i * 2304, Z, 0, 0, NDTOK, Dz, Dz);
        gemmb(Hb_bf, bcWqkv + (size_t)768 * 768, nullptr, CKV_bf, 1536,
              cbqkv + i * 2304 + 768, Z, 0, 0, NTOK, 1536, Dz);
        attn_mfma_kernel<<<dim3(1, Hh, Bz), 256, 0, stream>>>(
            Qc_bf, 768, 0, CKV_bf, 1536, 0, CKV_bf, 1536, 768, ATT_bf,
            Tz, Sz, scale, 0, nullptr);
        gemmb32(ATT_bf, bcWo, T1d, nullptr, Dz, cbo + i * Dz, Yb, Dz, 0, NDTOK, Dz, Dz);
        ln_kernel<<<NDTOK, 256, 0, stream>>>(T1d, Yb, Yb_bf, dln2g + i * Dz, dln2b + i * Dz);
        // feed-forward
        gemmb32(Yb_bf, bW1, nullptr, FF_bf, 1536, db1 + i * 1536, Z, 0, 1, NDTOK, 1536, Dz);
        gemmb32(FF_bf, bW2, T1d, nullptr, Dz, db2 + i * Dz, Yb, Dz, 0, NDTOK, Dz, 1536);
        ln_kernel<<<NDTOK, 256, 0, stream>>>(T1d, Yb, Yb_bf, dln3g + i * Dz, dln3b + i * Dz);
    }

    // --- Final FC ---
    conv6_kernel<<<2048, 256, 0, stream>>>(fcW, Vz * Dz, Z, 0, Z, 0, Z, 0, Z, 0, Z, 0, Wbuf);
    gemmb32(Yb_bf, Wbuf, outF, nullptr, Vz, fcb, Z, 0, 0, NDTOK, Vz, Dz);
}